// Round 10
// baseline (2712.565 us; speedup 1.0000x reference)
//
#include <hip/hip_runtime.h>
#include <hip/hip_bf16.h>
#include <hip/hip_fp16.h>
#include <cstdint>
#include <cstddef>

// ---------------- constants ----------------
#define N_ATOM 16384
#define M_NBR  12
#define NCRY   128
#define NM     (N_ATOM*M_NBR) // 196608

// output offsets (floats)
#define O_ZDEC 0
#define O_MU   44236800
#define O_LV   44237056
#define O_Z    44237312
#define O_TIF  44237568

typedef unsigned short ushort_t;
typedef float f32x4 __attribute__((ext_vector_type(4)));
typedef short bf16x8 __attribute__((ext_vector_type(8)));
typedef unsigned int u32x4 __attribute__((ext_vector_type(4)));

__device__ __forceinline__ float sigmoidf_(float x){ return 1.f/(1.f+__expf(-x)); }
__device__ __forceinline__ float softplusf_(float x){ return fmaxf(x,0.f) + log1pf(__expf(-fabsf(x))); }
__device__ __forceinline__ uint32_t rotl32_(uint32_t x, int r){ return (x<<r)|(x>>(32-r)); }
__device__ __forceinline__ float bf2f(ushort_t u){ return __uint_as_float(((uint32_t)u)<<16); }
__device__ __forceinline__ ushort_t f2bf(float x){
  uint32_t u = __float_as_uint(x);
  uint32_t r = (u + 0x7FFFu + ((u>>16)&1u)) >> 16;
  return (ushort_t)r;
}

// async global->LDS, 16B per lane; LDS dest = wave-uniform base + lane*16
#define GLDS16(g, l) __builtin_amdgcn_global_load_lds( \
    (const __attribute__((address_space(1))) void*)(g), \
    (__attribute__((address_space(3))) void*)(l), 16, 0, 0)

// ---------------- eps = jax.random.normal(key(42), (128,2)) ----------------
__global__ void gen_eps_kernel(float* __restrict__ eps){
  int j = threadIdx.x; // 256
  const uint32_t k0 = 0u, k1 = 42u;
  const uint32_t ks2 = k0 ^ k1 ^ 0x1BD11BDAu;
  uint32_t x0 = 0u + k0;
  uint32_t x1 = (uint32_t)j + k1;
#define RND_(r) { x0 += x1; x1 = rotl32_(x1, r); x1 ^= x0; }
  RND_(13) RND_(15) RND_(26) RND_(6)  x0 += k1;  x1 += ks2 + 1u;
  RND_(17) RND_(29) RND_(16) RND_(24) x0 += ks2; x1 += k0 + 2u;
  RND_(13) RND_(15) RND_(26) RND_(6)  x0 += k0;  x1 += k1 + 3u;
  RND_(17) RND_(29) RND_(16) RND_(24) x0 += k1;  x1 += ks2 + 4u;
  RND_(13) RND_(15) RND_(26) RND_(6)  x0 += ks2; x1 += k0 + 5u;
#undef RND_
  uint32_t bits = x0 ^ x1;
  float f = __uint_as_float((bits >> 9) | 0x3f800000u) - 1.0f;
  float u = __fadd_rn(__fmul_rn(f, 1.99999994f), -0.99999994f);
  u = fmaxf(-0.99999994f, u);
  float w = -log1pf(-u*u);
  float p;
  if (w < 5.0f){
    w -= 2.5f;
    p = 2.81022636e-08f;
    p = fmaf(p, w, 3.43273939e-07f);
    p = fmaf(p, w, -3.5233877e-06f);
    p = fmaf(p, w, -4.39150654e-06f);
    p = fmaf(p, w, 0.00021858087f);
    p = fmaf(p, w, -0.00125372503f);
    p = fmaf(p, w, -0.00417768164f);
    p = fmaf(p, w, 0.246640727f);
    p = fmaf(p, w, 1.50140941f);
  } else {
    w = sqrtf(w) - 3.0f;
    p = -0.000200214257f;
    p = fmaf(p, w, 0.000100950558f);
    p = fmaf(p, w, 0.00134934322f);
    p = fmaf(p, w, -0.00367342844f);
    p = fmaf(p, w, 0.00573950773f);
    p = fmaf(p, w, -0.0076224613f);
    p = fmaf(p, w, 0.00943887047f);
    p = fmaf(p, w, 1.00167406f);
    p = fmaf(p, w, 2.83297682f);
  }
  eps[j] = 1.41421356237f * (p * u);
}

// ---------------- total_input_fea output (coalesced, NT stores: true output) ------
__global__ void tif_v2(const float* __restrict__ atom, const float* __restrict__ nbr,
                       const int* __restrict__ idx, float* __restrict__ out){
  int e0 = blockIdx.x*2048 + threadIdx.x;
#pragma unroll
  for (int i=0;i<8;++i){
    int e = e0 + i*256;
    int r = e/225, c = e - r*225;
    float v;
    if (c < 92)       v = atom[(r/12)*92 + c];
    else if (c < 184) v = atom[idx[r]*92 + (c-92)];
    else              v = nbr[(size_t)r*41 + (c-184)];
    __builtin_nontemporal_store(v, out + (size_t)e);
  }
}

// ---------------- embeddings (write bf16 masters) ----------------
__global__ void embed_atom_kernel(const float* __restrict__ atom, const float* __restrict__ W,
                                  const float* __restrict__ bias, ushort_t* __restrict__ a0){
  __shared__ float row[92];
  int i = blockIdx.x; int t = threadIdx.x; // 128
  if (t < 92) row[t] = atom[i*92+t];
  __syncthreads();
  float s = bias[t];
#pragma unroll
  for (int k=0;k<92;++k) s = fmaf(row[k], W[k*128+t], s);
  a0[(size_t)i*128+t] = f2bf(s);
}

__global__ void embed_bond_kernel(const float* __restrict__ nbr, const float* __restrict__ W,
                                  const float* __restrict__ bias, ushort_t* __restrict__ nb0){
  __shared__ float rows[4][41];
  int r0 = blockIdx.x*4; int t = threadIdx.x; // 256
  if (t < 164) rows[t/41][t%41] = nbr[(size_t)r0*41 + t];
  __syncthreads();
  int rr = t >> 6, c = t & 63;
  float s = bias[c];
#pragma unroll
  for (int k=0;k<41;++k) s = fmaf(rows[rr][k], W[k*64+c], s);
  nb0[(size_t)(r0+rr)*64 + c] = f2bf(s);
}

// ---------------- weight transpose (Wa+Wb fused) + stats zeroing ----------
__global__ void wtr2_kernel(const float* __restrict__ Wa, const float* __restrict__ Wb,
                            ushort_t* __restrict__ Wt, float* __restrict__ zstats){
  __shared__ ushort_t tile[32][33];
  if (blockIdx.x == 0 && blockIdx.y == 0){
#pragma unroll
    for (int k=0;k<4;++k) zstats[threadIdx.x + k*256] = 0.f;
  }
  int by = blockIdx.y;
  const float* W; int NO, o0, obase;
  if (by < 8){ W = Wa; NO = 256; o0 = by*32; obase = o0; }
  else       { W = Wb; NO = 128; o0 = (by-8)*32; obase = 256 + o0; }
  int k0 = blockIdx.x*32;
  int tx = threadIdx.x & 31, ty = threadIdx.x >> 5; // 256 thr
#pragma unroll
  for (int i = ty; i < 32; i += 8)
    tile[i][tx] = f2bf(W[(size_t)(k0+i)*NO + o0 + tx]);
  __syncthreads();
#pragma unroll
  for (int i = ty; i < 32; i += 8)
    Wt[(size_t)(obase+i)*320 + k0 + tx] = tile[tx][i];
}

// ---------------- MFMA conv GEMM v7 (cached stores; big stays L3-resident) ----
// BM=256 x BN=128 per block, 4 waves (each 64 rows x 128 cols, acc 4x8 f32x4).
// BK=32 double-buffered via global_load_lds. Output col-block-major [3][NM][128].
__launch_bounds__(256, 2)
__global__ void conv_gemm_v7(const ushort_t* __restrict__ a_bf, const ushort_t* __restrict__ nb_bf,
                             const int* __restrict__ idx, const ushort_t* __restrict__ Wt,
                             __half* __restrict__ O, float* __restrict__ sums){
  __shared__ ushort_t sm[34816];   // staging: As 2x8192 @0, Bs 2x4096 @16384; epilogue [256][136]
  __shared__ float sqred[256];     // 128 sum + 128 ssq (this col block)
  __shared__ int idxs[256];
  ushort_t* As = sm;
  ushort_t* Bs = sm + 16384;
  const int t = threadIdx.x;
  const int lane = t & 63;
  const int w = t >> 6;
  const int lm = lane & 15, lg = lane >> 4;
  const int row0 = blockIdx.x * 256;
  const int cb   = blockIdx.y;          // col-block 0..2
  const int col0 = cb * 128;
  __half* Ob = O + (size_t)cb * ((size_t)NM*128);

  idxs[t] = idx[row0 + t];
  sqred[t] = 0.f;

  auto stage = [&](int ks, int b_){
    ushort_t* Ad = As + b_*8192;
    ushort_t* Bd = Bs + b_*4096;
#pragma unroll
    for (int i=0;i<4;++i){
      int e = t + i*256;              // 0..1023
      int r = e >> 2, ch = e & 3;
      const ushort_t* ga;
      if (ks < 4)      ga = a_bf + (size_t)((row0+r)/12)*128 + ks*32 + ch*8;
      else if (ks < 8) ga = a_bf + (size_t)idxs[r]*128 + (ks-4)*32 + ch*8;
      else             ga = nb_bf + (size_t)(row0+r)*64 + (ks-8)*32 + ch*8;
      GLDS16(ga, Ad + e*8);
    }
#pragma unroll
    for (int i=0;i<2;++i){
      int e = t + i*256;              // 0..511
      int r = e >> 2, ch = e & 3;
      GLDS16(Wt + (size_t)(col0+r)*320 + ks*32 + ch*8, Bd + e*8);
    }
  };

  stage(0, 0);
  __syncthreads();   // drains vmcnt (buf0 ready) + makes idxs visible

  f32x4 acc[4][8] = {};
  int buf = 0;
#pragma unroll
  for (int ks = 0; ks < 10; ++ks){
    if (ks < 9) stage(ks+1, buf^1);
    const ushort_t* Ab = As + buf*8192;
    const ushort_t* Bb = Bs + buf*4096;
    bf16x8 afr[4], bfr[8];
#pragma unroll
    for (int fm=0; fm<4; ++fm)
      afr[fm] = *(const bf16x8*)&Ab[(w*64 + fm*16 + lm)*32 + lg*8];
#pragma unroll
    for (int fn=0; fn<8; ++fn)
      bfr[fn] = *(const bf16x8*)&Bb[(fn*16 + lm)*32 + lg*8];
#pragma unroll
    for (int fm=0; fm<4; ++fm)
#pragma unroll
      for (int fn=0; fn<8; ++fn)
        acc[fm][fn] = __builtin_amdgcn_mfma_f32_16x16x32_bf16(afr[fm], bfr[fn], acc[fm][fn], 0, 0, 0);
    __syncthreads();
    buf ^= 1;
  }

  // epilogue: stage f16 tile [256][136] in LDS, then coalesced CACHED stores
  // (big is consumed by apply kernels within the pass -> keep it in L2/L3)
#pragma unroll
  for (int fm=0; fm<4; ++fm){
    int rw = w*64 + fm*16 + lg*4;
#pragma unroll
    for (int fn=0; fn<8; ++fn){
      int cl = fn*16 + lm;
#pragma unroll
      for (int j=0; j<4; ++j){
        __half h = __float2half(acc[fm][fn][j]);
        sm[(rw+j)*136 + cl] = *(ushort_t*)&h;
      }
    }
  }
  __syncthreads();

  const int cch = t & 15, rb = t >> 4;
  float s1[8] = {0.f,0.f,0.f,0.f,0.f,0.f,0.f,0.f};
  float s2[8] = {0.f,0.f,0.f,0.f,0.f,0.f,0.f,0.f};
#pragma unroll
  for (int i=0; i<16; ++i){
    int row = rb + i*16;
    u32x4 v = *(const u32x4*)&sm[row*136 + cch*8];
    *(u32x4*)(Ob + (size_t)(row0+row)*128 + cch*8) = v;
    const __half* hp = (const __half*)&v;
#pragma unroll
    for (int k=0;k<8;++k){
      float f = __half2float(hp[k]);
      s1[k] += f;
      s2[k] += f*f;
    }
  }
#pragma unroll
  for (int k=0;k<8;++k){
    atomicAdd(&sqred[cch*8+k], s1[k]);
    atomicAdd(&sqred[128+cch*8+k], s2[k]);
  }
  __syncthreads();
  if (t < 128){
    atomicAdd(&sums[col0 + t], sqred[t]);          // sum
    atomicAdd(&sums[384 + col0 + t], sqred[128+t]);// ssq
  }
}

// ---------------- conv apply kernels (BN from sum/ssq; stats fused) ----
// ga lives in O0 (cols 0-127) and O1 (cols 128-255), each [NM][128]
__global__ void apply_ga_v4(const __half* __restrict__ O0, const __half* __restrict__ O1,
                            const float* __restrict__ sums,
                            const float* __restrict__ g1a, const float* __restrict__ b1a,
                            float* __restrict__ asum, float* __restrict__ st){
  __shared__ float red[256];
  int t = threadIdx.x;           // 256 = 16 atoms x 16 col-chunks
  red[t] = 0.f;
  int c8 = t & 15, al = t >> 4;
  int i = blockIdx.x*16 + al;
  int c0 = c8*8;
  float gf[8], bfv[8], gc[8], bcv[8];
#pragma unroll
  for (int k=0;k<8;++k){
    int c = c0+k;
    float mf = sums[c]*(1.f/NM);
    float rf = rsqrtf(sums[384+c]*(1.f/NM) - mf*mf + 1e-5f);
    gf[k]  = g1a[c]*rf;      bfv[k] = b1a[c] - mf*gf[k];
    float mc = sums[c+128]*(1.f/NM);
    float rc = rsqrtf(sums[384+c+128]*(1.f/NM) - mc*mc + 1e-5f);
    gc[k]  = g1a[c+128]*rc;  bcv[k] = b1a[c+128] - mc*gc[k];
  }
  float s[8] = {0.f,0.f,0.f,0.f,0.f,0.f,0.f,0.f};
  size_t base = (size_t)i*12*128;
#pragma unroll
  for (int j=0;j<12;++j){
    u32x4 vf = *(const u32x4*)(O0 + base + j*128 + c0);
    u32x4 vc = *(const u32x4*)(O1 + base + j*128 + c0);
    const __half* hf = (const __half*)&vf;
    const __half* hc = (const __half*)&vc;
#pragma unroll
    for (int k=0;k<8;++k)
      s[k] += sigmoidf_(fmaf(__half2float(hf[k]), gf[k], bfv[k]))
            * softplusf_(fmaf(__half2float(hc[k]), gc[k], bcv[k]));
  }
  float* dst = asum + (size_t)i*128 + c0;
  __syncthreads();               // red zero visible before cross-thread atomics
#pragma unroll
  for (int k=0;k<8;++k){
    dst[k] = s[k];
    atomicAdd(&red[c0+k], s[k]);
    atomicAdd(&red[128+c0+k], s[k]*s[k]);
  }
  __syncthreads();
  atomicAdd(&st[t], red[t]);     // st[0..127] sum, st[128..255] ssq
}

// apply_out1 with inline BN2 stats from st
__global__ void apply_out1_v3(ushort_t* __restrict__ a0, const float* __restrict__ asum,
                              const float* __restrict__ st, const float* __restrict__ g2a,
                              const float* __restrict__ b2a){
  int e = blockIdx.x*256 + threadIdx.x; // n*128
  int c = e & 127;
  float m  = st[c]*(1.f/N_ATOM);
  float var = st[128+c]*(1.f/N_ATOM) - m*m;
  float rs = rsqrtf(var + 1e-5f);
  float g = g2a[c]*rs;
  float b = b2a[c] - m*g;
  a0[e] = f2bf(softplusf_(bf2f(a0[e]) + fmaf(asum[e], g, b)));
}

// gb lives in O2, [NM][128] (filter 0-63 -> global col 256+c, core 64-127 -> 320+c)
__global__ void apply_gb_v4(const __half* __restrict__ O2, ushort_t* __restrict__ nb,
                            const float* __restrict__ sums, const float* __restrict__ g1b,
                            const float* __restrict__ b1b){
  int t = threadIdx.x;          // 256 = 32 rows x 8 col-chunks
  int c8 = t & 7, rloc = t >> 3;
  int r = blockIdx.x*32 + rloc;
  int c0 = c8*8;
  float gf[8], bfv[8], gc[8], bcv[8];
#pragma unroll
  for (int k=0;k<8;++k){
    int c = c0+k;
    float mf = sums[256+c]*(1.f/NM);
    float rf = rsqrtf(sums[384+256+c]*(1.f/NM) - mf*mf + 1e-5f);
    gf[k]  = g1b[c]*rf;      bfv[k] = b1b[c] - mf*gf[k];
    float mc = sums[256+64+c]*(1.f/NM);
    float rc = rsqrtf(sums[384+256+64+c]*(1.f/NM) - mc*mc + 1e-5f);
    gc[k]  = g1b[c+64]*rc;   bcv[k] = b1b[c+64] - mc*gc[k];
  }
  size_t gbase = (size_t)r*128;
  u32x4 vf = *(const u32x4*)(O2 + gbase + c0);
  u32x4 vc = *(const u32x4*)(O2 + gbase + 64 + c0);
  const __half* hf = (const __half*)&vf;
  const __half* hc = (const __half*)&vc;
  ushort_t* np = nb + (size_t)r*64 + c0;
  u32x4 old = *(const u32x4*)np;
  const ushort_t* op = (const ushort_t*)&old;
  u32x4 outv;
  ushort_t* ov = (ushort_t*)&outv;
#pragma unroll
  for (int k=0;k<8;++k){
    float x = bf2f(op[k]) + sigmoidf_(fmaf(__half2float(hf[k]), gf[k], bfv[k]))
                          * softplusf_(fmaf(__half2float(hc[k]), gc[k], bcv[k]));
    ov[k] = f2bf(softplusf_(x));
  }
  *(u32x4*)np = outv;
}

// ---------------- pooling / VAE / decode ----------------
__global__ void pool_a_kernel(const ushort_t* __restrict__ a, float* __restrict__ pooled){
  int b = blockIdx.x; int c = threadIdx.x; // 128
  float s = 0.f;
  for (int i=0;i<128;++i) s += bf2f(a[(size_t)((b<<7)+i)*128 + c]);
  pooled[b*896 + c] = softplusf_(s * (1.f/128.f));
}

__launch_bounds__(768)
__global__ void pool_n_kernel(const ushort_t* __restrict__ nb, float* __restrict__ pooled){
  int b = blockIdx.x; int t = threadIdx.x; // 768
  float s = 0.f;
  for (int i=0;i<128;++i) s += bf2f(nb[(size_t)((b<<7)+i)*768 + t]);
  pooled[b*896 + 128 + t] = softplusf_(s * (1.f/128.f));
}

__global__ void muz_kernel(const float* __restrict__ pooled, const float* __restrict__ muW,
                           const float* __restrict__ mub, const float* __restrict__ lvW,
                           const float* __restrict__ lvb, const float* __restrict__ eps,
                           float* __restrict__ out_mu, float* __restrict__ out_lv,
                           float* __restrict__ out_z, float* __restrict__ zws){
  int t = threadIdx.x; // 256 -> (b,l)
  int b = t >> 1, l = t & 1;
  const float* pr = pooled + b*896;
  float smu = mub[l], slv = lvb[l];
  for (int k=0;k<896;++k){
    float p = pr[k];
    smu = fmaf(p, muW[k*2+l], smu);
    slv = fmaf(p, lvW[k*2+l], slv);
  }
  out_mu[t] = smu; out_lv[t] = slv;
  float zv = fmaf(eps[t], __expf(0.5f*slv), smu);
  out_z[t] = zv; zws[t] = zv;
}

__global__ void compute_f_kernel(const float* __restrict__ zws, const float* __restrict__ decW,
                                 const float* __restrict__ decb, const float* __restrict__ pooled,
                                 float* __restrict__ f){
  int b = blockIdx.x;
  float z0 = zws[b*2], z1 = zws[b*2+1];
  for (int k = threadIdx.x; k < 896; k += 256){
    float zd = fmaf(z0, decW[k], fmaf(z1, decW[896+k], decb[k]));
    f[b*896+k] = zd / pooled[b*896+k];
  }
}

__global__ void dec_atom_kernel(ushort_t* __restrict__ a, const float* __restrict__ f){
  int e = blockIdx.x*256+threadIdx.x; // n*128
  int c = e & 127; int b = e >> 14;
  a[e] = f2bf(softplusf_(bf2f(a[e]) * f[b*896 + c]));
}

__global__ void dec_bond_kernel(ushort_t* __restrict__ nb, const float* __restrict__ f){
  int i = blockIdx.x; int off = blockIdx.y*256 + threadIdx.x; // off < 768
  int b = i >> 7;
  size_t e = (size_t)i*768 + off;
  nb[e] = f2bf(softplusf_(bf2f(nb[e]) * f[b*896 + 128 + off]));
}

// ---------------- final embeddings ----------------
__global__ void embed_atom2_kernel(const ushort_t* __restrict__ a, const float* __restrict__ W,
                                   const float* __restrict__ bias, float* __restrict__ za2){
  __shared__ float row[128];
  int i = blockIdx.x; int t = threadIdx.x; // 128
  row[t] = bf2f(a[(size_t)i*128+t]);
  __syncthreads();
  if (t < 92){
    float s = bias[t];
#pragma unroll
    for (int k=0;k<128;++k) s = fmaf(row[k], W[k*92+t], s);
    za2[(size_t)i*92+t] = sigmoidf_(s);
  }
}

__global__ void bproj_kernel(const ushort_t* __restrict__ nb, const float* __restrict__ W,
                             const float* __restrict__ bias, float* __restrict__ bp){
  __shared__ float Ws[64][41];
  __shared__ float rows[6][64];
  int t = threadIdx.x; // 256
  for (int e=t; e<64*41; e+=256) Ws[e/41][e%41] = W[e];
  int r0 = blockIdx.x*6;
  for (int e=t; e<6*64; e+=256){
    int rr = e>>6, c = e&63;
    rows[rr][c] = bf2f(nb[(size_t)(r0+rr)*64 + c]);
  }
  __syncthreads();
  if (t < 246){
    int rr = t/41, o = t - rr*41;
    float s = bias[o];
#pragma unroll
    for (int k=0;k<64;++k) s = fmaf(rows[rr][k], Ws[k][o], s);
    bp[(size_t)(r0+rr)*41 + o] = sigmoidf_(s);
  }
}

__global__ void zdec_v2(const float* __restrict__ za2, const float* __restrict__ bp,
                        const int* __restrict__ idx, float* __restrict__ out){
  int e0 = blockIdx.x*2048 + threadIdx.x;
#pragma unroll
  for (int i=0;i<8;++i){
    int e = e0 + i*256;
    int r = e/225, c = e - r*225;
    float v;
    if (c < 92)       v = za2[(size_t)(r/12)*92 + c];
    else if (c < 184) v = za2[(size_t)idx[r]*92 + (c-92)];
    else              v = bp[(size_t)r*41 + (c-184)];
    __builtin_nontemporal_store(v, out + (size_t)e);
  }
}

// ---------------- host side ----------------
struct WsPlan {
  ushort_t *Abf, *NBbf, *Wt;
  __half* big;
  float *asum, *pooled, *fbuf, *zws, *eps, *sums, *st;
};

static void conv_pass(const WsPlan& P, const int* idx,
                      const float* Wa, const float* Wb,
                      const float* g1a, const float* b1a, const float* g1b, const float* b1b,
                      const float* g2a, const float* b2a,
                      hipStream_t stream){
  wtr2_kernel<<<dim3(10,12), 256, 0, stream>>>(Wa, Wb, P.Wt, P.sums);
  conv_gemm_v7<<<dim3(NM/256, 3), 256, 0, stream>>>(P.Abf, P.NBbf, idx, P.Wt, P.big, P.sums);
  const __half* O0 = P.big;
  const __half* O1 = P.big + (size_t)NM*128;
  const __half* O2 = P.big + (size_t)NM*256;
  apply_ga_v4<<<N_ATOM/16, 256, 0, stream>>>(O0, O1, P.sums, g1a, b1a, P.asum, P.st);
  apply_out1_v3<<<N_ATOM*128/256, 256, 0, stream>>>(P.Abf, P.asum, P.st, g2a, b2a);
  apply_gb_v4<<<NM/32, 256, 0, stream>>>(O2, P.NBbf, P.sums, g1b, b1b);
}

extern "C" void kernel_launch(void* const* d_in, const int* in_sizes, int n_in,
                              void* d_out, int out_size, void* d_ws, size_t ws_size,
                              hipStream_t stream) {
  (void)in_sizes; (void)n_in; (void)out_size; (void)ws_size;
  const float* atom_fea   = (const float*)d_in[0];
  const float* nbr_fea    = (const float*)d_in[1];
  const int*   idx        = (const int*)d_in[2];
  const float* emb_atom_W = (const float*)d_in[4];
  const float* emb_atom_b = (const float*)d_in[5];
  const float* emb_bond_W = (const float*)d_in[6];
  const float* emb_bond_b = (const float*)d_in[7];
  const float* emb_atom2_W= (const float*)d_in[8];
  const float* emb_atom2_b= (const float*)d_in[9];
  const float* emb_bond2_W= (const float*)d_in[10];
  const float* emb_bond2_b= (const float*)d_in[11];
  const float* mu_W       = (const float*)d_in[12];
  const float* mu_b       = (const float*)d_in[13];
  const float* lv_W       = (const float*)d_in[14];
  const float* lv_b       = (const float*)d_in[15];
  const float* dec_W      = (const float*)d_in[16];
  const float* dec_b      = (const float*)d_in[17];
  const float* c1_Wa  = (const float*)d_in[18];
  const float* c1_Wb  = (const float*)d_in[19];
  const float* c1_g1a = (const float*)d_in[20];
  const float* c1_b1a = (const float*)d_in[21];
  const float* c1_g1b = (const float*)d_in[22];
  const float* c1_b1b = (const float*)d_in[23];
  const float* c1_g2a = (const float*)d_in[24];
  const float* c1_b2a = (const float*)d_in[25];
  const float* c2_Wa  = (const float*)d_in[26];
  const float* c2_Wb  = (const float*)d_in[27];
  const float* c2_g1a = (const float*)d_in[28];
  const float* c2_b1a = (const float*)d_in[29];
  const float* c2_g1b = (const float*)d_in[30];
  const float* c2_b1b = (const float*)d_in[31];
  const float* c2_g2a = (const float*)d_in[32];
  const float* c2_b2a = (const float*)d_in[33];

  float* out = (float*)d_out;

  WsPlan P;
  char* w = (char*)d_ws;
  auto alloc = [&](size_t bytes) -> char* {
    char* p = w; w += (bytes + 255) & ~(size_t)255; return p;
  };
  P.Abf    = (ushort_t*)alloc((size_t)N_ATOM*128*2);
  P.NBbf   = (ushort_t*)alloc((size_t)NM*64*2);
  P.big    = (__half*)  alloc((size_t)NM*384*2);
  P.asum   = (float*)   alloc((size_t)N_ATOM*128*4);
  P.pooled = (float*)   alloc(114688*4);
  P.fbuf   = (float*)   alloc(114688*4);
  P.Wt     = (ushort_t*)alloc(384*320*2);
  P.zws    = (float*)   alloc(256*4);
  P.eps    = (float*)   alloc(256*4);
  P.sums   = (float*)   alloc(1024*4);   // sums[768] + st[256] contiguous (zeroed in wtr2)
  P.st     = P.sums + 768;
  float* za2   = P.asum;                 // reuse after conv stacks
  float* bproj = (float*)P.big;          // reuse big in the final phase

  gen_eps_kernel<<<1, 256, 0, stream>>>(P.eps);
  tif_v2<<<21600, 256, 0, stream>>>(atom_fea, nbr_fea, idx, out + O_TIF);
  embed_atom_kernel<<<N_ATOM, 128, 0, stream>>>(atom_fea, emb_atom_W, emb_atom_b, P.Abf);
  embed_bond_kernel<<<NM/4, 256, 0, stream>>>(nbr_fea, emb_bond_W, emb_bond_b, P.NBbf);

  for (int L=0; L<3; ++L){
    conv_pass(P, idx, c1_Wa + (size_t)L*320*256, c1_Wb + (size_t)L*320*128,
              c1_g1a+L*256, c1_b1a+L*256, c1_g1b+L*128, c1_b1b+L*128,
              c1_g2a+L*128, c1_b2a+L*128, stream);
  }

  pool_a_kernel<<<NCRY, 128, 0, stream>>>(P.Abf, P.pooled);
  pool_n_kernel<<<NCRY, 768, 0, stream>>>(P.NBbf, P.pooled);
  muz_kernel<<<1, 256, 0, stream>>>(P.pooled, mu_W, mu_b, lv_W, lv_b, P.eps,
                                    out + O_MU, out + O_LV, out + O_Z, P.zws);
  compute_f_kernel<<<NCRY, 256, 0, stream>>>(P.zws, dec_W, dec_b, P.pooled, P.fbuf);
  dec_atom_kernel<<<N_ATOM*128/256, 256, 0, stream>>>(P.Abf, P.fbuf);
  dim3 gdb(N_ATOM, 3);
  dec_bond_kernel<<<gdb, 256, 0, stream>>>(P.NBbf, P.fbuf);

  for (int L=0; L<3; ++L){
    conv_pass(P, idx, c2_Wa + (size_t)L*320*256, c2_Wb + (size_t)L*320*128,
              c2_g1a+L*256, c2_b1a+L*256, c2_g1b+L*128, c2_b1b+L*128,
              c2_g2a+L*128, c2_b2a+L*128, stream);
  }

  embed_atom2_kernel<<<N_ATOM, 128, 0, stream>>>(P.Abf, emb_atom2_W, emb_atom2_b, za2);
  bproj_kernel<<<NM/6, 256, 0, stream>>>(P.NBbf, emb_bond2_W, emb_bond2_b, bproj);
  zdec_v2<<<21600, 256, 0, stream>>>(za2, bproj, idx, out + O_ZDEC);
}

// Round 11
// 2591.021 us; speedup vs baseline: 1.0469x; 1.0469x over previous
//
#include <hip/hip_runtime.h>
#include <hip/hip_bf16.h>
#include <hip/hip_fp16.h>
#include <cstdint>
#include <cstddef>

// ---------------- constants ----------------
#define N_ATOM 16384
#define M_NBR  12
#define NCRY   128
#define NM     (N_ATOM*M_NBR) // 196608

// output offsets (floats)
#define O_ZDEC 0
#define O_MU   44236800
#define O_LV   44237056
#define O_Z    44237312
#define O_TIF  44237568

typedef unsigned short ushort_t;
typedef float f32x4 __attribute__((ext_vector_type(4)));
typedef short bf16x8 __attribute__((ext_vector_type(8)));
typedef unsigned int u32x4 __attribute__((ext_vector_type(4)));

__device__ __forceinline__ float sigmoidf_(float x){ return 1.f/(1.f+__expf(-x)); }
__device__ __forceinline__ float softplusf_(float x){ return fmaxf(x,0.f) + log1pf(__expf(-fabsf(x))); }
__device__ __forceinline__ uint32_t rotl32_(uint32_t x, int r){ return (x<<r)|(x>>(32-r)); }
__device__ __forceinline__ float bf2f(ushort_t u){ return __uint_as_float(((uint32_t)u)<<16); }
__device__ __forceinline__ ushort_t f2bf(float x){
  uint32_t u = __float_as_uint(x);
  uint32_t r = (u + 0x7FFFu + ((u>>16)&1u)) >> 16;
  return (ushort_t)r;
}

// async global->LDS, 16B per lane; LDS dest = wave-uniform base + lane*16
#define GLDS16(g, l) __builtin_amdgcn_global_load_lds( \
    (const __attribute__((address_space(1))) void*)(g), \
    (__attribute__((address_space(3))) void*)(l), 16, 0, 0)

// ---------------- eps = jax.random.normal(key(42), (128,2)) ----------------
__global__ void gen_eps_kernel(float* __restrict__ eps){
  int j = threadIdx.x; // 256
  const uint32_t k0 = 0u, k1 = 42u;
  const uint32_t ks2 = k0 ^ k1 ^ 0x1BD11BDAu;
  uint32_t x0 = 0u + k0;
  uint32_t x1 = (uint32_t)j + k1;
#define RND_(r) { x0 += x1; x1 = rotl32_(x1, r); x1 ^= x0; }
  RND_(13) RND_(15) RND_(26) RND_(6)  x0 += k1;  x1 += ks2 + 1u;
  RND_(17) RND_(29) RND_(16) RND_(24) x0 += ks2; x1 += k0 + 2u;
  RND_(13) RND_(15) RND_(26) RND_(6)  x0 += k0;  x1 += k1 + 3u;
  RND_(17) RND_(29) RND_(16) RND_(24) x0 += k1;  x1 += ks2 + 4u;
  RND_(13) RND_(15) RND_(26) RND_(6)  x0 += ks2; x1 += k0 + 5u;
#undef RND_
  uint32_t bits = x0 ^ x1;
  float f = __uint_as_float((bits >> 9) | 0x3f800000u) - 1.0f;
  float u = __fadd_rn(__fmul_rn(f, 1.99999994f), -0.99999994f);
  u = fmaxf(-0.99999994f, u);
  float w = -log1pf(-u*u);
  float p;
  if (w < 5.0f){
    w -= 2.5f;
    p = 2.81022636e-08f;
    p = fmaf(p, w, 3.43273939e-07f);
    p = fmaf(p, w, -3.5233877e-06f);
    p = fmaf(p, w, -4.39150654e-06f);
    p = fmaf(p, w, 0.00021858087f);
    p = fmaf(p, w, -0.00125372503f);
    p = fmaf(p, w, -0.00417768164f);
    p = fmaf(p, w, 0.246640727f);
    p = fmaf(p, w, 1.50140941f);
  } else {
    w = sqrtf(w) - 3.0f;
    p = -0.000200214257f;
    p = fmaf(p, w, 0.000100950558f);
    p = fmaf(p, w, 0.00134934322f);
    p = fmaf(p, w, -0.00367342844f);
    p = fmaf(p, w, 0.00573950773f);
    p = fmaf(p, w, -0.0076224613f);
    p = fmaf(p, w, 0.00943887047f);
    p = fmaf(p, w, 1.00167406f);
    p = fmaf(p, w, 2.83297682f);
  }
  eps[j] = 1.41421356237f * (p * u);
}

// ---------------- total_input_fea output (coalesced, NT stores: true output) ------
__global__ void tif_v2(const float* __restrict__ atom, const float* __restrict__ nbr,
                       const int* __restrict__ idx, float* __restrict__ out){
  int e0 = blockIdx.x*2048 + threadIdx.x;
#pragma unroll
  for (int i=0;i<8;++i){
    int e = e0 + i*256;
    int r = e/225, c = e - r*225;
    float v;
    if (c < 92)       v = atom[(r/12)*92 + c];
    else if (c < 184) v = atom[idx[r]*92 + (c-92)];
    else              v = nbr[(size_t)r*41 + (c-184)];
    __builtin_nontemporal_store(v, out + (size_t)e);
  }
}

// ---------------- embeddings (write bf16 masters) ----------------
__global__ void embed_atom_kernel(const float* __restrict__ atom, const float* __restrict__ W,
                                  const float* __restrict__ bias, ushort_t* __restrict__ a0){
  __shared__ float row[92];
  int i = blockIdx.x; int t = threadIdx.x; // 128
  if (t < 92) row[t] = atom[i*92+t];
  __syncthreads();
  float s = bias[t];
#pragma unroll
  for (int k=0;k<92;++k) s = fmaf(row[k], W[k*128+t], s);
  a0[(size_t)i*128+t] = f2bf(s);
}

__global__ void embed_bond_kernel(const float* __restrict__ nbr, const float* __restrict__ W,
                                  const float* __restrict__ bias, ushort_t* __restrict__ nb0){
  __shared__ float rows[4][41];
  int r0 = blockIdx.x*4; int t = threadIdx.x; // 256
  if (t < 164) rows[t/41][t%41] = nbr[(size_t)r0*41 + t];
  __syncthreads();
  int rr = t >> 6, c = t & 63;
  float s = bias[c];
#pragma unroll
  for (int k=0;k<41;++k) s = fmaf(rows[rr][k], W[k*64+c], s);
  nb0[(size_t)(r0+rr)*64 + c] = f2bf(s);
}

// ---------------- weight transpose (Wa+Wb fused) + stats zeroing ----------
__global__ void wtr2_kernel(const float* __restrict__ Wa, const float* __restrict__ Wb,
                            ushort_t* __restrict__ Wt, float* __restrict__ zstats){
  __shared__ ushort_t tile[32][33];
  if (blockIdx.x == 0 && blockIdx.y == 0){
#pragma unroll
    for (int k=0;k<4;++k) zstats[threadIdx.x + k*256] = 0.f;
  }
  int by = blockIdx.y;
  const float* W; int NO, o0, obase;
  if (by < 8){ W = Wa; NO = 256; o0 = by*32; obase = o0; }
  else       { W = Wb; NO = 128; o0 = (by-8)*32; obase = 256 + o0; }
  int k0 = blockIdx.x*32;
  int tx = threadIdx.x & 31, ty = threadIdx.x >> 5; // 256 thr
#pragma unroll
  for (int i = ty; i < 32; i += 8)
    tile[i][tx] = f2bf(W[(size_t)(k0+i)*NO + o0 + tx]);
  __syncthreads();
#pragma unroll
  for (int i = ty; i < 32; i += 8)
    Wt[(size_t)(obase+i)*320 + k0 + tx] = tile[tx][i];
}

// ---------------- MFMA conv GEMM v8: counted-vmcnt software pipeline ----
// BM=256 x BN=128 per block, 4 waves (each 64 rows x 128 cols, acc 4x8 f32x4).
// BK=32 double-buffered via global_load_lds (6 loads/thread/stage).
// Per K-step: issue next stage -> s_waitcnt vmcnt(6) -> s_barrier -> MFMA ->
// lgkmcnt(0)+sched_barrier -> s_barrier. Loads stay in flight across barriers.
// Output col-block-major [3][NM][128], NT stores (R9-proven).
__launch_bounds__(256, 2)
__global__ void conv_gemm_v8(const ushort_t* __restrict__ a_bf, const ushort_t* __restrict__ nb_bf,
                             const int* __restrict__ idx, const ushort_t* __restrict__ Wt,
                             __half* __restrict__ O, float* __restrict__ sums){
  __shared__ ushort_t sm[34816];   // staging: As 2x8192 @0, Bs 2x4096 @16384; epilogue [256][136]
  __shared__ float sqred[256];     // 128 sum + 128 ssq (this col block)
  __shared__ int idxs[256];
  ushort_t* As = sm;
  ushort_t* Bs = sm + 16384;
  const int t = threadIdx.x;
  const int lane = t & 63;
  const int w = t >> 6;
  const int lm = lane & 15, lg = lane >> 4;
  const int row0 = blockIdx.x * 256;
  const int cb   = blockIdx.y;          // col-block 0..2
  const int col0 = cb * 128;
  __half* Ob = O + (size_t)cb * ((size_t)NM*128);

  idxs[t] = idx[row0 + t];   // first consumed by stage(4) -> many barriers later
  sqred[t] = 0.f;

  auto stage = [&](int ks, int b_){
    ushort_t* Ad = As + b_*8192;
    ushort_t* Bd = Bs + b_*4096;
#pragma unroll
    for (int i=0;i<4;++i){
      int e = t + i*256;              // 0..1023
      int r = e >> 2, ch = e & 3;
      const ushort_t* ga;
      if (ks < 4)      ga = a_bf + (size_t)((row0+r)/12)*128 + ks*32 + ch*8;
      else if (ks < 8) ga = a_bf + (size_t)idxs[r]*128 + (ks-4)*32 + ch*8;
      else             ga = nb_bf + (size_t)(row0+r)*64 + (ks-8)*32 + ch*8;
      GLDS16(ga, Ad + e*8);
    }
#pragma unroll
    for (int i=0;i<2;++i){
      int e = t + i*256;              // 0..511
      int r = e >> 2, ch = e & 3;
      GLDS16(Wt + (size_t)(col0+r)*320 + ks*32 + ch*8, Bd + e*8);
    }
  };

  stage(0, 0);                        // batch 0 in flight

  f32x4 acc[4][8] = {};
  int buf = 0;
#pragma unroll
  for (int ks = 0; ks < 10; ++ks){
    if (ks < 9){
      stage(ks+1, buf^1);             // batch ks+1 in flight (6 more)
      asm volatile("s_waitcnt vmcnt(6)" ::: "memory");  // batch ks landed (mine)
    } else {
      asm volatile("s_waitcnt vmcnt(0)" ::: "memory");  // final batch landed
    }
    __builtin_amdgcn_s_barrier();     // all waves' batch ks landed
    __builtin_amdgcn_sched_barrier(0);
    const ushort_t* Ab = As + buf*8192;
    const ushort_t* Bb = Bs + buf*4096;
    bf16x8 afr[4], bfr[8];
#pragma unroll
    for (int fm=0; fm<4; ++fm)
      afr[fm] = *(const bf16x8*)&Ab[(w*64 + fm*16 + lm)*32 + lg*8];
#pragma unroll
    for (int fn=0; fn<8; ++fn)
      bfr[fn] = *(const bf16x8*)&Bb[(fn*16 + lm)*32 + lg*8];
#pragma unroll
    for (int fm=0; fm<4; ++fm)
#pragma unroll
      for (int fn=0; fn<8; ++fn)
        acc[fm][fn] = __builtin_amdgcn_mfma_f32_16x16x32_bf16(afr[fm], bfr[fn], acc[fm][fn], 0, 0, 0);
    asm volatile("s_waitcnt lgkmcnt(0)" ::: "memory");  // my ds_reads of buf done
    __builtin_amdgcn_sched_barrier(0);                   // rule #18 fence
    __builtin_amdgcn_s_barrier();     // all waves done reading buf -> safe to overwrite
    buf ^= 1;
  }

  // epilogue: stage f16 tile [256][136] in LDS, then coalesced NT stores + sum/ssq
#pragma unroll
  for (int fm=0; fm<4; ++fm){
    int rw = w*64 + fm*16 + lg*4;
#pragma unroll
    for (int fn=0; fn<8; ++fn){
      int cl = fn*16 + lm;
#pragma unroll
      for (int j=0; j<4; ++j){
        __half h = __float2half(acc[fm][fn][j]);
        sm[(rw+j)*136 + cl] = *(ushort_t*)&h;
      }
    }
  }
  __syncthreads();

  const int cch = t & 15, rb = t >> 4;
  float s1[8] = {0.f,0.f,0.f,0.f,0.f,0.f,0.f,0.f};
  float s2[8] = {0.f,0.f,0.f,0.f,0.f,0.f,0.f,0.f};
#pragma unroll
  for (int i=0; i<16; ++i){
    int row = rb + i*16;
    u32x4 v = *(const u32x4*)&sm[row*136 + cch*8];
    __builtin_nontemporal_store(v, (u32x4*)(Ob + (size_t)(row0+row)*128 + cch*8));
    const __half* hp = (const __half*)&v;
#pragma unroll
    for (int k=0;k<8;++k){
      float f = __half2float(hp[k]);
      s1[k] += f;
      s2[k] += f*f;
    }
  }
#pragma unroll
  for (int k=0;k<8;++k){
    atomicAdd(&sqred[cch*8+k], s1[k]);
    atomicAdd(&sqred[128+cch*8+k], s2[k]);
  }
  __syncthreads();
  if (t < 128){
    atomicAdd(&sums[col0 + t], sqred[t]);          // sum
    atomicAdd(&sums[384 + col0 + t], sqred[128+t]);// ssq
  }
}

// ---------------- conv apply kernels (BN from sum/ssq; stats fused) ----
// ga lives in O0 (cols 0-127) and O1 (cols 128-255), each [NM][128]
__global__ void apply_ga_v4(const __half* __restrict__ O0, const __half* __restrict__ O1,
                            const float* __restrict__ sums,
                            const float* __restrict__ g1a, const float* __restrict__ b1a,
                            float* __restrict__ asum, float* __restrict__ st){
  __shared__ float red[256];
  int t = threadIdx.x;           // 256 = 16 atoms x 16 col-chunks
  red[t] = 0.f;
  int c8 = t & 15, al = t >> 4;
  int i = blockIdx.x*16 + al;
  int c0 = c8*8;
  float gf[8], bfv[8], gc[8], bcv[8];
#pragma unroll
  for (int k=0;k<8;++k){
    int c = c0+k;
    float mf = sums[c]*(1.f/NM);
    float rf = rsqrtf(sums[384+c]*(1.f/NM) - mf*mf + 1e-5f);
    gf[k]  = g1a[c]*rf;      bfv[k] = b1a[c] - mf*gf[k];
    float mc = sums[c+128]*(1.f/NM);
    float rc = rsqrtf(sums[384+c+128]*(1.f/NM) - mc*mc + 1e-5f);
    gc[k]  = g1a[c+128]*rc;  bcv[k] = b1a[c+128] - mc*gc[k];
  }
  float s[8] = {0.f,0.f,0.f,0.f,0.f,0.f,0.f,0.f};
  size_t base = (size_t)i*12*128;
#pragma unroll
  for (int j=0;j<12;++j){
    u32x4 vf = __builtin_nontemporal_load((const u32x4*)(O0 + base + j*128 + c0));
    u32x4 vc = __builtin_nontemporal_load((const u32x4*)(O1 + base + j*128 + c0));
    const __half* hf = (const __half*)&vf;
    const __half* hc = (const __half*)&vc;
#pragma unroll
    for (int k=0;k<8;++k)
      s[k] += sigmoidf_(fmaf(__half2float(hf[k]), gf[k], bfv[k]))
            * softplusf_(fmaf(__half2float(hc[k]), gc[k], bcv[k]));
  }
  float* dst = asum + (size_t)i*128 + c0;
  __syncthreads();               // red zero visible before cross-thread atomics
#pragma unroll
  for (int k=0;k<8;++k){
    dst[k] = s[k];
    atomicAdd(&red[c0+k], s[k]);
    atomicAdd(&red[128+c0+k], s[k]*s[k]);
  }
  __syncthreads();
  atomicAdd(&st[t], red[t]);     // st[0..127] sum, st[128..255] ssq
}

// apply_out1 with inline BN2 stats from st
__global__ void apply_out1_v3(ushort_t* __restrict__ a0, const float* __restrict__ asum,
                              const float* __restrict__ st, const float* __restrict__ g2a,
                              const float* __restrict__ b2a){
  int e = blockIdx.x*256 + threadIdx.x; // n*128
  int c = e & 127;
  float m  = st[c]*(1.f/N_ATOM);
  float var = st[128+c]*(1.f/N_ATOM) - m*m;
  float rs = rsqrtf(var + 1e-5f);
  float g = g2a[c]*rs;
  float b = b2a[c] - m*g;
  a0[e] = f2bf(softplusf_(bf2f(a0[e]) + fmaf(asum[e], g, b)));
}

// gb lives in O2, [NM][128] (filter 0-63 -> global col 256+c, core 64-127 -> 320+c)
__global__ void apply_gb_v4(const __half* __restrict__ O2, ushort_t* __restrict__ nb,
                            const float* __restrict__ sums, const float* __restrict__ g1b,
                            const float* __restrict__ b1b){
  int t = threadIdx.x;          // 256 = 32 rows x 8 col-chunks
  int c8 = t & 7, rloc = t >> 3;
  int r = blockIdx.x*32 + rloc;
  int c0 = c8*8;
  float gf[8], bfv[8], gc[8], bcv[8];
#pragma unroll
  for (int k=0;k<8;++k){
    int c = c0+k;
    float mf = sums[256+c]*(1.f/NM);
    float rf = rsqrtf(sums[384+256+c]*(1.f/NM) - mf*mf + 1e-5f);
    gf[k]  = g1b[c]*rf;      bfv[k] = b1b[c] - mf*gf[k];
    float mc = sums[256+64+c]*(1.f/NM);
    float rc = rsqrtf(sums[384+256+64+c]*(1.f/NM) - mc*mc + 1e-5f);
    gc[k]  = g1b[c+64]*rc;   bcv[k] = b1b[c+64] - mc*gc[k];
  }
  size_t gbase = (size_t)r*128;
  u32x4 vf = __builtin_nontemporal_load((const u32x4*)(O2 + gbase + c0));
  u32x4 vc = __builtin_nontemporal_load((const u32x4*)(O2 + gbase + 64 + c0));
  const __half* hf = (const __half*)&vf;
  const __half* hc = (const __half*)&vc;
  ushort_t* np = nb + (size_t)r*64 + c0;
  u32x4 old = *(const u32x4*)np;
  const ushort_t* op = (const ushort_t*)&old;
  u32x4 outv;
  ushort_t* ov = (ushort_t*)&outv;
#pragma unroll
  for (int k=0;k<8;++k){
    float x = bf2f(op[k]) + sigmoidf_(fmaf(__half2float(hf[k]), gf[k], bfv[k]))
                          * softplusf_(fmaf(__half2float(hc[k]), gc[k], bcv[k]));
    ov[k] = f2bf(softplusf_(x));
  }
  *(u32x4*)np = outv;
}

// ---------------- pooling / VAE / decode ----------------
__global__ void pool_a_kernel(const ushort_t* __restrict__ a, float* __restrict__ pooled){
  int b = blockIdx.x; int c = threadIdx.x; // 128
  float s = 0.f;
  for (int i=0;i<128;++i) s += bf2f(a[(size_t)((b<<7)+i)*128 + c]);
  pooled[b*896 + c] = softplusf_(s * (1.f/128.f));
}

__launch_bounds__(768)
__global__ void pool_n_kernel(const ushort_t* __restrict__ nb, float* __restrict__ pooled){
  int b = blockIdx.x; int t = threadIdx.x; // 768
  float s = 0.f;
  for (int i=0;i<128;++i) s += bf2f(nb[(size_t)((b<<7)+i)*768 + t]);
  pooled[b*896 + 128 + t] = softplusf_(s * (1.f/128.f));
}

__global__ void muz_kernel(const float* __restrict__ pooled, const float* __restrict__ muW,
                           const float* __restrict__ mub, const float* __restrict__ lvW,
                           const float* __restrict__ lvb, const float* __restrict__ eps,
                           float* __restrict__ out_mu, float* __restrict__ out_lv,
                           float* __restrict__ out_z, float* __restrict__ zws){
  int t = threadIdx.x; // 256 -> (b,l)
  int b = t >> 1, l = t & 1;
  const float* pr = pooled + b*896;
  float smu = mub[l], slv = lvb[l];
  for (int k=0;k<896;++k){
    float p = pr[k];
    smu = fmaf(p, muW[k*2+l], smu);
    slv = fmaf(p, lvW[k*2+l], slv);
  }
  out_mu[t] = smu; out_lv[t] = slv;
  float zv = fmaf(eps[t], __expf(0.5f*slv), smu);
  out_z[t] = zv; zws[t] = zv;
}

__global__ void compute_f_kernel(const float* __restrict__ zws, const float* __restrict__ decW,
                                 const float* __restrict__ decb, const float* __restrict__ pooled,
                                 float* __restrict__ f){
  int b = blockIdx.x;
  float z0 = zws[b*2], z1 = zws[b*2+1];
  for (int k = threadIdx.x; k < 896; k += 256){
    float zd = fmaf(z0, decW[k], fmaf(z1, decW[896+k], decb[k]));
    f[b*896+k] = zd / pooled[b*896+k];
  }
}

__global__ void dec_atom_kernel(ushort_t* __restrict__ a, const float* __restrict__ f){
  int e = blockIdx.x*256+threadIdx.x; // n*128
  int c = e & 127; int b = e >> 14;
  a[e] = f2bf(softplusf_(bf2f(a[e]) * f[b*896 + c]));
}

__global__ void dec_bond_kernel(ushort_t* __restrict__ nb, const float* __restrict__ f){
  int i = blockIdx.x; int off = blockIdx.y*256 + threadIdx.x; // off < 768
  int b = i >> 7;
  size_t e = (size_t)i*768 + off;
  nb[e] = f2bf(softplusf_(bf2f(nb[e]) * f[b*896 + 128 + off]));
}

// ---------------- final embeddings ----------------
__global__ void embed_atom2_kernel(const ushort_t* __restrict__ a, const float* __restrict__ W,
                                   const float* __restrict__ bias, float* __restrict__ za2){
  __shared__ float row[128];
  int i = blockIdx.x; int t = threadIdx.x; // 128
  row[t] = bf2f(a[(size_t)i*128+t]);
  __syncthreads();
  if (t < 92){
    float s = bias[t];
#pragma unroll
    for (int k=0;k<128;++k) s = fmaf(row[k], W[k*92+t], s);
    za2[(size_t)i*92+t] = sigmoidf_(s);
  }
}

__global__ void bproj_kernel(const ushort_t* __restrict__ nb, const float* __restrict__ W,
                             const float* __restrict__ bias, float* __restrict__ bp){
  __shared__ float Ws[64][41];
  __shared__ float rows[6][64];
  int t = threadIdx.x; // 256
  for (int e=t; e<64*41; e+=256) Ws[e/41][e%41] = W[e];
  int r0 = blockIdx.x*6;
  for (int e=t; e<6*64; e+=256){
    int rr = e>>6, c = e&63;
    rows[rr][c] = bf2f(nb[(size_t)(r0+rr)*64 + c]);
  }
  __syncthreads();
  if (t < 246){
    int rr = t/41, o = t - rr*41;
    float s = bias[o];
#pragma unroll
    for (int k=0;k<64;++k) s = fmaf(rows[rr][k], Ws[k][o], s);
    bp[(size_t)(r0+rr)*41 + o] = sigmoidf_(s);
  }
}

__global__ void zdec_v2(const float* __restrict__ za2, const float* __restrict__ bp,
                        const int* __restrict__ idx, float* __restrict__ out){
  int e0 = blockIdx.x*2048 + threadIdx.x;
#pragma unroll
  for (int i=0;i<8;++i){
    int e = e0 + i*256;
    int r = e/225, c = e - r*225;
    float v;
    if (c < 92)       v = za2[(size_t)(r/12)*92 + c];
    else if (c < 184) v = za2[(size_t)idx[r]*92 + (c-92)];
    else              v = bp[(size_t)r*41 + (c-184)];
    __builtin_nontemporal_store(v, out + (size_t)e);
  }
}

// ---------------- host side ----------------
struct WsPlan {
  ushort_t *Abf, *NBbf, *Wt;
  __half* big;
  float *asum, *pooled, *fbuf, *zws, *eps, *sums, *st;
};

static void conv_pass(const WsPlan& P, const int* idx,
                      const float* Wa, const float* Wb,
                      const float* g1a, const float* b1a, const float* g1b, const float* b1b,
                      const float* g2a, const float* b2a,
                      hipStream_t stream){
  wtr2_kernel<<<dim3(10,12), 256, 0, stream>>>(Wa, Wb, P.Wt, P.sums);
  conv_gemm_v8<<<dim3(NM/256, 3), 256, 0, stream>>>(P.Abf, P.NBbf, idx, P.Wt, P.big, P.sums);
  const __half* O0 = P.big;
  const __half* O1 = P.big + (size_t)NM*128;
  const __half* O2 = P.big + (size_t)NM*256;
  apply_ga_v4<<<N_ATOM/16, 256, 0, stream>>>(O0, O1, P.sums, g1a, b1a, P.asum, P.st);
  apply_out1_v3<<<N_ATOM*128/256, 256, 0, stream>>>(P.Abf, P.asum, P.st, g2a, b2a);
  apply_gb_v4<<<NM/32, 256, 0, stream>>>(O2, P.NBbf, P.sums, g1b, b1b);
}

extern "C" void kernel_launch(void* const* d_in, const int* in_sizes, int n_in,
                              void* d_out, int out_size, void* d_ws, size_t ws_size,
                              hipStream_t stream) {
  (void)in_sizes; (void)n_in; (void)out_size; (void)ws_size;
  const float* atom_fea   = (const float*)d_in[0];
  const float* nbr_fea    = (const float*)d_in[1];
  const int*   idx        = (const int*)d_in[2];
  const float* emb_atom_W = (const float*)d_in[4];
  const float* emb_atom_b = (const float*)d_in[5];
  const float* emb_bond_W = (const float*)d_in[6];
  const float* emb_bond_b = (const float*)d_in[7];
  const float* emb_atom2_W= (const float*)d_in[8];
  const float* emb_atom2_b= (const float*)d_in[9];
  const float* emb_bond2_W= (const float*)d_in[10];
  const float* emb_bond2_b= (const float*)d_in[11];
  const float* mu_W       = (const float*)d_in[12];
  const float* mu_b       = (const float*)d_in[13];
  const float* lv_W       = (const float*)d_in[14];
  const float* lv_b       = (const float*)d_in[15];
  const float* dec_W      = (const float*)d_in[16];
  const float* dec_b      = (const float*)d_in[17];
  const float* c1_Wa  = (const float*)d_in[18];
  const float* c1_Wb  = (const float*)d_in[19];
  const float* c1_g1a = (const float*)d_in[20];
  const float* c1_b1a = (const float*)d_in[21];
  const float* c1_g1b = (const float*)d_in[22];
  const float* c1_b1b = (const float*)d_in[23];
  const float* c1_g2a = (const float*)d_in[24];
  const float* c1_b2a = (const float*)d_in[25];
  const float* c2_Wa  = (const float*)d_in[26];
  const float* c2_Wb  = (const float*)d_in[27];
  const float* c2_g1a = (const float*)d_in[28];
  const float* c2_b1a = (const float*)d_in[29];
  const float* c2_g1b = (const float*)d_in[30];
  const float* c2_b1b = (const float*)d_in[31];
  const float* c2_g2a = (const float*)d_in[32];
  const float* c2_b2a = (const float*)d_in[33];

  float* out = (float*)d_out;

  WsPlan P;
  char* w = (char*)d_ws;
  auto alloc = [&](size_t bytes) -> char* {
    char* p = w; w += (bytes + 255) & ~(size_t)255; return p;
  };
  P.Abf    = (ushort_t*)alloc((size_t)N_ATOM*128*2);
  P.NBbf   = (ushort_t*)alloc((size_t)NM*64*2);
  P.big    = (__half*)  alloc((size_t)NM*384*2);
  P.asum   = (float*)   alloc((size_t)N_ATOM*128*4);
  P.pooled = (float*)   alloc(114688*4);
  P.fbuf   = (float*)   alloc(114688*4);
  P.Wt     = (ushort_t*)alloc(384*320*2);
  P.zws    = (float*)   alloc(256*4);
  P.eps    = (float*)   alloc(256*4);
  P.sums   = (float*)   alloc(1024*4);   // sums[768] + st[256] contiguous (zeroed in wtr2)
  P.st     = P.sums + 768;
  float* za2   = P.asum;                 // reuse after conv stacks
  float* bproj = (float*)P.big;          // reuse big in the final phase

  gen_eps_kernel<<<1, 256, 0, stream>>>(P.eps);
  tif_v2<<<21600, 256, 0, stream>>>(atom_fea, nbr_fea, idx, out + O_TIF);
  embed_atom_kernel<<<N_ATOM, 128, 0, stream>>>(atom_fea, emb_atom_W, emb_atom_b, P.Abf);
  embed_bond_kernel<<<NM/4, 256, 0, stream>>>(nbr_fea, emb_bond_W, emb_bond_b, P.NBbf);

  for (int L=0; L<3; ++L){
    conv_pass(P, idx, c1_Wa + (size_t)L*320*256, c1_Wb + (size_t)L*320*128,
              c1_g1a+L*256, c1_b1a+L*256, c1_g1b+L*128, c1_b1b+L*128,
              c1_g2a+L*128, c1_b2a+L*128, stream);
  }

  pool_a_kernel<<<NCRY, 128, 0, stream>>>(P.Abf, P.pooled);
  pool_n_kernel<<<NCRY, 768, 0, stream>>>(P.NBbf, P.pooled);
  muz_kernel<<<1, 256, 0, stream>>>(P.pooled, mu_W, mu_b, lv_W, lv_b, P.eps,
                                    out + O_MU, out + O_LV, out + O_Z, P.zws);
  compute_f_kernel<<<NCRY, 256, 0, stream>>>(P.zws, dec_W, dec_b, P.pooled, P.fbuf);
  dec_atom_kernel<<<N_ATOM*128/256, 256, 0, stream>>>(P.Abf, P.fbuf);
  dim3 gdb(N_ATOM, 3);
  dec_bond_kernel<<<gdb, 256, 0, stream>>>(P.NBbf, P.fbuf);

  for (int L=0; L<3; ++L){
    conv_pass(P, idx, c2_Wa + (size_t)L*320*256, c2_Wb + (size_t)L*320*128,
              c2_g1a+L*256, c2_b1a+L*256, c2_g1b+L*128, c2_b1b+L*128,
              c2_g2a+L*128, c2_b2a+L*128, stream);
  }

  embed_atom2_kernel<<<N_ATOM, 128, 0, stream>>>(P.Abf, emb_atom2_W, emb_atom2_b, za2);
  bproj_kernel<<<NM/6, 256, 0, stream>>>(P.NBbf, emb_bond2_W, emb_bond2_b, bproj);
  zdec_v2<<<21600, 256, 0, stream>>>(za2, bproj, idx, out + O_ZDEC);
}

// Round 12
// 2440.199 us; speedup vs baseline: 1.1116x; 1.0618x over previous
//
#include <hip/hip_runtime.h>
#include <hip/hip_bf16.h>
#include <hip/hip_fp16.h>
#include <cstdint>
#include <cstddef>

// ---------------- constants ----------------
#define N_ATOM 16384
#define M_NBR  12
#define NCRY   128
#define NM     (N_ATOM*M_NBR) // 196608

// output offsets (floats)
#define O_ZDEC 0
#define O_MU   44236800
#define O_LV   44237056
#define O_Z    44237312
#define O_TIF  44237568

typedef unsigned short ushort_t;
typedef float f32x4 __attribute__((ext_vector_type(4)));
typedef short bf16x8 __attribute__((ext_vector_type(8)));
typedef unsigned int u32x4 __attribute__((ext_vector_type(4)));

__device__ __forceinline__ float sigmoidf_(float x){ return 1.f/(1.f+__expf(-x)); }
__device__ __forceinline__ float softplusf_(float x){ return fmaxf(x,0.f) + log1pf(__expf(-fabsf(x))); }
__device__ __forceinline__ uint32_t rotl32_(uint32_t x, int r){ return (x<<r)|(x>>(32-r)); }
__device__ __forceinline__ float bf2f(ushort_t u){ return __uint_as_float(((uint32_t)u)<<16); }
__device__ __forceinline__ ushort_t f2bf(float x){
  uint32_t u = __float_as_uint(x);
  uint32_t r = (u + 0x7FFFu + ((u>>16)&1u)) >> 16;
  return (ushort_t)r;
}

// async global->LDS, 16B per lane; LDS dest = wave-uniform base + lane*16
#define GLDS16(g, l) __builtin_amdgcn_global_load_lds( \
    (const __attribute__((address_space(1))) void*)(g), \
    (__attribute__((address_space(3))) void*)(l), 16, 0, 0)

// ---------------- eps = jax.random.normal(key(42), (128,2)) ----------------
__global__ void gen_eps_kernel(float* __restrict__ eps){
  int j = threadIdx.x; // 256
  const uint32_t k0 = 0u, k1 = 42u;
  const uint32_t ks2 = k0 ^ k1 ^ 0x1BD11BDAu;
  uint32_t x0 = 0u + k0;
  uint32_t x1 = (uint32_t)j + k1;
#define RND_(r) { x0 += x1; x1 = rotl32_(x1, r); x1 ^= x0; }
  RND_(13) RND_(15) RND_(26) RND_(6)  x0 += k1;  x1 += ks2 + 1u;
  RND_(17) RND_(29) RND_(16) RND_(24) x0 += ks2; x1 += k0 + 2u;
  RND_(13) RND_(15) RND_(26) RND_(6)  x0 += k0;  x1 += k1 + 3u;
  RND_(17) RND_(29) RND_(16) RND_(24) x0 += k1;  x1 += ks2 + 4u;
  RND_(13) RND_(15) RND_(26) RND_(6)  x0 += ks2; x1 += k0 + 5u;
#undef RND_
  uint32_t bits = x0 ^ x1;
  float f = __uint_as_float((bits >> 9) | 0x3f800000u) - 1.0f;
  float u = __fadd_rn(__fmul_rn(f, 1.99999994f), -0.99999994f);
  u = fmaxf(-0.99999994f, u);
  float w = -log1pf(-u*u);
  float p;
  if (w < 5.0f){
    w -= 2.5f;
    p = 2.81022636e-08f;
    p = fmaf(p, w, 3.43273939e-07f);
    p = fmaf(p, w, -3.5233877e-06f);
    p = fmaf(p, w, -4.39150654e-06f);
    p = fmaf(p, w, 0.00021858087f);
    p = fmaf(p, w, -0.00125372503f);
    p = fmaf(p, w, -0.00417768164f);
    p = fmaf(p, w, 0.246640727f);
    p = fmaf(p, w, 1.50140941f);
  } else {
    w = sqrtf(w) - 3.0f;
    p = -0.000200214257f;
    p = fmaf(p, w, 0.000100950558f);
    p = fmaf(p, w, 0.00134934322f);
    p = fmaf(p, w, -0.00367342844f);
    p = fmaf(p, w, 0.00573950773f);
    p = fmaf(p, w, -0.0076224613f);
    p = fmaf(p, w, 0.00943887047f);
    p = fmaf(p, w, 1.00167406f);
    p = fmaf(p, w, 2.83297682f);
  }
  eps[j] = 1.41421356237f * (p * u);
}

// ---------------- total_input_fea output (coalesced, NT stores: true output) ------
__global__ void tif_v2(const float* __restrict__ atom, const float* __restrict__ nbr,
                       const int* __restrict__ idx, float* __restrict__ out){
  int e0 = blockIdx.x*2048 + threadIdx.x;
#pragma unroll
  for (int i=0;i<8;++i){
    int e = e0 + i*256;
    int r = e/225, c = e - r*225;
    float v;
    if (c < 92)       v = atom[(r/12)*92 + c];
    else if (c < 184) v = atom[idx[r]*92 + (c-92)];
    else              v = nbr[(size_t)r*41 + (c-184)];
    __builtin_nontemporal_store(v, out + (size_t)e);
  }
}

// ---------------- embeddings (write bf16 masters) ----------------
__global__ void embed_atom_kernel(const float* __restrict__ atom, const float* __restrict__ W,
                                  const float* __restrict__ bias, ushort_t* __restrict__ a0){
  __shared__ float row[92];
  int i = blockIdx.x; int t = threadIdx.x; // 128
  if (t < 92) row[t] = atom[i*92+t];
  __syncthreads();
  float s = bias[t];
#pragma unroll
  for (int k=0;k<92;++k) s = fmaf(row[k], W[k*128+t], s);
  a0[(size_t)i*128+t] = f2bf(s);
}

__global__ void embed_bond_kernel(const float* __restrict__ nbr, const float* __restrict__ W,
                                  const float* __restrict__ bias, ushort_t* __restrict__ nb0){
  __shared__ float rows[4][41];
  int r0 = blockIdx.x*4; int t = threadIdx.x; // 256
  if (t < 164) rows[t/41][t%41] = nbr[(size_t)r0*41 + t];
  __syncthreads();
  int rr = t >> 6, c = t & 63;
  float s = bias[c];
#pragma unroll
  for (int k=0;k<41;++k) s = fmaf(rows[rr][k], W[k*64+c], s);
  nb0[(size_t)(r0+rr)*64 + c] = f2bf(s);
}

// ---------------- weight transpose (pass 0) + stats zeroing ----------
__global__ void wtr2_kernel(const float* __restrict__ Wa, const float* __restrict__ Wb,
                            ushort_t* __restrict__ Wt, float* __restrict__ zstats){
  __shared__ ushort_t tile[32][33];
  if (blockIdx.x == 0 && blockIdx.y == 0){
#pragma unroll
    for (int k=0;k<4;++k) zstats[threadIdx.x + k*256] = 0.f;
  }
  int by = blockIdx.y;
  const float* W; int NO, o0, obase;
  if (by < 8){ W = Wa; NO = 256; o0 = by*32; obase = o0; }
  else       { W = Wb; NO = 128; o0 = (by-8)*32; obase = 256 + o0; }
  int k0 = blockIdx.x*32;
  int tx = threadIdx.x & 31, ty = threadIdx.x >> 5; // 256 thr
#pragma unroll
  for (int i = ty; i < 32; i += 8)
    tile[i][tx] = f2bf(W[(size_t)(k0+i)*NO + o0 + tx]);
  __syncthreads();
#pragma unroll
  for (int i = ty; i < 32; i += 8)
    Wt[(size_t)(obase+i)*320 + k0 + tx] = tile[tx][i];
}

// ---------------- MFMA conv GEMM v8: counted-vmcnt software pipeline + setprio ----
__launch_bounds__(256, 2)
__global__ void conv_gemm_v8(const ushort_t* __restrict__ a_bf, const ushort_t* __restrict__ nb_bf,
                             const int* __restrict__ idx, const ushort_t* __restrict__ Wt,
                             __half* __restrict__ O, float* __restrict__ sums){
  __shared__ ushort_t sm[34816];   // staging: As 2x8192 @0, Bs 2x4096 @16384; epilogue [256][136]
  __shared__ float sqred[256];     // 128 sum + 128 ssq (this col block)
  __shared__ int idxs[256];
  ushort_t* As = sm;
  ushort_t* Bs = sm + 16384;
  const int t = threadIdx.x;
  const int lane = t & 63;
  const int w = t >> 6;
  const int lm = lane & 15, lg = lane >> 4;
  const int row0 = blockIdx.x * 256;
  const int cb   = blockIdx.y;          // col-block 0..2
  const int col0 = cb * 128;
  __half* Ob = O + (size_t)cb * ((size_t)NM*128);

  idxs[t] = idx[row0 + t];   // first consumed by stage(4) -> many barriers later
  sqred[t] = 0.f;

  auto stage = [&](int ks, int b_){
    ushort_t* Ad = As + b_*8192;
    ushort_t* Bd = Bs + b_*4096;
#pragma unroll
    for (int i=0;i<4;++i){
      int e = t + i*256;              // 0..1023
      int r = e >> 2, ch = e & 3;
      const ushort_t* ga;
      if (ks < 4)      ga = a_bf + (size_t)((row0+r)/12)*128 + ks*32 + ch*8;
      else if (ks < 8) ga = a_bf + (size_t)idxs[r]*128 + (ks-4)*32 + ch*8;
      else             ga = nb_bf + (size_t)(row0+r)*64 + (ks-8)*32 + ch*8;
      GLDS16(ga, Ad + e*8);
    }
#pragma unroll
    for (int i=0;i<2;++i){
      int e = t + i*256;              // 0..511
      int r = e >> 2, ch = e & 3;
      GLDS16(Wt + (size_t)(col0+r)*320 + ks*32 + ch*8, Bd + e*8);
    }
  };

  stage(0, 0);                        // batch 0 in flight

  f32x4 acc[4][8] = {};
  int buf = 0;
#pragma unroll
  for (int ks = 0; ks < 10; ++ks){
    if (ks < 9){
      stage(ks+1, buf^1);             // batch ks+1 in flight (6 more)
      asm volatile("s_waitcnt vmcnt(6)" ::: "memory");  // batch ks landed (mine)
    } else {
      asm volatile("s_waitcnt vmcnt(0)" ::: "memory");  // final batch landed
    }
    __builtin_amdgcn_s_barrier();     // all waves' batch ks landed
    __builtin_amdgcn_sched_barrier(0);
    const ushort_t* Ab = As + buf*8192;
    const ushort_t* Bb = Bs + buf*4096;
    bf16x8 afr[4], bfr[8];
#pragma unroll
    for (int fm=0; fm<4; ++fm)
      afr[fm] = *(const bf16x8*)&Ab[(w*64 + fm*16 + lm)*32 + lg*8];
#pragma unroll
    for (int fn=0; fn<8; ++fn)
      bfr[fn] = *(const bf16x8*)&Bb[(fn*16 + lm)*32 + lg*8];
    __builtin_amdgcn_s_setprio(1);
#pragma unroll
    for (int fm=0; fm<4; ++fm)
#pragma unroll
      for (int fn=0; fn<8; ++fn)
        acc[fm][fn] = __builtin_amdgcn_mfma_f32_16x16x32_bf16(afr[fm], bfr[fn], acc[fm][fn], 0, 0, 0);
    __builtin_amdgcn_s_setprio(0);
    asm volatile("s_waitcnt lgkmcnt(0)" ::: "memory");  // my ds_reads of buf done
    __builtin_amdgcn_sched_barrier(0);                   // rule #18 fence
    __builtin_amdgcn_s_barrier();     // all waves done reading buf -> safe to overwrite
    buf ^= 1;
  }

  // epilogue: stage f16 tile [256][136] in LDS, then coalesced NT stores + sum/ssq
#pragma unroll
  for (int fm=0; fm<4; ++fm){
    int rw = w*64 + fm*16 + lg*4;
#pragma unroll
    for (int fn=0; fn<8; ++fn){
      int cl = fn*16 + lm;
#pragma unroll
      for (int j=0; j<4; ++j){
        __half h = __float2half(acc[fm][fn][j]);
        sm[(rw+j)*136 + cl] = *(ushort_t*)&h;
      }
    }
  }
  __syncthreads();

  const int cch = t & 15, rb = t >> 4;
  float s1[8] = {0.f,0.f,0.f,0.f,0.f,0.f,0.f,0.f};
  float s2[8] = {0.f,0.f,0.f,0.f,0.f,0.f,0.f,0.f};
#pragma unroll
  for (int i=0; i<16; ++i){
    int row = rb + i*16;
    u32x4 v = *(const u32x4*)&sm[row*136 + cch*8];
    __builtin_nontemporal_store(v, (u32x4*)(Ob + (size_t)(row0+row)*128 + cch*8));
    const __half* hp = (const __half*)&v;
#pragma unroll
    for (int k=0;k<8;++k){
      float f = __half2float(hp[k]);
      s1[k] += f;
      s2[k] += f*f;
    }
  }
#pragma unroll
  for (int k=0;k<8;++k){
    atomicAdd(&sqred[cch*8+k], s1[k]);
    atomicAdd(&sqred[128+cch*8+k], s2[k]);
  }
  __syncthreads();
  if (t < 128){
    atomicAdd(&sums[col0 + t], sqred[t]);          // sum
    atomicAdd(&sums[384 + col0 + t], sqred[128+t]);// ssq
  }
}

// ---------------- fused apply: ga (blocks 0..1023) + gb (blocks 1024..7167) ----
__global__ void apply_gagb(const __half* __restrict__ O0, const __half* __restrict__ O1,
                           const __half* __restrict__ O2, ushort_t* __restrict__ nb,
                           const float* __restrict__ sums,
                           const float* __restrict__ g1a, const float* __restrict__ b1a,
                           const float* __restrict__ g1b, const float* __restrict__ b1b,
                           float* __restrict__ asum, float* __restrict__ st){
  __shared__ float red[256];
  int bx = blockIdx.x;
  int t = threadIdx.x;
  if (bx < 1024){
    // ---- ga part: 16 atoms x 16 col-chunks ----
    red[t] = 0.f;
    int c8 = t & 15, al = t >> 4;
    int i = bx*16 + al;
    int c0 = c8*8;
    float gf[8], bfv[8], gc[8], bcv[8];
#pragma unroll
    for (int k=0;k<8;++k){
      int c = c0+k;
      float mf = sums[c]*(1.f/NM);
      float rf = rsqrtf(sums[384+c]*(1.f/NM) - mf*mf + 1e-5f);
      gf[k]  = g1a[c]*rf;      bfv[k] = b1a[c] - mf*gf[k];
      float mc = sums[c+128]*(1.f/NM);
      float rc = rsqrtf(sums[384+c+128]*(1.f/NM) - mc*mc + 1e-5f);
      gc[k]  = g1a[c+128]*rc;  bcv[k] = b1a[c+128] - mc*gc[k];
    }
    float s[8] = {0.f,0.f,0.f,0.f,0.f,0.f,0.f,0.f};
    size_t base = (size_t)i*12*128;
#pragma unroll
    for (int j=0;j<12;++j){
      u32x4 vf = __builtin_nontemporal_load((const u32x4*)(O0 + base + j*128 + c0));
      u32x4 vc = __builtin_nontemporal_load((const u32x4*)(O1 + base + j*128 + c0));
      const __half* hf = (const __half*)&vf;
      const __half* hc = (const __half*)&vc;
#pragma unroll
      for (int k=0;k<8;++k)
        s[k] += sigmoidf_(fmaf(__half2float(hf[k]), gf[k], bfv[k]))
              * softplusf_(fmaf(__half2float(hc[k]), gc[k], bcv[k]));
    }
    float* dst = asum + (size_t)i*128 + c0;
    __syncthreads();               // red zero visible before cross-thread atomics
#pragma unroll
    for (int k=0;k<8;++k){
      dst[k] = s[k];
      atomicAdd(&red[c0+k], s[k]);
      atomicAdd(&red[128+c0+k], s[k]*s[k]);
    }
    __syncthreads();
    atomicAdd(&st[t], red[t]);     // st[0..127] sum, st[128..255] ssq
  } else {
    // ---- gb part: 32 rows x 8 col-chunks ----
    int c8 = t & 7, rloc = t >> 3;
    int r = (bx-1024)*32 + rloc;
    int c0 = c8*8;
    float gf[8], bfv[8], gc[8], bcv[8];
#pragma unroll
    for (int k=0;k<8;++k){
      int c = c0+k;
      float mf = sums[256+c]*(1.f/NM);
      float rf = rsqrtf(sums[384+256+c]*(1.f/NM) - mf*mf + 1e-5f);
      gf[k]  = g1b[c]*rf;      bfv[k] = b1b[c] - mf*gf[k];
      float mc = sums[256+64+c]*(1.f/NM);
      float rc = rsqrtf(sums[384+256+64+c]*(1.f/NM) - mc*mc + 1e-5f);
      gc[k]  = g1b[c+64]*rc;   bcv[k] = b1b[c+64] - mc*gc[k];
    }
    size_t gbase = (size_t)r*128;
    u32x4 vf = __builtin_nontemporal_load((const u32x4*)(O2 + gbase + c0));
    u32x4 vc = __builtin_nontemporal_load((const u32x4*)(O2 + gbase + 64 + c0));
    const __half* hf = (const __half*)&vf;
    const __half* hc = (const __half*)&vc;
    ushort_t* np = nb + (size_t)r*64 + c0;
    u32x4 old = *(const u32x4*)np;
    const ushort_t* op = (const ushort_t*)&old;
    u32x4 outv;
    ushort_t* ov = (ushort_t*)&outv;
#pragma unroll
    for (int k=0;k<8;++k){
      float x = bf2f(op[k]) + sigmoidf_(fmaf(__half2float(hf[k]), gf[k], bfv[k]))
                            * softplusf_(fmaf(__half2float(hc[k]), gc[k], bcv[k]));
      ov[k] = f2bf(softplusf_(x));
    }
    *(u32x4*)np = outv;
  }
}

// ---------------- fused: apply_out1 (blocks 121..8312) + next-pass wtr (0..119)
//                  + next-pass stats zero (block 120) ----
__global__ void out1_wtr(ushort_t* __restrict__ a0, const float* __restrict__ asum,
                         const float* __restrict__ st, const float* __restrict__ g2a,
                         const float* __restrict__ b2a,
                         const float* __restrict__ Wa_next, const float* __restrict__ Wb_next,
                         ushort_t* __restrict__ Wt, float* __restrict__ zstats){
  __shared__ ushort_t tile[32][33];
  int bx = blockIdx.x;
  int t = threadIdx.x;
  if (bx < 120){
    if (Wa_next == nullptr) return;
    int by = bx / 10, kx = bx - by*10;
    const float* W; int NO, o0, obase;
    if (by < 8){ W = Wa_next; NO = 256; o0 = by*32; obase = o0; }
    else       { W = Wb_next; NO = 128; o0 = (by-8)*32; obase = 256 + o0; }
    int k0 = kx*32;
    int tx = t & 31, ty = t >> 5;
#pragma unroll
    for (int i = ty; i < 32; i += 8)
      tile[i][tx] = f2bf(W[(size_t)(k0+i)*NO + o0 + tx]);
    __syncthreads();
#pragma unroll
    for (int i = ty; i < 32; i += 8)
      Wt[(size_t)(obase+i)*320 + k0 + tx] = tile[tx][i];
  } else if (bx == 120){
    if (Wa_next == nullptr) return;
#pragma unroll
    for (int k=0;k<4;++k) zstats[t + k*256] = 0.f;
  } else {
    int e = (bx-121)*256 + t; // n*128
    int c = e & 127;
    float m  = st[c]*(1.f/N_ATOM);
    float var = st[128+c]*(1.f/N_ATOM) - m*m;
    float rs = rsqrtf(var + 1e-5f);
    float g = g2a[c]*rs;
    float b = b2a[c] - m*g;
    a0[e] = f2bf(softplusf_(bf2f(a0[e]) + fmaf(asum[e], g, b)));
  }
}

// ---------------- pooling / VAE / decode ----------------
__global__ void pool_a_kernel(const ushort_t* __restrict__ a, float* __restrict__ pooled){
  int b = blockIdx.x; int c = threadIdx.x; // 128
  float s = 0.f;
  for (int i=0;i<128;++i) s += bf2f(a[(size_t)((b<<7)+i)*128 + c]);
  pooled[b*896 + c] = softplusf_(s * (1.f/128.f));
}

__launch_bounds__(768)
__global__ void pool_n_kernel(const ushort_t* __restrict__ nb, float* __restrict__ pooled){
  int b = blockIdx.x; int t = threadIdx.x; // 768
  float s = 0.f;
  for (int i=0;i<128;++i) s += bf2f(nb[(size_t)((b<<7)+i)*768 + t]);
  pooled[b*896 + 128 + t] = softplusf_(s * (1.f/128.f));
}

__global__ void muz_kernel(const float* __restrict__ pooled, const float* __restrict__ muW,
                           const float* __restrict__ mub, const float* __restrict__ lvW,
                           const float* __restrict__ lvb, const float* __restrict__ eps,
                           float* __restrict__ out_mu, float* __restrict__ out_lv,
                           float* __restrict__ out_z, float* __restrict__ zws){
  int t = threadIdx.x; // 256 -> (b,l)
  int b = t >> 1, l = t & 1;
  const float* pr = pooled + b*896;
  float smu = mub[l], slv = lvb[l];
  for (int k=0;k<896;++k){
    float p = pr[k];
    smu = fmaf(p, muW[k*2+l], smu);
    slv = fmaf(p, lvW[k*2+l], slv);
  }
  out_mu[t] = smu; out_lv[t] = slv;
  float zv = fmaf(eps[t], __expf(0.5f*slv), smu);
  out_z[t] = zv; zws[t] = zv;
}

__global__ void compute_f_kernel(const float* __restrict__ zws, const float* __restrict__ decW,
                                 const float* __restrict__ decb, const float* __restrict__ pooled,
                                 float* __restrict__ f){
  int b = blockIdx.x;
  float z0 = zws[b*2], z1 = zws[b*2+1];
  for (int k = threadIdx.x; k < 896; k += 256){
    float zd = fmaf(z0, decW[k], fmaf(z1, decW[896+k], decb[k]));
    f[b*896+k] = zd / pooled[b*896+k];
  }
}

__global__ void dec_atom_kernel(ushort_t* __restrict__ a, const float* __restrict__ f){
  int e = blockIdx.x*256+threadIdx.x; // n*128
  int c = e & 127; int b = e >> 14;
  a[e] = f2bf(softplusf_(bf2f(a[e]) * f[b*896 + c]));
}

__global__ void dec_bond_kernel(ushort_t* __restrict__ nb, const float* __restrict__ f){
  int i = blockIdx.x; int off = blockIdx.y*256 + threadIdx.x; // off < 768
  int b = i >> 7;
  size_t e = (size_t)i*768 + off;
  nb[e] = f2bf(softplusf_(bf2f(nb[e]) * f[b*896 + 128 + off]));
}

// ---------------- final embeddings ----------------
__global__ void embed_atom2_kernel(const ushort_t* __restrict__ a, const float* __restrict__ W,
                                   const float* __restrict__ bias, float* __restrict__ za2){
  __shared__ float row[128];
  int i = blockIdx.x; int t = threadIdx.x; // 128
  row[t] = bf2f(a[(size_t)i*128+t]);
  __syncthreads();
  if (t < 92){
    float s = bias[t];
#pragma unroll
    for (int k=0;k<128;++k) s = fmaf(row[k], W[k*92+t], s);
    za2[(size_t)i*92+t] = sigmoidf_(s);
  }
}

__global__ void bproj_kernel(const ushort_t* __restrict__ nb, const float* __restrict__ W,
                             const float* __restrict__ bias, float* __restrict__ bp){
  __shared__ float Ws[64][41];
  __shared__ float rows[6][64];
  int t = threadIdx.x; // 256
  for (int e=t; e<64*41; e+=256) Ws[e/41][e%41] = W[e];
  int r0 = blockIdx.x*6;
  for (int e=t; e<6*64; e+=256){
    int rr = e>>6, c = e&63;
    rows[rr][c] = bf2f(nb[(size_t)(r0+rr)*64 + c]);
  }
  __syncthreads();
  if (t < 246){
    int rr = t/41, o = t - rr*41;
    float s = bias[o];
#pragma unroll
    for (int k=0;k<64;++k) s = fmaf(rows[rr][k], Ws[k][o], s);
    bp[(size_t)(r0+rr)*41 + o] = sigmoidf_(s);
  }
}

__global__ void zdec_v2(const float* __restrict__ za2, const float* __restrict__ bp,
                        const int* __restrict__ idx, float* __restrict__ out){
  int e0 = blockIdx.x*2048 + threadIdx.x;
#pragma unroll
  for (int i=0;i<8;++i){
    int e = e0 + i*256;
    int r = e/225, c = e - r*225;
    float v;
    if (c < 92)       v = za2[(size_t)(r/12)*92 + c];
    else if (c < 184) v = za2[(size_t)idx[r]*92 + (c-92)];
    else              v = bp[(size_t)r*41 + (c-184)];
    __builtin_nontemporal_store(v, out + (size_t)e);
  }
}

// ---------------- host side ----------------
struct WsPlan {
  ushort_t *Abf, *NBbf, *Wt;
  __half* big;
  float *asum, *pooled, *fbuf, *zws, *eps, *sums0, *sums1;
};

struct PassW {
  const float *Wa,*Wb,*g1a,*b1a,*g1b,*b1b,*g2a,*b2a;
};

extern "C" void kernel_launch(void* const* d_in, const int* in_sizes, int n_in,
                              void* d_out, int out_size, void* d_ws, size_t ws_size,
                              hipStream_t stream) {
  (void)in_sizes; (void)n_in; (void)out_size; (void)ws_size;
  const float* atom_fea   = (const float*)d_in[0];
  const float* nbr_fea    = (const float*)d_in[1];
  const int*   idx        = (const int*)d_in[2];
  const float* emb_atom_W = (const float*)d_in[4];
  const float* emb_atom_b = (const float*)d_in[5];
  const float* emb_bond_W = (const float*)d_in[6];
  const float* emb_bond_b = (const float*)d_in[7];
  const float* emb_atom2_W= (const float*)d_in[8];
  const float* emb_atom2_b= (const float*)d_in[9];
  const float* emb_bond2_W= (const float*)d_in[10];
  const float* emb_bond2_b= (const float*)d_in[11];
  const float* mu_W       = (const float*)d_in[12];
  const float* mu_b       = (const float*)d_in[13];
  const float* lv_W       = (const float*)d_in[14];
  const float* lv_b       = (const float*)d_in[15];
  const float* dec_W      = (const float*)d_in[16];
  const float* dec_b      = (const float*)d_in[17];
  const float* c1_Wa  = (const float*)d_in[18];
  const float* c1_Wb  = (const float*)d_in[19];
  const float* c1_g1a = (const float*)d_in[20];
  const float* c1_b1a = (const float*)d_in[21];
  const float* c1_g1b = (const float*)d_in[22];
  const float* c1_b1b = (const float*)d_in[23];
  const float* c1_g2a = (const float*)d_in[24];
  const float* c1_b2a = (const float*)d_in[25];
  const float* c2_Wa  = (const float*)d_in[26];
  const float* c2_Wb  = (const float*)d_in[27];
  const float* c2_g1a = (const float*)d_in[28];
  const float* c2_b1a = (const float*)d_in[29];
  const float* c2_g1b = (const float*)d_in[30];
  const float* c2_b1b = (const float*)d_in[31];
  const float* c2_g2a = (const float*)d_in[32];
  const float* c2_b2a = (const float*)d_in[33];

  float* out = (float*)d_out;

  WsPlan P;
  char* w = (char*)d_ws;
  auto alloc = [&](size_t bytes) -> char* {
    char* p = w; w += (bytes + 255) & ~(size_t)255; return p;
  };
  P.Abf    = (ushort_t*)alloc((size_t)N_ATOM*128*2);
  P.NBbf   = (ushort_t*)alloc((size_t)NM*64*2);
  P.big    = (__half*)  alloc((size_t)NM*384*2);
  P.asum   = (float*)   alloc((size_t)N_ATOM*128*4);
  P.pooled = (float*)   alloc(114688*4);
  P.fbuf   = (float*)   alloc(114688*4);
  P.Wt     = (ushort_t*)alloc(384*320*2);
  P.zws    = (float*)   alloc(256*4);
  P.eps    = (float*)   alloc(256*4);
  P.sums0  = (float*)   alloc(1024*4);   // slot 0: sums[768] + st[256]
  P.sums1  = (float*)   alloc(1024*4);   // slot 1
  float* za2   = P.asum;                 // reuse after conv stacks
  float* bproj = (float*)P.big;          // reuse big in the final phase

  PassW pw[6] = {
    { c1_Wa,            c1_Wb,            c1_g1a,       c1_b1a,       c1_g1b,       c1_b1b,       c1_g2a,       c1_b2a       },
    { c1_Wa+320*256,    c1_Wb+320*128,    c1_g1a+256,   c1_b1a+256,   c1_g1b+128,   c1_b1b+128,   c1_g2a+128,   c1_b2a+128   },
    { c1_Wa+2*320*256,  c1_Wb+2*320*128,  c1_g1a+2*256, c1_b1a+2*256, c1_g1b+2*128, c1_b1b+2*128, c1_g2a+2*128, c1_b2a+2*128 },
    { c2_Wa,            c2_Wb,            c2_g1a,       c2_b1a,       c2_g1b,       c2_b1b,       c2_g2a,       c2_b2a       },
    { c2_Wa+320*256,    c2_Wb+320*128,    c2_g1a+256,   c2_b1a+256,   c2_g1b+128,   c2_b1b+128,   c2_g2a+128,   c2_b2a+128   },
    { c2_Wa+2*320*256,  c2_Wb+2*320*128,  c2_g1a+2*256, c2_b1a+2*256, c2_g1b+2*128, c2_b1b+2*128, c2_g2a+2*128, c2_b2a+2*128 },
  };

  auto conv_pass = [&](int p){
    float* sums_cur = (p & 1) ? P.sums1 : P.sums0;
    float* sums_nxt = (p & 1) ? P.sums0 : P.sums1;
    const __half* O0 = P.big;
    const __half* O1 = P.big + (size_t)NM*128;
    const __half* O2 = P.big + (size_t)NM*256;
    conv_gemm_v8<<<dim3(NM/256, 3), 256, 0, stream>>>(P.Abf, P.NBbf, idx, P.Wt, P.big, sums_cur);
    apply_gagb<<<7168, 256, 0, stream>>>(O0, O1, O2, P.NBbf, sums_cur,
                                         pw[p].g1a, pw[p].b1a, pw[p].g1b, pw[p].b1b,
                                         P.asum, sums_cur + 768);
    const float* Wa_n = (p < 5) ? pw[p+1].Wa : nullptr;
    const float* Wb_n = (p < 5) ? pw[p+1].Wb : nullptr;
    out1_wtr<<<8313, 256, 0, stream>>>(P.Abf, P.asum, sums_cur + 768,
                                       pw[p].g2a, pw[p].b2a, Wa_n, Wb_n, P.Wt, sums_nxt);
  };

  gen_eps_kernel<<<1, 256, 0, stream>>>(P.eps);
  tif_v2<<<21600, 256, 0, stream>>>(atom_fea, nbr_fea, idx, out + O_TIF);
  embed_atom_kernel<<<N_ATOM, 128, 0, stream>>>(atom_fea, emb_atom_W, emb_atom_b, P.Abf);
  embed_bond_kernel<<<NM/4, 256, 0, stream>>>(nbr_fea, emb_bond_W, emb_bond_b, P.NBbf);
  wtr2_kernel<<<dim3(10,12), 256, 0, stream>>>(pw[0].Wa, pw[0].Wb, P.Wt, P.sums0);

  conv_pass(0);
  conv_pass(1);
  conv_pass(2);

  pool_a_kernel<<<NCRY, 128, 0, stream>>>(P.Abf, P.pooled);
  pool_n_kernel<<<NCRY, 768, 0, stream>>>(P.NBbf, P.pooled);
  muz_kernel<<<1, 256, 0, stream>>>(P.pooled, mu_W, mu_b, lv_W, lv_b, P.eps,
                                    out + O_MU, out + O_LV, out + O_Z, P.zws);
  compute_f_kernel<<<NCRY, 256, 0, stream>>>(P.zws, dec_W, dec_b, P.pooled, P.fbuf);
  dec_atom_kernel<<<N_ATOM*128/256, 256, 0, stream>>>(P.Abf, P.fbuf);
  dim3 gdb(N_ATOM, 3);
  dec_bond_kernel<<<gdb, 256, 0, stream>>>(P.NBbf, P.fbuf);

  conv_pass(3);
  conv_pass(4);
  conv_pass(5);

  embed_atom2_kernel<<<N_ATOM, 128, 0, stream>>>(P.Abf, emb_atom2_W, emb_atom2_b, za2);
  bproj_kernel<<<NM/6, 256, 0, stream>>>(P.NBbf, emb_bond2_W, emb_bond2_b, bproj);
  zdec_v2<<<21600, 256, 0, stream>>>(za2, bproj, idx, out + O_ZDEC);
}

// Round 13
// 1648.801 us; speedup vs baseline: 1.6452x; 1.4800x over previous
//
#include <hip/hip_runtime.h>
#include <hip/hip_bf16.h>
#include <hip/hip_fp16.h>
#include <cstdint>
#include <cstddef>

// ---------------- constants ----------------
#define N_ATOM 16384
#define M_NBR  12
#define NCRY   128
#define NM     (N_ATOM*M_NBR) // 196608

// output offsets (floats)
#define O_ZDEC 0
#define O_MU   44236800
#define O_LV   44237056
#define O_Z    44237312
#define O_TIF  44237568

typedef unsigned short ushort_t;
typedef float f32x4 __attribute__((ext_vector_type(4)));
typedef short bf16x8 __attribute__((ext_vector_type(8)));
typedef unsigned int u32x4 __attribute__((ext_vector_type(4)));

// fast-math activation helpers (v_exp/v_log/v_rcp paths; ~1e-7 rel err, fine vs 0.2525 thr)
__device__ __forceinline__ float sigmoidf_(float x){
  return __fdividef(1.f, 1.f + __expf(-x));
}
__device__ __forceinline__ float softplusf_(float x){
  return fmaxf(x,0.f) + 0.69314718056f * __log2f(1.f + __expf(-fabsf(x)));
}
__device__ __forceinline__ uint32_t rotl32_(uint32_t x, int r){ return (x<<r)|(x>>(32-r)); }
__device__ __forceinline__ float bf2f(ushort_t u){ return __uint_as_float(((uint32_t)u)<<16); }
__device__ __forceinline__ ushort_t f2bf(float x){
  uint32_t u = __float_as_uint(x);
  uint32_t r = (u + 0x7FFFu + ((u>>16)&1u)) >> 16;
  return (ushort_t)r;
}

// async global->LDS, 16B per lane; LDS dest = wave-uniform base + lane*16
#define GLDS16(g, l) __builtin_amdgcn_global_load_lds( \
    (const __attribute__((address_space(1))) void*)(g), \
    (__attribute__((address_space(3))) void*)(l), 16, 0, 0)

// ---------------- eps = jax.random.normal(key(42), (128,2)) ----------------
// PRECISE math here (must track JAX reference closely)
__global__ void gen_eps_kernel(float* __restrict__ eps){
  int j = threadIdx.x; // 256
  const uint32_t k0 = 0u, k1 = 42u;
  const uint32_t ks2 = k0 ^ k1 ^ 0x1BD11BDAu;
  uint32_t x0 = 0u + k0;
  uint32_t x1 = (uint32_t)j + k1;
#define RND_(r) { x0 += x1; x1 = rotl32_(x1, r); x1 ^= x0; }
  RND_(13) RND_(15) RND_(26) RND_(6)  x0 += k1;  x1 += ks2 + 1u;
  RND_(17) RND_(29) RND_(16) RND_(24) x0 += ks2; x1 += k0 + 2u;
  RND_(13) RND_(15) RND_(26) RND_(6)  x0 += k0;  x1 += k1 + 3u;
  RND_(17) RND_(29) RND_(16) RND_(24) x0 += k1;  x1 += ks2 + 4u;
  RND_(13) RND_(15) RND_(26) RND_(6)  x0 += ks2; x1 += k0 + 5u;
#undef RND_
  uint32_t bits = x0 ^ x1;
  float f = __uint_as_float((bits >> 9) | 0x3f800000u) - 1.0f;
  float u = __fadd_rn(__fmul_rn(f, 1.99999994f), -0.99999994f);
  u = fmaxf(-0.99999994f, u);
  float w = -log1pf(-u*u);
  float p;
  if (w < 5.0f){
    w -= 2.5f;
    p = 2.81022636e-08f;
    p = fmaf(p, w, 3.43273939e-07f);
    p = fmaf(p, w, -3.5233877e-06f);
    p = fmaf(p, w, -4.39150654e-06f);
    p = fmaf(p, w, 0.00021858087f);
    p = fmaf(p, w, -0.00125372503f);
    p = fmaf(p, w, -0.00417768164f);
    p = fmaf(p, w, 0.246640727f);
    p = fmaf(p, w, 1.50140941f);
  } else {
    w = sqrtf(w) - 3.0f;
    p = -0.000200214257f;
    p = fmaf(p, w, 0.000100950558f);
    p = fmaf(p, w, 0.00134934322f);
    p = fmaf(p, w, -0.00367342844f);
    p = fmaf(p, w, 0.00573950773f);
    p = fmaf(p, w, -0.0076224613f);
    p = fmaf(p, w, 0.00943887047f);
    p = fmaf(p, w, 1.00167406f);
    p = fmaf(p, w, 2.83297682f);
  }
  eps[j] = 1.41421356237f * (p * u);
}

// ---------------- total_input_fea output (coalesced, NT stores: true output) ------
__global__ void tif_v2(const float* __restrict__ atom, const float* __restrict__ nbr,
                       const int* __restrict__ idx, float* __restrict__ out){
  int e0 = blockIdx.x*2048 + threadIdx.x;
#pragma unroll
  for (int i=0;i<8;++i){
    int e = e0 + i*256;
    int r = e/225, c = e - r*225;
    float v;
    if (c < 92)       v = atom[(r/12)*92 + c];
    else if (c < 184) v = atom[idx[r]*92 + (c-92)];
    else              v = nbr[(size_t)r*41 + (c-184)];
    __builtin_nontemporal_store(v, out + (size_t)e);
  }
}

// ---------------- embeddings (write bf16 masters) ----------------
__global__ void embed_atom_kernel(const float* __restrict__ atom, const float* __restrict__ W,
                                  const float* __restrict__ bias, ushort_t* __restrict__ a0){
  __shared__ float row[92];
  int i = blockIdx.x; int t = threadIdx.x; // 128
  if (t < 92) row[t] = atom[i*92+t];
  __syncthreads();
  float s = bias[t];
#pragma unroll
  for (int k=0;k<92;++k) s = fmaf(row[k], W[k*128+t], s);
  a0[(size_t)i*128+t] = f2bf(s);
}

__global__ void embed_bond_kernel(const float* __restrict__ nbr, const float* __restrict__ W,
                                  const float* __restrict__ bias, ushort_t* __restrict__ nb0){
  __shared__ float rows[4][41];
  int r0 = blockIdx.x*4; int t = threadIdx.x; // 256
  if (t < 164) rows[t/41][t%41] = nbr[(size_t)r0*41 + t];
  __syncthreads();
  int rr = t >> 6, c = t & 63;
  float s = bias[c];
#pragma unroll
  for (int k=0;k<41;++k) s = fmaf(rows[rr][k], W[k*64+c], s);
  nb0[(size_t)(r0+rr)*64 + c] = f2bf(s);
}

// ---------------- weight transpose (pass 0) + stats zeroing ----------
__global__ void wtr2_kernel(const float* __restrict__ Wa, const float* __restrict__ Wb,
                            ushort_t* __restrict__ Wt, float* __restrict__ zstats){
  __shared__ ushort_t tile[32][33];
  if (blockIdx.x == 0 && blockIdx.y == 0){
#pragma unroll
    for (int k=0;k<4;++k) zstats[threadIdx.x + k*256] = 0.f;
  }
  int by = blockIdx.y;
  const float* W; int NO, o0, obase;
  if (by < 8){ W = Wa; NO = 256; o0 = by*32; obase = o0; }
  else       { W = Wb; NO = 128; o0 = (by-8)*32; obase = 256 + o0; }
  int k0 = blockIdx.x*32;
  int tx = threadIdx.x & 31, ty = threadIdx.x >> 5; // 256 thr
#pragma unroll
  for (int i = ty; i < 32; i += 8)
    tile[i][tx] = f2bf(W[(size_t)(k0+i)*NO + o0 + tx]);
  __syncthreads();
#pragma unroll
  for (int i = ty; i < 32; i += 8)
    Wt[(size_t)(obase+i)*320 + k0 + tx] = tile[tx][i];
}

// ---------------- MFMA conv GEMM v8: counted-vmcnt software pipeline + setprio ----
__launch_bounds__(256, 2)
__global__ void conv_gemm_v8(const ushort_t* __restrict__ a_bf, const ushort_t* __restrict__ nb_bf,
                             const int* __restrict__ idx, const ushort_t* __restrict__ Wt,
                             __half* __restrict__ O, float* __restrict__ sums){
  __shared__ ushort_t sm[34816];   // staging: As 2x8192 @0, Bs 2x4096 @16384; epilogue [256][136]
  __shared__ float sqred[256];     // 128 sum + 128 ssq (this col block)
  __shared__ int idxs[256];
  ushort_t* As = sm;
  ushort_t* Bs = sm + 16384;
  const int t = threadIdx.x;
  const int lane = t & 63;
  const int w = t >> 6;
  const int lm = lane & 15, lg = lane >> 4;
  const int row0 = blockIdx.x * 256;
  const int cb   = blockIdx.y;          // col-block 0..2
  const int col0 = cb * 128;
  __half* Ob = O + (size_t)cb * ((size_t)NM*128);

  idxs[t] = idx[row0 + t];   // first consumed by stage(4) -> many barriers later
  sqred[t] = 0.f;

  auto stage = [&](int ks, int b_){
    ushort_t* Ad = As + b_*8192;
    ushort_t* Bd = Bs + b_*4096;
#pragma unroll
    for (int i=0;i<4;++i){
      int e = t + i*256;              // 0..1023
      int r = e >> 2, ch = e & 3;
      const ushort_t* ga;
      if (ks < 4)      ga = a_bf + (size_t)((row0+r)/12)*128 + ks*32 + ch*8;
      else if (ks < 8) ga = a_bf + (size_t)idxs[r]*128 + (ks-4)*32 + ch*8;
      else             ga = nb_bf + (size_t)(row0+r)*64 + (ks-8)*32 + ch*8;
      GLDS16(ga, Ad + e*8);
    }
#pragma unroll
    for (int i=0;i<2;++i){
      int e = t + i*256;              // 0..511
      int r = e >> 2, ch = e & 3;
      GLDS16(Wt + (size_t)(col0+r)*320 + ks*32 + ch*8, Bd + e*8);
    }
  };

  stage(0, 0);                        // batch 0 in flight

  f32x4 acc[4][8] = {};
  int buf = 0;
#pragma unroll
  for (int ks = 0; ks < 10; ++ks){
    if (ks < 9){
      stage(ks+1, buf^1);             // batch ks+1 in flight (6 more)
      asm volatile("s_waitcnt vmcnt(6)" ::: "memory");  // batch ks landed (mine)
    } else {
      asm volatile("s_waitcnt vmcnt(0)" ::: "memory");  // final batch landed
    }
    __builtin_amdgcn_s_barrier();     // all waves' batch ks landed
    __builtin_amdgcn_sched_barrier(0);
    const ushort_t* Ab = As + buf*8192;
    const ushort_t* Bb = Bs + buf*4096;
    bf16x8 afr[4], bfr[8];
#pragma unroll
    for (int fm=0; fm<4; ++fm)
      afr[fm] = *(const bf16x8*)&Ab[(w*64 + fm*16 + lm)*32 + lg*8];
#pragma unroll
    for (int fn=0; fn<8; ++fn)
      bfr[fn] = *(const bf16x8*)&Bb[(fn*16 + lm)*32 + lg*8];
    __builtin_amdgcn_s_setprio(1);
#pragma unroll
    for (int fm=0; fm<4; ++fm)
#pragma unroll
      for (int fn=0; fn<8; ++fn)
        acc[fm][fn] = __builtin_amdgcn_mfma_f32_16x16x32_bf16(afr[fm], bfr[fn], acc[fm][fn], 0, 0, 0);
    __builtin_amdgcn_s_setprio(0);
    asm volatile("s_waitcnt lgkmcnt(0)" ::: "memory");  // my ds_reads of buf done
    __builtin_amdgcn_sched_barrier(0);                   // rule #18 fence
    __builtin_amdgcn_s_barrier();     // all waves done reading buf -> safe to overwrite
    buf ^= 1;
  }

  // epilogue: stage f16 tile [256][136] in LDS, then coalesced NT stores + sum/ssq
#pragma unroll
  for (int fm=0; fm<4; ++fm){
    int rw = w*64 + fm*16 + lg*4;
#pragma unroll
    for (int fn=0; fn<8; ++fn){
      int cl = fn*16 + lm;
#pragma unroll
      for (int j=0; j<4; ++j){
        __half h = __float2half(acc[fm][fn][j]);
        sm[(rw+j)*136 + cl] = *(ushort_t*)&h;
      }
    }
  }
  __syncthreads();

  const int cch = t & 15, rb = t >> 4;
  float s1[8] = {0.f,0.f,0.f,0.f,0.f,0.f,0.f,0.f};
  float s2[8] = {0.f,0.f,0.f,0.f,0.f,0.f,0.f,0.f};
#pragma unroll
  for (int i=0; i<16; ++i){
    int row = rb + i*16;
    u32x4 v = *(const u32x4*)&sm[row*136 + cch*8];
    __builtin_nontemporal_store(v, (u32x4*)(Ob + (size_t)(row0+row)*128 + cch*8));
    const __half* hp = (const __half*)&v;
#pragma unroll
    for (int k=0;k<8;++k){
      float f = __half2float(hp[k]);
      s1[k] += f;
      s2[k] += f*f;
    }
  }
#pragma unroll
  for (int k=0;k<8;++k){
    atomicAdd(&sqred[cch*8+k], s1[k]);
    atomicAdd(&sqred[128+cch*8+k], s2[k]);
  }
  __syncthreads();
  if (t < 128){
    atomicAdd(&sums[col0 + t], sqred[t]);          // sum
    atomicAdd(&sums[384 + col0 + t], sqred[128+t]);// ssq
  }
}

// ---------------- fused apply: ga (blocks 0..1023) + gb (blocks 1024..7167) ----
__global__ void apply_gagb(const __half* __restrict__ O0, const __half* __restrict__ O1,
                           const __half* __restrict__ O2, ushort_t* __restrict__ nb,
                           const float* __restrict__ sums,
                           const float* __restrict__ g1a, const float* __restrict__ b1a,
                           const float* __restrict__ g1b, const float* __restrict__ b1b,
                           float* __restrict__ asum, float* __restrict__ st){
  __shared__ float red[256];
  int bx = blockIdx.x;
  int t = threadIdx.x;
  if (bx < 1024){
    // ---- ga part: 16 atoms x 16 col-chunks ----
    red[t] = 0.f;
    int c8 = t & 15, al = t >> 4;
    int i = bx*16 + al;
    int c0 = c8*8;
    float gf[8], bfv[8], gc[8], bcv[8];
#pragma unroll
    for (int k=0;k<8;++k){
      int c = c0+k;
      float mf = sums[c]*(1.f/NM);
      float rf = rsqrtf(sums[384+c]*(1.f/NM) - mf*mf + 1e-5f);
      gf[k]  = g1a[c]*rf;      bfv[k] = b1a[c] - mf*gf[k];
      float mc = sums[c+128]*(1.f/NM);
      float rc = rsqrtf(sums[384+c+128]*(1.f/NM) - mc*mc + 1e-5f);
      gc[k]  = g1a[c+128]*rc;  bcv[k] = b1a[c+128] - mc*gc[k];
    }
    float s[8] = {0.f,0.f,0.f,0.f,0.f,0.f,0.f,0.f};
    size_t base = (size_t)i*12*128;
#pragma unroll
    for (int j=0;j<12;++j){
      u32x4 vf = __builtin_nontemporal_load((const u32x4*)(O0 + base + j*128 + c0));
      u32x4 vc = __builtin_nontemporal_load((const u32x4*)(O1 + base + j*128 + c0));
      const __half* hf = (const __half*)&vf;
      const __half* hc = (const __half*)&vc;
#pragma unroll
      for (int k=0;k<8;++k)
        s[k] += sigmoidf_(fmaf(__half2float(hf[k]), gf[k], bfv[k]))
              * softplusf_(fmaf(__half2float(hc[k]), gc[k], bcv[k]));
    }
    float* dst = asum + (size_t)i*128 + c0;
    __syncthreads();               // red zero visible before cross-thread atomics
#pragma unroll
    for (int k=0;k<8;++k){
      dst[k] = s[k];
      atomicAdd(&red[c0+k], s[k]);
      atomicAdd(&red[128+c0+k], s[k]*s[k]);
    }
    __syncthreads();
    atomicAdd(&st[t], red[t]);     // st[0..127] sum, st[128..255] ssq
  } else {
    // ---- gb part: 32 rows x 8 col-chunks ----
    int c8 = t & 7, rloc = t >> 3;
    int r = (bx-1024)*32 + rloc;
    int c0 = c8*8;
    float gf[8], bfv[8], gc[8], bcv[8];
#pragma unroll
    for (int k=0;k<8;++k){
      int c = c0+k;
      float mf = sums[256+c]*(1.f/NM);
      float rf = rsqrtf(sums[384+256+c]*(1.f/NM) - mf*mf + 1e-5f);
      gf[k]  = g1b[c]*rf;      bfv[k] = b1b[c] - mf*gf[k];
      float mc = sums[256+64+c]*(1.f/NM);
      float rc = rsqrtf(sums[384+256+64+c]*(1.f/NM) - mc*mc + 1e-5f);
      gc[k]  = g1b[c+64]*rc;   bcv[k] = b1b[c+64] - mc*gc[k];
    }
    size_t gbase = (size_t)r*128;
    u32x4 vf = __builtin_nontemporal_load((const u32x4*)(O2 + gbase + c0));
    u32x4 vc = __builtin_nontemporal_load((const u32x4*)(O2 + gbase + 64 + c0));
    const __half* hf = (const __half*)&vf;
    const __half* hc = (const __half*)&vc;
    ushort_t* np = nb + (size_t)r*64 + c0;
    u32x4 old = *(const u32x4*)np;
    const ushort_t* op = (const ushort_t*)&old;
    u32x4 outv;
    ushort_t* ov = (ushort_t*)&outv;
#pragma unroll
    for (int k=0;k<8;++k){
      float x = bf2f(op[k]) + sigmoidf_(fmaf(__half2float(hf[k]), gf[k], bfv[k]))
                            * softplusf_(fmaf(__half2float(hc[k]), gc[k], bcv[k]));
      ov[k] = f2bf(softplusf_(x));
    }
    *(u32x4*)np = outv;
  }
}

// ---------------- fused: apply_out1 (blocks 121..8312) + next-pass wtr (0..119)
//                  + next-pass stats zero (block 120) ----
__global__ void out1_wtr(ushort_t* __restrict__ a0, const float* __restrict__ asum,
                         const float* __restrict__ st, const float* __restrict__ g2a,
                         const float* __restrict__ b2a,
                         const float* __restrict__ Wa_next, const float* __restrict__ Wb_next,
                         ushort_t* __restrict__ Wt, float* __restrict__ zstats){
  __shared__ ushort_t tile[32][33];
  int bx = blockIdx.x;
  int t = threadIdx.x;
  if (bx < 120){
    if (Wa_next == nullptr) return;
    int by = bx / 10, kx = bx - by*10;
    const float* W; int NO, o0, obase;
    if (by < 8){ W = Wa_next; NO = 256; o0 = by*32; obase = o0; }
    else       { W = Wb_next; NO = 128; o0 = (by-8)*32; obase = 256 + o0; }
    int k0 = kx*32;
    int tx = t & 31, ty = t >> 5;
#pragma unroll
    for (int i = ty; i < 32; i += 8)
      tile[i][tx] = f2bf(W[(size_t)(k0+i)*NO + o0 + tx]);
    __syncthreads();
#pragma unroll
    for (int i = ty; i < 32; i += 8)
      Wt[(size_t)(obase+i)*320 + k0 + tx] = tile[tx][i];
  } else if (bx == 120){
    if (Wa_next == nullptr) return;
#pragma unroll
    for (int k=0;k<4;++k) zstats[t + k*256] = 0.f;
  } else {
    int e = (bx-121)*256 + t; // n*128
    int c = e & 127;
    float m  = st[c]*(1.f/N_ATOM);
    float var = st[128+c]*(1.f/N_ATOM) - m*m;
    float rs = rsqrtf(var + 1e-5f);
    float g = g2a[c]*rs;
    float b = b2a[c] - m*g;
    a0[e] = f2bf(softplusf_(bf2f(a0[e]) + fmaf(asum[e], g, b)));
  }
}

// ---------------- pooling / VAE / decode ----------------
__global__ void pool_a_kernel(const ushort_t* __restrict__ a, float* __restrict__ pooled){
  int b = blockIdx.x; int c = threadIdx.x; // 128
  float s = 0.f;
  for (int i=0;i<128;++i) s += bf2f(a[(size_t)((b<<7)+i)*128 + c]);
  pooled[b*896 + c] = softplusf_(s * (1.f/128.f));
}

__launch_bounds__(768)
__global__ void pool_n_kernel(const ushort_t* __restrict__ nb, float* __restrict__ pooled){
  int b = blockIdx.x; int t = threadIdx.x; // 768
  float s = 0.f;
  for (int i=0;i<128;++i) s += bf2f(nb[(size_t)((b<<7)+i)*768 + t]);
  pooled[b*896 + 128 + t] = softplusf_(s * (1.f/128.f));
}

__global__ void muz_kernel(const float* __restrict__ pooled, const float* __restrict__ muW,
                           const float* __restrict__ mub, const float* __restrict__ lvW,
                           const float* __restrict__ lvb, const float* __restrict__ eps,
                           float* __restrict__ out_mu, float* __restrict__ out_lv,
                           float* __restrict__ out_z, float* __restrict__ zws){
  int t = threadIdx.x; // 256 -> (b,l)
  int b = t >> 1, l = t & 1;
  const float* pr = pooled + b*896;
  float smu = mub[l], slv = lvb[l];
  for (int k=0;k<896;++k){
    float p = pr[k];
    smu = fmaf(p, muW[k*2+l], smu);
    slv = fmaf(p, lvW[k*2+l], slv);
  }
  out_mu[t] = smu; out_lv[t] = slv;
  float zv = fmaf(eps[t], __expf(0.5f*slv), smu);
  out_z[t] = zv; zws[t] = zv;
}

__global__ void compute_f_kernel(const float* __restrict__ zws, const float* __restrict__ decW,
                                 const float* __restrict__ decb, const float* __restrict__ pooled,
                                 float* __restrict__ f){
  int b = blockIdx.x;
  float z0 = zws[b*2], z1 = zws[b*2+1];
  for (int k = threadIdx.x; k < 896; k += 256){
    float zd = fmaf(z0, decW[k], fmaf(z1, decW[896+k], decb[k]));
    f[b*896+k] = __fdividef(zd, pooled[b*896+k]);
  }
}

__global__ void dec_atom_kernel(ushort_t* __restrict__ a, const float* __restrict__ f){
  int e = blockIdx.x*256+threadIdx.x; // n*128
  int c = e & 127; int b = e >> 14;
  a[e] = f2bf(softplusf_(bf2f(a[e]) * f[b*896 + c]));
}

__global__ void dec_bond_kernel(ushort_t* __restrict__ nb, const float* __restrict__ f){
  int i = blockIdx.x; int off = blockIdx.y*256 + threadIdx.x; // off < 768
  int b = i >> 7;
  size_t e = (size_t)i*768 + off;
  nb[e] = f2bf(softplusf_(bf2f(nb[e]) * f[b*896 + 128 + off]));
}

// ---------------- final embeddings ----------------
__global__ void embed_atom2_kernel(const ushort_t* __restrict__ a, const float* __restrict__ W,
                                   const float* __restrict__ bias, float* __restrict__ za2){
  __shared__ float row[128];
  int i = blockIdx.x; int t = threadIdx.x; // 128
  row[t] = bf2f(a[(size_t)i*128+t]);
  __syncthreads();
  if (t < 92){
    float s = bias[t];
#pragma unroll
    for (int k=0;k<128;++k) s = fmaf(row[k], W[k*92+t], s);
    za2[(size_t)i*92+t] = sigmoidf_(s);
  }
}

__global__ void bproj_kernel(const ushort_t* __restrict__ nb, const float* __restrict__ W,
                             const float* __restrict__ bias, float* __restrict__ bp){
  __shared__ float Ws[64][41];
  __shared__ float rows[6][64];
  int t = threadIdx.x; // 256
  for (int e=t; e<64*41; e+=256) Ws[e/41][e%41] = W[e];
  int r0 = blockIdx.x*6;
  for (int e=t; e<6*64; e+=256){
    int rr = e>>6, c = e&63;
    rows[rr][c] = bf2f(nb[(size_t)(r0+rr)*64 + c]);
  }
  __syncthreads();
  if (t < 246){
    int rr = t/41, o = t - rr*41;
    float s = bias[o];
#pragma unroll
    for (int k=0;k<64;++k) s = fmaf(rows[rr][k], Ws[k][o], s);
    bp[(size_t)(r0+rr)*41 + o] = sigmoidf_(s);
  }
}

__global__ void zdec_v2(const float* __restrict__ za2, const float* __restrict__ bp,
                        const int* __restrict__ idx, float* __restrict__ out){
  int e0 = blockIdx.x*2048 + threadIdx.x;
#pragma unroll
  for (int i=0;i<8;++i){
    int e = e0 + i*256;
    int r = e/225, c = e - r*225;
    float v;
    if (c < 92)       v = za2[(size_t)(r/12)*92 + c];
    else if (c < 184) v = za2[(size_t)idx[r]*92 + (c-92)];
    else              v = bp[(size_t)r*41 + (c-184)];
    __builtin_nontemporal_store(v, out + (size_t)e);
  }
}

// ---------------- host side ----------------
struct WsPlan {
  ushort_t *Abf, *NBbf, *Wt;
  __half* big;
  float *asum, *pooled, *fbuf, *zws, *eps, *sums0, *sums1;
};

struct PassW {
  const float *Wa,*Wb,*g1a,*b1a,*g1b,*b1b,*g2a,*b2a;
};

extern "C" void kernel_launch(void* const* d_in, const int* in_sizes, int n_in,
                              void* d_out, int out_size, void* d_ws, size_t ws_size,
                              hipStream_t stream) {
  (void)in_sizes; (void)n_in; (void)out_size; (void)ws_size;
  const float* atom_fea   = (const float*)d_in[0];
  const float* nbr_fea    = (const float*)d_in[1];
  const int*   idx        = (const int*)d_in[2];
  const float* emb_atom_W = (const float*)d_in[4];
  const float* emb_atom_b = (const float*)d_in[5];
  const float* emb_bond_W = (const float*)d_in[6];
  const float* emb_bond_b = (const float*)d_in[7];
  const float* emb_atom2_W= (const float*)d_in[8];
  const float* emb_atom2_b= (const float*)d_in[9];
  const float* emb_bond2_W= (const float*)d_in[10];
  const float* emb_bond2_b= (const float*)d_in[11];
  const float* mu_W       = (const float*)d_in[12];
  const float* mu_b       = (const float*)d_in[13];
  const float* lv_W       = (const float*)d_in[14];
  const float* lv_b       = (const float*)d_in[15];
  const float* dec_W      = (const float*)d_in[16];
  const float* dec_b      = (const float*)d_in[17];
  const float* c1_Wa  = (const float*)d_in[18];
  const float* c1_Wb  = (const float*)d_in[19];
  const float* c1_g1a = (const float*)d_in[20];
  const float* c1_b1a = (const float*)d_in[21];
  const float* c1_g1b = (const float*)d_in[22];
  const float* c1_b1b = (const float*)d_in[23];
  const float* c1_g2a = (const float*)d_in[24];
  const float* c1_b2a = (const float*)d_in[25];
  const float* c2_Wa  = (const float*)d_in[26];
  const float* c2_Wb  = (const float*)d_in[27];
  const float* c2_g1a = (const float*)d_in[28];
  const float* c2_b1a = (const float*)d_in[29];
  const float* c2_g1b = (const float*)d_in[30];
  const float* c2_b1b = (const float*)d_in[31];
  const float* c2_g2a = (const float*)d_in[32];
  const float* c2_b2a = (const float*)d_in[33];

  float* out = (float*)d_out;

  WsPlan P;
  char* w = (char*)d_ws;
  auto alloc = [&](size_t bytes) -> char* {
    char* p = w; w += (bytes + 255) & ~(size_t)255; return p;
  };
  P.Abf    = (ushort_t*)alloc((size_t)N_ATOM*128*2);
  P.NBbf   = (ushort_t*)alloc((size_t)NM*64*2);
  P.big    = (__half*)  alloc((size_t)NM*384*2);
  P.asum   = (float*)   alloc((size_t)N_ATOM*128*4);
  P.pooled = (float*)   alloc(114688*4);
  P.fbuf   = (float*)   alloc(114688*4);
  P.Wt     = (ushort_t*)alloc(384*320*2);
  P.zws    = (float*)   alloc(256*4);
  P.eps    = (float*)   alloc(256*4);
  P.sums0  = (float*)   alloc(1024*4);   // slot 0: sums[768] + st[256]
  P.sums1  = (float*)   alloc(1024*4);   // slot 1
  float* za2   = P.asum;                 // reuse after conv stacks
  float* bproj = (float*)P.big;          // reuse big in the final phase

  PassW pw[6] = {
    { c1_Wa,            c1_Wb,            c1_g1a,       c1_b1a,       c1_g1b,       c1_b1b,       c1_g2a,       c1_b2a       },
    { c1_Wa+320*256,    c1_Wb+320*128,    c1_g1a+256,   c1_b1a+256,   c1_g1b+128,   c1_b1b+128,   c1_g2a+128,   c1_b2a+128   },
    { c1_Wa+2*320*256,  c1_Wb+2*320*128,  c1_g1a+2*256, c1_b1a+2*256, c1_g1b+2*128, c1_b1b+2*128, c1_g2a+2*128, c1_b2a+2*128 },
    { c2_Wa,            c2_Wb,            c2_g1a,       c2_b1a,       c2_g1b,       c2_b1b,       c2_g2a,       c2_b2a       },
    { c2_Wa+320*256,    c2_Wb+320*128,    c2_g1a+256,   c2_b1a+256,   c2_g1b+128,   c2_b1b+128,   c2_g2a+128,   c2_b2a+128   },
    { c2_Wa+2*320*256,  c2_Wb+2*320*128,  c2_g1a+2*256, c2_b1a+2*256, c2_g1b+2*128, c2_b1b+2*128, c2_g2a+2*128, c2_b2a+2*128 },
  };

  auto conv_pass = [&](int p){
    float* sums_cur = (p & 1) ? P.sums1 : P.sums0;
    float* sums_nxt = (p & 1) ? P.sums0 : P.sums1;
    const __half* O0 = P.big;
    const __half* O1 = P.big + (size_t)NM*128;
    const __half* O2 = P.big + (size_t)NM*256;
    conv_gemm_v8<<<dim3(NM/256, 3), 256, 0, stream>>>(P.Abf, P.NBbf, idx, P.Wt, P.big, sums_cur);
    apply_gagb<<<7168, 256, 0, stream>>>(O0, O1, O2, P.NBbf, sums_cur,
                                         pw[p].g1a, pw[p].b1a, pw[p].g1b, pw[p].b1b,
                                         P.asum, sums_cur + 768);
    const float* Wa_n = (p < 5) ? pw[p+1].Wa : nullptr;
    const float* Wb_n = (p < 5) ? pw[p+1].Wb : nullptr;
    out1_wtr<<<8313, 256, 0, stream>>>(P.Abf, P.asum, sums_cur + 768,
                                       pw[p].g2a, pw[p].b2a, Wa_n, Wb_n, P.Wt, sums_nxt);
  };

  gen_eps_kernel<<<1, 256, 0, stream>>>(P.eps);
  tif_v2<<<21600, 256, 0, stream>>>(atom_fea, nbr_fea, idx, out + O_TIF);
  embed_atom_kernel<<<N_ATOM, 128, 0, stream>>>(atom_fea, emb_atom_W, emb_atom_b, P.Abf);
  embed_bond_kernel<<<NM/4, 256, 0, stream>>>(nbr_fea, emb_bond_W, emb_bond_b, P.NBbf);
  wtr2_kernel<<<dim3(10,12), 256, 0, stream>>>(pw[0].Wa, pw[0].Wb, P.Wt, P.sums0);

  conv_pass(0);
  conv_pass(1);
  conv_pass(2);

  pool_a_kernel<<<NCRY, 128, 0, stream>>>(P.Abf, P.pooled);
  pool_n_kernel<<<NCRY, 768, 0, stream>>>(P.NBbf, P.pooled);
  muz_kernel<<<1, 256, 0, stream>>>(P.pooled, mu_W, mu_b, lv_W, lv_b, P.eps,
                                    out + O_MU, out + O_LV, out + O_Z, P.zws);
  compute_f_kernel<<<NCRY, 256, 0, stream>>>(P.zws, dec_W, dec_b, P.pooled, P.fbuf);
  dec_atom_kernel<<<N_ATOM*128/256, 256, 0, stream>>>(P.Abf, P.fbuf);
  dim3 gdb(N_ATOM, 3);
  dec_bond_kernel<<<gdb, 256, 0, stream>>>(P.NBbf, P.fbuf);

  conv_pass(3);
  conv_pass(4);
  conv_pass(5);

  embed_atom2_kernel<<<N_ATOM, 128, 0, stream>>>(P.Abf, emb_atom2_W, emb_atom2_b, za2);
  bproj_kernel<<<NM/6, 256, 0, stream>>>(P.NBbf, emb_bond2_W, emb_bond2_b, bproj);
  zdec_v2<<<21600, 256, 0, stream>>>(za2, bproj, idx, out + O_ZDEC);
}

// Round 14
// 1630.385 us; speedup vs baseline: 1.6638x; 1.0113x over previous
//
#include <hip/hip_runtime.h>
#include <hip/hip_bf16.h>
#include <hip/hip_fp16.h>
#include <cstdint>
#include <cstddef>

// ---------------- constants ----------------
#define N_ATOM 16384
#define M_NBR  12
#define NCRY   128
#define NM     (N_ATOM*M_NBR) // 196608

// output offsets (floats)
#define O_ZDEC 0
#define O_MU   44236800
#define O_LV   44237056
#define O_Z    44237312
#define O_TIF  44237568

typedef unsigned short ushort_t;
typedef float f32x4 __attribute__((ext_vector_type(4)));
typedef short bf16x8 __attribute__((ext_vector_type(8)));
typedef unsigned int u32x4 __attribute__((ext_vector_type(4)));

// fast-math activation helpers (v_exp/v_log/v_rcp paths; ~1e-7 rel err, fine vs 0.2525 thr)
__device__ __forceinline__ float sigmoidf_(float x){
  return __fdividef(1.f, 1.f + __expf(-x));
}
__device__ __forceinline__ float softplusf_(float x){
  return fmaxf(x,0.f) + 0.69314718056f * __log2f(1.f + __expf(-fabsf(x)));
}
__device__ __forceinline__ uint32_t rotl32_(uint32_t x, int r){ return (x<<r)|(x>>(32-r)); }
__device__ __forceinline__ float bf2f(ushort_t u){ return __uint_as_float(((uint32_t)u)<<16); }
__device__ __forceinline__ ushort_t f2bf(float x){
  uint32_t u = __float_as_uint(x);
  uint32_t r = (u + 0x7FFFu + ((u>>16)&1u)) >> 16;
  return (ushort_t)r;
}

// async global->LDS, 16B per lane; LDS dest = wave-uniform base + lane*16
#define GLDS16(g, l) __builtin_amdgcn_global_load_lds( \
    (const __attribute__((address_space(1))) void*)(g), \
    (__attribute__((address_space(3))) void*)(l), 16, 0, 0)

// ---------------- eps = jax.random.normal(key(42), (128,2)) ----------------
// PRECISE math here (must track JAX reference closely)
__global__ void gen_eps_kernel(float* __restrict__ eps){
  int j = threadIdx.x; // 256
  const uint32_t k0 = 0u, k1 = 42u;
  const uint32_t ks2 = k0 ^ k1 ^ 0x1BD11BDAu;
  uint32_t x0 = 0u + k0;
  uint32_t x1 = (uint32_t)j + k1;
#define RND_(r) { x0 += x1; x1 = rotl32_(x1, r); x1 ^= x0; }
  RND_(13) RND_(15) RND_(26) RND_(6)  x0 += k1;  x1 += ks2 + 1u;
  RND_(17) RND_(29) RND_(16) RND_(24) x0 += ks2; x1 += k0 + 2u;
  RND_(13) RND_(15) RND_(26) RND_(6)  x0 += k0;  x1 += k1 + 3u;
  RND_(17) RND_(29) RND_(16) RND_(24) x0 += k1;  x1 += ks2 + 4u;
  RND_(13) RND_(15) RND_(26) RND_(6)  x0 += ks2; x1 += k0 + 5u;
#undef RND_
  uint32_t bits = x0 ^ x1;
  float f = __uint_as_float((bits >> 9) | 0x3f800000u) - 1.0f;
  float u = __fadd_rn(__fmul_rn(f, 1.99999994f), -0.99999994f);
  u = fmaxf(-0.99999994f, u);
  float w = -log1pf(-u*u);
  float p;
  if (w < 5.0f){
    w -= 2.5f;
    p = 2.81022636e-08f;
    p = fmaf(p, w, 3.43273939e-07f);
    p = fmaf(p, w, -3.5233877e-06f);
    p = fmaf(p, w, -4.39150654e-06f);
    p = fmaf(p, w, 0.00021858087f);
    p = fmaf(p, w, -0.00125372503f);
    p = fmaf(p, w, -0.00417768164f);
    p = fmaf(p, w, 0.246640727f);
    p = fmaf(p, w, 1.50140941f);
  } else {
    w = sqrtf(w) - 3.0f;
    p = -0.000200214257f;
    p = fmaf(p, w, 0.000100950558f);
    p = fmaf(p, w, 0.00134934322f);
    p = fmaf(p, w, -0.00367342844f);
    p = fmaf(p, w, 0.00573950773f);
    p = fmaf(p, w, -0.0076224613f);
    p = fmaf(p, w, 0.00943887047f);
    p = fmaf(p, w, 1.00167406f);
    p = fmaf(p, w, 2.83297682f);
  }
  eps[j] = 1.41421356237f * (p * u);
}

// ---------------- total_input_fea output (coalesced, NT stores: true output) ------
__global__ void tif_v2(const float* __restrict__ atom, const float* __restrict__ nbr,
                       const int* __restrict__ idx, float* __restrict__ out){
  int e0 = blockIdx.x*2048 + threadIdx.x;
#pragma unroll
  for (int i=0;i<8;++i){
    int e = e0 + i*256;
    int r = e/225, c = e - r*225;
    float v;
    if (c < 92)       v = atom[(r/12)*92 + c];
    else if (c < 184) v = atom[idx[r]*92 + (c-92)];
    else              v = nbr[(size_t)r*41 + (c-184)];
    __builtin_nontemporal_store(v, out + (size_t)e);
  }
}

// ---------------- embeddings (write bf16 masters) ----------------
__global__ void embed_atom_kernel(const float* __restrict__ atom, const float* __restrict__ W,
                                  const float* __restrict__ bias, ushort_t* __restrict__ a0){
  __shared__ float row[92];
  int i = blockIdx.x; int t = threadIdx.x; // 128
  if (t < 92) row[t] = atom[i*92+t];
  __syncthreads();
  float s = bias[t];
#pragma unroll
  for (int k=0;k<92;++k) s = fmaf(row[k], W[k*128+t], s);
  a0[(size_t)i*128+t] = f2bf(s);
}

__global__ void embed_bond_kernel(const float* __restrict__ nbr, const float* __restrict__ W,
                                  const float* __restrict__ bias, ushort_t* __restrict__ nb0){
  __shared__ float rows[4][41];
  int r0 = blockIdx.x*4; int t = threadIdx.x; // 256
  if (t < 164) rows[t/41][t%41] = nbr[(size_t)r0*41 + t];
  __syncthreads();
  int rr = t >> 6, c = t & 63;
  float s = bias[c];
#pragma unroll
  for (int k=0;k<41;++k) s = fmaf(rows[rr][k], W[k*64+c], s);
  nb0[(size_t)(r0+rr)*64 + c] = f2bf(s);
}

// ---------------- weight transpose (pass 0) + stats zeroing ----------
__global__ void wtr2_kernel(const float* __restrict__ Wa, const float* __restrict__ Wb,
                            ushort_t* __restrict__ Wt, float* __restrict__ zstats){
  __shared__ ushort_t tile[32][33];
  if (blockIdx.x == 0 && blockIdx.y == 0){
#pragma unroll
    for (int k=0;k<4;++k) zstats[threadIdx.x + k*256] = 0.f;
  }
  int by = blockIdx.y;
  const float* W; int NO, o0, obase;
  if (by < 8){ W = Wa; NO = 256; o0 = by*32; obase = o0; }
  else       { W = Wb; NO = 128; o0 = (by-8)*32; obase = 256 + o0; }
  int k0 = blockIdx.x*32;
  int tx = threadIdx.x & 31, ty = threadIdx.x >> 5; // 256 thr
#pragma unroll
  for (int i = ty; i < 32; i += 8)
    tile[i][tx] = f2bf(W[(size_t)(k0+i)*NO + o0 + tx]);
  __syncthreads();
#pragma unroll
  for (int i = ty; i < 32; i += 8)
    Wt[(size_t)(obase+i)*320 + k0 + tx] = tile[tx][i];
}

// ---------------- MFMA conv GEMM v9: 3-stage counted-vmcnt pipeline + setprio ----
// BM=256 x BN=128 per block, 4 waves (each 64 rows x 128 cols, acc 4x8 f32x4).
// BK=32 TRIPLE-buffered via global_load_lds (6 loads/thread/stage; 2 batches in flight).
// vmcnt: steady=12 (2 batches out), ks=8 -> 6, ks=9 -> 0. Output [3][NM][128], NT stores.
// Dynamic LDS: As 3x16KB + Bs 3x8KB = 72KB, sqred 1KB, idxs 1KB = 75776 B (2 blocks/CU).
#define GEMM_LDS_V9 75776
__launch_bounds__(256, 2)
__global__ void conv_gemm_v9(const ushort_t* __restrict__ a_bf, const ushort_t* __restrict__ nb_bf,
                             const int* __restrict__ idx, const ushort_t* __restrict__ Wt,
                             __half* __restrict__ O, float* __restrict__ sums){
  extern __shared__ char smraw[];
  ushort_t* sm   = (ushort_t*)smraw;           // As: 3x8192 ushorts @0; Bs: 3x4096 @24576
  float*   sqred = (float*)(smraw + 73728);    // 256 floats
  int*     idxs  = (int*)(smraw + 74752);      // 256 ints
  ushort_t* As = sm;
  ushort_t* Bs = sm + 24576;
  const int t = threadIdx.x;
  const int lane = t & 63;
  const int w = t >> 6;
  const int lm = lane & 15, lg = lane >> 4;
  const int row0 = blockIdx.x * 256;
  const int cb   = blockIdx.y;          // col-block 0..2
  const int col0 = cb * 128;
  __half* Ob = O + (size_t)cb * ((size_t)NM*128);

  idxs[t] = idx[row0 + t];   // first consumed by stage(4), issued at ks=2 (after barriers)
  sqred[t] = 0.f;

  auto stage = [&](int ks, int b_){
    ushort_t* Ad = As + b_*8192;
    ushort_t* Bd = Bs + b_*4096;
#pragma unroll
    for (int i=0;i<4;++i){
      int e = t + i*256;              // 0..1023
      int r = e >> 2, ch = e & 3;
      const ushort_t* ga;
      if (ks < 4)      ga = a_bf + (size_t)((row0+r)/12)*128 + ks*32 + ch*8;
      else if (ks < 8) ga = a_bf + (size_t)idxs[r]*128 + (ks-4)*32 + ch*8;
      else             ga = nb_bf + (size_t)(row0+r)*64 + (ks-8)*32 + ch*8;
      GLDS16(ga, Ad + e*8);
    }
#pragma unroll
    for (int i=0;i<2;++i){
      int e = t + i*256;              // 0..511
      int r = e >> 2, ch = e & 3;
      GLDS16(Wt + (size_t)(col0+r)*320 + ks*32 + ch*8, Bd + e*8);
    }
  };

  stage(0, 0);                        // batches 0,1 in flight (12 loads/thread)
  stage(1, 1);

  f32x4 acc[4][8] = {};
#pragma unroll
  for (int ks = 0; ks < 10; ++ks){
    const int buf = ks % 3;
    if (ks < 8){
      stage(ks+2, (ks+2) % 3);        // 3rd batch in flight (18 out)
      asm volatile("s_waitcnt vmcnt(12)" ::: "memory");  // oldest 6 (batch ks) landed
    } else if (ks == 8){
      asm volatile("s_waitcnt vmcnt(6)" ::: "memory");   // batch 8 landed (9 in flight)
    } else {
      asm volatile("s_waitcnt vmcnt(0)" ::: "memory");   // batch 9 landed
    }
    __builtin_amdgcn_s_barrier();     // all waves' batch ks landed
    __builtin_amdgcn_sched_barrier(0);
    const ushort_t* Ab = As + buf*8192;
    const ushort_t* Bb = Bs + buf*4096;
    bf16x8 afr[4], bfr[8];
#pragma unroll
    for (int fm=0; fm<4; ++fm)
      afr[fm] = *(const bf16x8*)&Ab[(w*64 + fm*16 + lm)*32 + lg*8];
#pragma unroll
    for (int fn=0; fn<8; ++fn)
      bfr[fn] = *(const bf16x8*)&Bb[(fn*16 + lm)*32 + lg*8];
    __builtin_amdgcn_s_setprio(1);
#pragma unroll
    for (int fm=0; fm<4; ++fm)
#pragma unroll
      for (int fn=0; fn<8; ++fn)
        acc[fm][fn] = __builtin_amdgcn_mfma_f32_16x16x32_bf16(afr[fm], bfr[fn], acc[fm][fn], 0, 0, 0);
    __builtin_amdgcn_s_setprio(0);
    asm volatile("s_waitcnt lgkmcnt(0)" ::: "memory");  // my ds_reads of buf done
    __builtin_amdgcn_sched_barrier(0);                   // rule #18 fence
    __builtin_amdgcn_s_barrier();     // all waves done reading buf -> safe to overwrite
  }

  // epilogue: stage f16 tile [256][136] in LDS (69632 B, below sqred), NT stores + sum/ssq
#pragma unroll
  for (int fm=0; fm<4; ++fm){
    int rw = w*64 + fm*16 + lg*4;
#pragma unroll
    for (int fn=0; fn<8; ++fn){
      int cl = fn*16 + lm;
#pragma unroll
      for (int j=0; j<4; ++j){
        __half h = __float2half(acc[fm][fn][j]);
        sm[(rw+j)*136 + cl] = *(ushort_t*)&h;
      }
    }
  }
  __syncthreads();

  const int cch = t & 15, rb = t >> 4;
  float s1[8] = {0.f,0.f,0.f,0.f,0.f,0.f,0.f,0.f};
  float s2[8] = {0.f,0.f,0.f,0.f,0.f,0.f,0.f,0.f};
#pragma unroll
  for (int i=0; i<16; ++i){
    int row = rb + i*16;
    u32x4 v = *(const u32x4*)&sm[row*136 + cch*8];
    __builtin_nontemporal_store(v, (u32x4*)(Ob + (size_t)(row0+row)*128 + cch*8));
    const __half* hp = (const __half*)&v;
#pragma unroll
    for (int k=0;k<8;++k){
      float f = __half2float(hp[k]);
      s1[k] += f;
      s2[k] += f*f;
    }
  }
#pragma unroll
  for (int k=0;k<8;++k){
    atomicAdd(&sqred[cch*8+k], s1[k]);
    atomicAdd(&sqred[128+cch*8+k], s2[k]);
  }
  __syncthreads();
  if (t < 128){
    atomicAdd(&sums[col0 + t], sqred[t]);          // sum
    atomicAdd(&sums[384 + col0 + t], sqred[128+t]);// ssq
  }
}

// ---------------- fused apply: ga (blocks 0..1023) + gb (blocks 1024..7167) ----
__global__ void apply_gagb(const __half* __restrict__ O0, const __half* __restrict__ O1,
                           const __half* __restrict__ O2, ushort_t* __restrict__ nb,
                           const float* __restrict__ sums,
                           const float* __restrict__ g1a, const float* __restrict__ b1a,
                           const float* __restrict__ g1b, const float* __restrict__ b1b,
                           float* __restrict__ asum, float* __restrict__ st){
  __shared__ float red[256];
  int bx = blockIdx.x;
  int t = threadIdx.x;
  if (bx < 1024){
    // ---- ga part: 16 atoms x 16 col-chunks ----
    red[t] = 0.f;
    int c8 = t & 15, al = t >> 4;
    int i = bx*16 + al;
    int c0 = c8*8;
    float gf[8], bfv[8], gc[8], bcv[8];
#pragma unroll
    for (int k=0;k<8;++k){
      int c = c0+k;
      float mf = sums[c]*(1.f/NM);
      float rf = rsqrtf(sums[384+c]*(1.f/NM) - mf*mf + 1e-5f);
      gf[k]  = g1a[c]*rf;      bfv[k] = b1a[c] - mf*gf[k];
      float mc = sums[c+128]*(1.f/NM);
      float rc = rsqrtf(sums[384+c+128]*(1.f/NM) - mc*mc + 1e-5f);
      gc[k]  = g1a[c+128]*rc;  bcv[k] = b1a[c+128] - mc*gc[k];
    }
    float s[8] = {0.f,0.f,0.f,0.f,0.f,0.f,0.f,0.f};
    size_t base = (size_t)i*12*128;
#pragma unroll
    for (int j=0;j<12;++j){
      u32x4 vf = __builtin_nontemporal_load((const u32x4*)(O0 + base + j*128 + c0));
      u32x4 vc = __builtin_nontemporal_load((const u32x4*)(O1 + base + j*128 + c0));
      const __half* hf = (const __half*)&vf;
      const __half* hc = (const __half*)&vc;
#pragma unroll
      for (int k=0;k<8;++k)
        s[k] += sigmoidf_(fmaf(__half2float(hf[k]), gf[k], bfv[k]))
              * softplusf_(fmaf(__half2float(hc[k]), gc[k], bcv[k]));
    }
    float* dst = asum + (size_t)i*128 + c0;
    __syncthreads();               // red zero visible before cross-thread atomics
#pragma unroll
    for (int k=0;k<8;++k){
      dst[k] = s[k];
      atomicAdd(&red[c0+k], s[k]);
      atomicAdd(&red[128+c0+k], s[k]*s[k]);
    }
    __syncthreads();
    atomicAdd(&st[t], red[t]);     // st[0..127] sum, st[128..255] ssq
  } else {
    // ---- gb part: 32 rows x 8 col-chunks ----
    int c8 = t & 7, rloc = t >> 3;
    int r = (bx-1024)*32 + rloc;
    int c0 = c8*8;
    float gf[8], bfv[8], gc[8], bcv[8];
#pragma unroll
    for (int k=0;k<8;++k){
      int c = c0+k;
      float mf = sums[256+c]*(1.f/NM);
      float rf = rsqrtf(sums[384+256+c]*(1.f/NM) - mf*mf + 1e-5f);
      gf[k]  = g1b[c]*rf;      bfv[k] = b1b[c] - mf*gf[k];
      float mc = sums[256+64+c]*(1.f/NM);
      float rc = rsqrtf(sums[384+256+64+c]*(1.f/NM) - mc*mc + 1e-5f);
      gc[k]  = g1b[c+64]*rc;   bcv[k] = b1b[c+64] - mc*gc[k];
    }
    size_t gbase = (size_t)r*128;
    u32x4 vf = __builtin_nontemporal_load((const u32x4*)(O2 + gbase + c0));
    u32x4 vc = __builtin_nontemporal_load((const u32x4*)(O2 + gbase + 64 + c0));
    const __half* hf = (const __half*)&vf;
    const __half* hc = (const __half*)&vc;
    ushort_t* np = nb + (size_t)r*64 + c0;
    u32x4 old = *(const u32x4*)np;
    const ushort_t* op = (const ushort_t*)&old;
    u32x4 outv;
    ushort_t* ov = (ushort_t*)&outv;
#pragma unroll
    for (int k=0;k<8;++k){
      float x = bf2f(op[k]) + sigmoidf_(fmaf(__half2float(hf[k]), gf[k], bfv[k]))
                            * softplusf_(fmaf(__half2float(hc[k]), gc[k], bcv[k]));
      ov[k] = f2bf(softplusf_(x));
    }
    *(u32x4*)np = outv;
  }
}

// ---------------- fused: apply_out1 (blocks 121..8312) + next-pass wtr (0..119)
//                  + next-pass stats zero (block 120) ----
__global__ void out1_wtr(ushort_t* __restrict__ a0, const float* __restrict__ asum,
                         const float* __restrict__ st, const float* __restrict__ g2a,
                         const float* __restrict__ b2a,
                         const float* __restrict__ Wa_next, const float* __restrict__ Wb_next,
                         ushort_t* __restrict__ Wt, float* __restrict__ zstats){
  __shared__ ushort_t tile[32][33];
  int bx = blockIdx.x;
  int t = threadIdx.x;
  if (bx < 120){
    if (Wa_next == nullptr) return;
    int by = bx / 10, kx = bx - by*10;
    const float* W; int NO, o0, obase;
    if (by < 8){ W = Wa_next; NO = 256; o0 = by*32; obase = o0; }
    else       { W = Wb_next; NO = 128; o0 = (by-8)*32; obase = 256 + o0; }
    int k0 = kx*32;
    int tx = t & 31, ty = t >> 5;
#pragma unroll
    for (int i = ty; i < 32; i += 8)
      tile[i][tx] = f2bf(W[(size_t)(k0+i)*NO + o0 + tx]);
    __syncthreads();
#pragma unroll
    for (int i = ty; i < 32; i += 8)
      Wt[(size_t)(obase+i)*320 + k0 + tx] = tile[tx][i];
  } else if (bx == 120){
    if (Wa_next == nullptr) return;
#pragma unroll
    for (int k=0;k<4;++k) zstats[t + k*256] = 0.f;
  } else {
    int e = (bx-121)*256 + t; // n*128
    int c = e & 127;
    float m  = st[c]*(1.f/N_ATOM);
    float var = st[128+c]*(1.f/N_ATOM) - m*m;
    float rs = rsqrtf(var + 1e-5f);
    float g = g2a[c]*rs;
    float b = b2a[c] - m*g;
    a0[e] = f2bf(softplusf_(bf2f(a0[e]) + fmaf(asum[e], g, b)));
  }
}

// ---------------- pooling / VAE / decode ----------------
__global__ void pool_a_kernel(const ushort_t* __restrict__ a, float* __restrict__ pooled){
  int b = blockIdx.x; int c = threadIdx.x; // 128
  float s = 0.f;
  for (int i=0;i<128;++i) s += bf2f(a[(size_t)((b<<7)+i)*128 + c]);
  pooled[b*896 + c] = softplusf_(s * (1.f/128.f));
}

__launch_bounds__(768)
__global__ void pool_n_kernel(const ushort_t* __restrict__ nb, float* __restrict__ pooled){
  int b = blockIdx.x; int t = threadIdx.x; // 768
  float s = 0.f;
  for (int i=0;i<128;++i) s += bf2f(nb[(size_t)((b<<7)+i)*768 + t]);
  pooled[b*896 + 128 + t] = softplusf_(s * (1.f/128.f));
}

__global__ void muz_kernel(const float* __restrict__ pooled, const float* __restrict__ muW,
                           const float* __restrict__ mub, const float* __restrict__ lvW,
                           const float* __restrict__ lvb, const float* __restrict__ eps,
                           float* __restrict__ out_mu, float* __restrict__ out_lv,
                           float* __restrict__ out_z, float* __restrict__ zws){
  int t = threadIdx.x; // 256 -> (b,l)
  int b = t >> 1, l = t & 1;
  const float* pr = pooled + b*896;
  float smu = mub[l], slv = lvb[l];
  for (int k=0;k<896;++k){
    float p = pr[k];
    smu = fmaf(p, muW[k*2+l], smu);
    slv = fmaf(p, lvW[k*2+l], slv);
  }
  out_mu[t] = smu; out_lv[t] = slv;
  float zv = fmaf(eps[t], __expf(0.5f*slv), smu);
  out_z[t] = zv; zws[t] = zv;
}

__global__ void compute_f_kernel(const float* __restrict__ zws, const float* __restrict__ decW,
                                 const float* __restrict__ decb, const float* __restrict__ pooled,
                                 float* __restrict__ f){
  int b = blockIdx.x;
  float z0 = zws[b*2], z1 = zws[b*2+1];
  for (int k = threadIdx.x; k < 896; k += 256){
    float zd = fmaf(z0, decW[k], fmaf(z1, decW[896+k], decb[k]));
    f[b*896+k] = __fdividef(zd, pooled[b*896+k]);
  }
}

__global__ void dec_atom_kernel(ushort_t* __restrict__ a, const float* __restrict__ f){
  int e = blockIdx.x*256+threadIdx.x; // n*128
  int c = e & 127; int b = e >> 14;
  a[e] = f2bf(softplusf_(bf2f(a[e]) * f[b*896 + c]));
}

__global__ void dec_bond_kernel(ushort_t* __restrict__ nb, const float* __restrict__ f){
  int i = blockIdx.x; int off = blockIdx.y*256 + threadIdx.x; // off < 768
  int b = i >> 7;
  size_t e = (size_t)i*768 + off;
  nb[e] = f2bf(softplusf_(bf2f(nb[e]) * f[b*896 + 128 + off]));
}

// ---------------- final embeddings ----------------
__global__ void embed_atom2_kernel(const ushort_t* __restrict__ a, const float* __restrict__ W,
                                   const float* __restrict__ bias, float* __restrict__ za2){
  __shared__ float row[128];
  int i = blockIdx.x; int t = threadIdx.x; // 128
  row[t] = bf2f(a[(size_t)i*128+t]);
  __syncthreads();
  if (t < 92){
    float s = bias[t];
#pragma unroll
    for (int k=0;k<128;++k) s = fmaf(row[k], W[k*92+t], s);
    za2[(size_t)i*92+t] = sigmoidf_(s);
  }
}

__global__ void bproj_kernel(const ushort_t* __restrict__ nb, const float* __restrict__ W,
                             const float* __restrict__ bias, float* __restrict__ bp){
  __shared__ float Ws[64][41];
  __shared__ float rows[6][64];
  int t = threadIdx.x; // 256
  for (int e=t; e<64*41; e+=256) Ws[e/41][e%41] = W[e];
  int r0 = blockIdx.x*6;
  for (int e=t; e<6*64; e+=256){
    int rr = e>>6, c = e&63;
    rows[rr][c] = bf2f(nb[(size_t)(r0+rr)*64 + c]);
  }
  __syncthreads();
  if (t < 246){
    int rr = t/41, o = t - rr*41;
    float s = bias[o];
#pragma unroll
    for (int k=0;k<64;++k) s = fmaf(rows[rr][k], Ws[k][o], s);
    bp[(size_t)(r0+rr)*41 + o] = sigmoidf_(s);
  }
}

__global__ void zdec_v2(const float* __restrict__ za2, const float* __restrict__ bp,
                        const int* __restrict__ idx, float* __restrict__ out){
  int e0 = blockIdx.x*2048 + threadIdx.x;
#pragma unroll
  for (int i=0;i<8;++i){
    int e = e0 + i*256;
    int r = e/225, c = e - r*225;
    float v;
    if (c < 92)       v = za2[(size_t)(r/12)*92 + c];
    else if (c < 184) v = za2[(size_t)idx[r]*92 + (c-92)];
    else              v = bp[(size_t)r*41 + (c-184)];
    __builtin_nontemporal_store(v, out + (size_t)e);
  }
}

// ---------------- host side ----------------
struct WsPlan {
  ushort_t *Abf, *NBbf, *Wt;
  __half* big;
  float *asum, *pooled, *fbuf, *zws, *eps, *sums0, *sums1;
};

struct PassW {
  const float *Wa,*Wb,*g1a,*b1a,*g1b,*b1b,*g2a,*b2a;
};

extern "C" void kernel_launch(void* const* d_in, const int* in_sizes, int n_in,
                              void* d_out, int out_size, void* d_ws, size_t ws_size,
                              hipStream_t stream) {
  (void)in_sizes; (void)n_in; (void)out_size; (void)ws_size;
  const float* atom_fea   = (const float*)d_in[0];
  const float* nbr_fea    = (const float*)d_in[1];
  const int*   idx        = (const int*)d_in[2];
  const float* emb_atom_W = (const float*)d_in[4];
  const float* emb_atom_b = (const float*)d_in[5];
  const float* emb_bond_W = (const float*)d_in[6];
  const float* emb_bond_b = (const float*)d_in[7];
  const float* emb_atom2_W= (const float*)d_in[8];
  const float* emb_atom2_b= (const float*)d_in[9];
  const float* emb_bond2_W= (const float*)d_in[10];
  const float* emb_bond2_b= (const float*)d_in[11];
  const float* mu_W       = (const float*)d_in[12];
  const float* mu_b       = (const float*)d_in[13];
  const float* lv_W       = (const float*)d_in[14];
  const float* lv_b       = (const float*)d_in[15];
  const float* dec_W      = (const float*)d_in[16];
  const float* dec_b      = (const float*)d_in[17];
  const float* c1_Wa  = (const float*)d_in[18];
  const float* c1_Wb  = (const float*)d_in[19];
  const float* c1_g1a = (const float*)d_in[20];
  const float* c1_b1a = (const float*)d_in[21];
  const float* c1_g1b = (const float*)d_in[22];
  const float* c1_b1b = (const float*)d_in[23];
  const float* c1_g2a = (const float*)d_in[24];
  const float* c1_b2a = (const float*)d_in[25];
  const float* c2_Wa  = (const float*)d_in[26];
  const float* c2_Wb  = (const float*)d_in[27];
  const float* c2_g1a = (const float*)d_in[28];
  const float* c2_b1a = (const float*)d_in[29];
  const float* c2_g1b = (const float*)d_in[30];
  const float* c2_b1b = (const float*)d_in[31];
  const float* c2_g2a = (const float*)d_in[32];
  const float* c2_b2a = (const float*)d_in[33];

  float* out = (float*)d_out;

  hipFuncSetAttribute((const void*)conv_gemm_v9,
                      hipFuncAttributeMaxDynamicSharedMemorySize, GEMM_LDS_V9);

  WsPlan P;
  char* w = (char*)d_ws;
  auto alloc = [&](size_t bytes) -> char* {
    char* p = w; w += (bytes + 255) & ~(size_t)255; return p;
  };
  P.Abf    = (ushort_t*)alloc((size_t)N_ATOM*128*2);
  P.NBbf   = (ushort_t*)alloc((size_t)NM*64*2);
  P.big    = (__half*)  alloc((size_t)NM*384*2);
  P.asum   = (float*)   alloc((size_t)N_ATOM*128*4);
  P.pooled = (float*)   alloc(114688*4);
  P.fbuf   = (float*)   alloc(114688*4);
  P.Wt     = (ushort_t*)alloc(384*320*2);
  P.zws    = (float*)   alloc(256*4);
  P.eps    = (float*)   alloc(256*4);
  P.sums0  = (float*)   alloc(1024*4);   // slot 0: sums[768] + st[256]
  P.sums1  = (float*)   alloc(1024*4);   // slot 1
  float* za2   = P.asum;                 // reuse after conv stacks
  float* bproj = (float*)P.big;          // reuse big in the final phase

  PassW pw[6] = {
    { c1_Wa,            c1_Wb,            c1_g1a,       c1_b1a,       c1_g1b,       c1_b1b,       c1_g2a,       c1_b2a       },
    { c1_Wa+320*256,    c1_Wb+320*128,    c1_g1a+256,   c1_b1a+256,   c1_g1b+128,   c1_b1b+128,   c1_g2a+128,   c1_b2a+128   },
    { c1_Wa+2*320*256,  c1_Wb+2*320*128,  c1_g1a+2*256, c1_b1a+2*256, c1_g1b+2*128, c1_b1b+2*128, c1_g2a+2*128, c1_b2a+2*128 },
    { c2_Wa,            c2_Wb,            c2_g1a,       c2_b1a,       c2_g1b,       c2_b1b,       c2_g2a,       c2_b2a       },
    { c2_Wa+320*256,    c2_Wb+320*128,    c2_g1a+256,   c2_b1a+256,   c2_g1b+128,   c2_b1b+128,   c2_g2a+128,   c2_b2a+128   },
    { c2_Wa+2*320*256,  c2_Wb+2*320*128,  c2_g1a+2*256, c2_b1a+2*256, c2_g1b+2*128, c2_b1b+2*128, c2_g2a+2*128, c2_b2a+2*128 },
  };

  auto conv_pass = [&](int p){
    float* sums_cur = (p & 1) ? P.sums1 : P.sums0;
    float* sums_nxt = (p & 1) ? P.sums0 : P.sums1;
    const __half* O0 = P.big;
    const __half* O1 = P.big + (size_t)NM*128;
    const __half* O2 = P.big + (size_t)NM*256;
    conv_gemm_v9<<<dim3(NM/256, 3), 256, GEMM_LDS_V9, stream>>>(P.Abf, P.NBbf, idx, P.Wt, P.big, sums_cur);
    apply_gagb<<<7168, 256, 0, stream>>>(O0, O1, O2, P.NBbf, sums_cur,
                                         pw[p].g1a, pw[p].b1a, pw[p].g1b, pw[p].b1b,
                                         P.asum, sums_cur + 768);
    const float* Wa_n = (p < 5) ? pw[p+1].Wa : nullptr;
    const float* Wb_n = (p < 5) ? pw[p+1].Wb : nullptr;
    out1_wtr<<<8313, 256, 0, stream>>>(P.Abf, P.asum, sums_cur + 768,
                                       pw[p].g2a, pw[p].b2a, Wa_n, Wb_n, P.Wt, sums_nxt);
  };

  gen_eps_kernel<<<1, 256, 0, stream>>>(P.eps);
  tif_v2<<<21600, 256, 0, stream>>>(atom_fea, nbr_fea, idx, out + O_TIF);
  embed_atom_kernel<<<N_ATOM, 128, 0, stream>>>(atom_fea, emb_atom_W, emb_atom_b, P.Abf);
  embed_bond_kernel<<<NM/4, 256, 0, stream>>>(nbr_fea, emb_bond_W, emb_bond_b, P.NBbf);
  wtr2_kernel<<<dim3(10,12), 256, 0, stream>>>(pw[0].Wa, pw[0].Wb, P.Wt, P.sums0);

  conv_pass(0);
  conv_pass(1);
  conv_pass(2);

  pool_a_kernel<<<NCRY, 128, 0, stream>>>(P.Abf, P.pooled);
  pool_n_kernel<<<NCRY, 768, 0, stream>>>(P.NBbf, P.pooled);
  muz_kernel<<<1, 256, 0, stream>>>(P.pooled, mu_W, mu_b, lv_W, lv_b, P.eps,
                                    out + O_MU, out + O_LV, out + O_Z, P.zws);
  compute_f_kernel<<<NCRY, 256, 0, stream>>>(P.zws, dec_W, dec_b, P.pooled, P.fbuf);
  dec_atom_kernel<<<N_ATOM*128/256, 256, 0, stream>>>(P.Abf, P.fbuf);
  dim3 gdb(N_ATOM, 3);
  dec_bond_kernel<<<gdb, 256, 0, stream>>>(P.NBbf, P.fbuf);

  conv_pass(3);
  conv_pass(4);
  conv_pass(5);

  embed_atom2_kernel<<<N_ATOM, 128, 0, stream>>>(P.Abf, emb_atom2_W, emb_atom2_b, za2);
  bproj_kernel<<<NM/6, 256, 0, stream>>>(P.NBbf, emb_bond2_W, emb_bond2_b, bproj);
  zdec_v2<<<21600, 256, 0, stream>>>(za2, bproj, idx, out + O_ZDEC);
}

// Round 15
// 1583.552 us; speedup vs baseline: 1.7130x; 1.0296x over previous
//
#include <hip/hip_runtime.h>
#include <hip/hip_bf16.h>
#include <hip/hip_fp16.h>
#include <cstdint>
#include <cstddef>

// ---------------- constants ----------------
#define N_ATOM 16384
#define M_NBR  12
#define NCRY   128
#define NM     (N_ATOM*M_NBR) // 196608

// output offsets (floats)
#define O_ZDEC 0
#define O_MU   44236800
#define O_LV   44237056
#define O_Z    44237312
#define O_TIF  44237568

typedef unsigned short ushort_t;
typedef float f32x4 __attribute__((ext_vector_type(4)));
typedef short bf16x8 __attribute__((ext_vector_type(8)));
typedef unsigned int u32x4 __attribute__((ext_vector_type(4)));

// fast-math activation helpers (v_exp/v_log/v_rcp paths; ~1e-7 rel err, fine vs 0.2525 thr)
__device__ __forceinline__ float sigmoidf_(float x){
  return __fdividef(1.f, 1.f + __expf(-x));
}
__device__ __forceinline__ float softplusf_(float x){
  return fmaxf(x,0.f) + 0.69314718056f * __log2f(1.f + __expf(-fabsf(x)));
}
__device__ __forceinline__ uint32_t rotl32_(uint32_t x, int r){ return (x<<r)|(x>>(32-r)); }
__device__ __forceinline__ float bf2f(ushort_t u){ return __uint_as_float(((uint32_t)u)<<16); }
__device__ __forceinline__ ushort_t f2bf(float x){
  uint32_t u = __float_as_uint(x);
  uint32_t r = (u + 0x7FFFu + ((u>>16)&1u)) >> 16;
  return (ushort_t)r;
}

// async global->LDS, 16B per lane; LDS dest = wave-uniform base + lane*16
#define GLDS16(g, l) __builtin_amdgcn_global_load_lds( \
    (const __attribute__((address_space(1))) void*)(g), \
    (__attribute__((address_space(3))) void*)(l), 16, 0, 0)

// ---------------- total_input_fea output (coalesced, NT stores: true output) ------
__global__ void tif_v2(const float* __restrict__ atom, const float* __restrict__ nbr,
                       const int* __restrict__ idx, float* __restrict__ out){
  int e0 = blockIdx.x*2048 + threadIdx.x;
#pragma unroll
  for (int i=0;i<8;++i){
    int e = e0 + i*256;
    int r = e/225, c = e - r*225;
    float v;
    if (c < 92)       v = atom[(r/12)*92 + c];
    else if (c < 184) v = atom[idx[r]*92 + (c-92)];
    else              v = nbr[(size_t)r*41 + (c-184)];
    __builtin_nontemporal_store(v, out + (size_t)e);
  }
}

// ---------------- fused embeddings (write bf16 masters) ----------------
// blocks 0..8191: atom (2 atoms/block); blocks 8192..57343: bond (4 rows/block)
__global__ void embed_fused(const float* __restrict__ atom, const float* __restrict__ nbr,
                            const float* __restrict__ Wa, const float* __restrict__ ba,
                            const float* __restrict__ Wb, const float* __restrict__ bb,
                            ushort_t* __restrict__ a0, ushort_t* __restrict__ nb0){
  int bx = blockIdx.x; int t = threadIdx.x; // 256
  if (bx < 8192){
    __shared__ float row[2][92];
    int al = t >> 7, tt = t & 127;
    int i = bx*2 + al;
    if (tt < 92) row[al][tt] = atom[i*92+tt];
    __syncthreads();
    float s = ba[tt];
#pragma unroll
    for (int k=0;k<92;++k) s = fmaf(row[al][k], Wa[k*128+tt], s);
    a0[(size_t)i*128+tt] = f2bf(s);
  } else {
    __shared__ float rows[4][41];
    int r0 = (bx-8192)*4;
    if (t < 164) rows[t/41][t%41] = nbr[(size_t)r0*41 + t];
    __syncthreads();
    int rr = t >> 6, c = t & 63;
    float s = bb[c];
#pragma unroll
    for (int k=0;k<41;++k) s = fmaf(rows[rr][k], Wb[k*64+c], s);
    nb0[(size_t)(r0+rr)*64 + c] = f2bf(s);
  }
}

// ---------------- weight transpose (pass 0) + stats zeroing ----------
__global__ void wtr2_kernel(const float* __restrict__ Wa, const float* __restrict__ Wb,
                            ushort_t* __restrict__ Wt, float* __restrict__ zstats){
  __shared__ ushort_t tile[32][33];
  if (blockIdx.x == 0 && blockIdx.y == 0){
#pragma unroll
    for (int k=0;k<4;++k) zstats[threadIdx.x + k*256] = 0.f;
  }
  int by = blockIdx.y;
  const float* W; int NO, o0, obase;
  if (by < 8){ W = Wa; NO = 256; o0 = by*32; obase = o0; }
  else       { W = Wb; NO = 128; o0 = (by-8)*32; obase = 256 + o0; }
  int k0 = blockIdx.x*32;
  int tx = threadIdx.x & 31, ty = threadIdx.x >> 5; // 256 thr
#pragma unroll
  for (int i = ty; i < 32; i += 8)
    tile[i][tx] = f2bf(W[(size_t)(k0+i)*NO + o0 + tx]);
  __syncthreads();
#pragma unroll
  for (int i = ty; i < 32; i += 8)
    Wt[(size_t)(obase+i)*320 + k0 + tx] = tile[tx][i];
}

// ---------------- MFMA conv GEMM v10: v9 pipeline + bijective XCD swizzle ----
// Grid: 2304 1D blocks. XCD x owns logical ids [x*288,(x+1)*288): 96 contiguous
// row0-groups x 3 col-blocks -> NBbf/Abf col-block re-reads hit the same L2.
#define GEMM_LDS_V9 75776
__launch_bounds__(256, 2)
__global__ void conv_gemm_v10(const ushort_t* __restrict__ a_bf, const ushort_t* __restrict__ nb_bf,
                              const int* __restrict__ idx, const ushort_t* __restrict__ Wt,
                              __half* __restrict__ O, float* __restrict__ sums){
  extern __shared__ char smraw[];
  ushort_t* sm   = (ushort_t*)smraw;           // As: 3x8192 ushorts @0; Bs: 3x4096 @24576
  float*   sqred = (float*)(smraw + 73728);    // 256 floats
  int*     idxs  = (int*)(smraw + 74752);      // 256 ints
  ushort_t* As = sm;
  ushort_t* Bs = sm + 24576;
  const int t = threadIdx.x;
  const int lane = t & 63;
  const int w = t >> 6;
  const int lm = lane & 15, lg = lane >> 4;
  // bijective XCD swizzle: 2304 = 8 XCD * 288; logical = r0i*3 + cb
  const int flat = blockIdx.x;
  const int wg   = (flat & 7)*288 + (flat >> 3);
  const int r0i  = wg / 3;
  const int cb   = wg - r0i*3;
  const int row0 = r0i * 256;
  const int col0 = cb * 128;
  __half* Ob = O + (size_t)cb * ((size_t)NM*128);

  idxs[t] = idx[row0 + t];
  sqred[t] = 0.f;

  auto stage = [&](int ks, int b_){
    ushort_t* Ad = As + b_*8192;
    ushort_t* Bd = Bs + b_*4096;
#pragma unroll
    for (int i=0;i<4;++i){
      int e = t + i*256;              // 0..1023
      int r = e >> 2, ch = e & 3;
      const ushort_t* ga;
      if (ks < 4)      ga = a_bf + (size_t)((row0+r)/12)*128 + ks*32 + ch*8;
      else if (ks < 8) ga = a_bf + (size_t)idxs[r]*128 + (ks-4)*32 + ch*8;
      else             ga = nb_bf + (size_t)(row0+r)*64 + (ks-8)*32 + ch*8;
      GLDS16(ga, Ad + e*8);
    }
#pragma unroll
    for (int i=0;i<2;++i){
      int e = t + i*256;              // 0..511
      int r = e >> 2, ch = e & 3;
      GLDS16(Wt + (size_t)(col0+r)*320 + ks*32 + ch*8, Bd + e*8);
    }
  };

  stage(0, 0);                        // batches 0,1 in flight
  stage(1, 1);

  f32x4 acc[4][8] = {};
#pragma unroll
  for (int ks = 0; ks < 10; ++ks){
    const int buf = ks % 3;
    if (ks < 8){
      stage(ks+2, (ks+2) % 3);
      asm volatile("s_waitcnt vmcnt(12)" ::: "memory");  // oldest 6 (batch ks) landed
    } else if (ks == 8){
      asm volatile("s_waitcnt vmcnt(6)" ::: "memory");
    } else {
      asm volatile("s_waitcnt vmcnt(0)" ::: "memory");
    }
    __builtin_amdgcn_s_barrier();
    __builtin_amdgcn_sched_barrier(0);
    const ushort_t* Ab = As + buf*8192;
    const ushort_t* Bb = Bs + buf*4096;
    bf16x8 afr[4], bfr[8];
#pragma unroll
    for (int fm=0; fm<4; ++fm)
      afr[fm] = *(const bf16x8*)&Ab[(w*64 + fm*16 + lm)*32 + lg*8];
#pragma unroll
    for (int fn=0; fn<8; ++fn)
      bfr[fn] = *(const bf16x8*)&Bb[(fn*16 + lm)*32 + lg*8];
    __builtin_amdgcn_s_setprio(1);
#pragma unroll
    for (int fm=0; fm<4; ++fm)
#pragma unroll
      for (int fn=0; fn<8; ++fn)
        acc[fm][fn] = __builtin_amdgcn_mfma_f32_16x16x32_bf16(afr[fm], bfr[fn], acc[fm][fn], 0, 0, 0);
    __builtin_amdgcn_s_setprio(0);
    asm volatile("s_waitcnt lgkmcnt(0)" ::: "memory");
    __builtin_amdgcn_sched_barrier(0);                   // rule #18 fence
    __builtin_amdgcn_s_barrier();
  }

  // epilogue: stage f16 tile [256][136] in LDS, NT stores + sum/ssq
#pragma unroll
  for (int fm=0; fm<4; ++fm){
    int rw = w*64 + fm*16 + lg*4;
#pragma unroll
    for (int fn=0; fn<8; ++fn){
      int cl = fn*16 + lm;
#pragma unroll
      for (int j=0; j<4; ++j){
        __half h = __float2half(acc[fm][fn][j]);
        sm[(rw+j)*136 + cl] = *(ushort_t*)&h;
      }
    }
  }
  __syncthreads();

  const int cch = t & 15, rb = t >> 4;
  float s1[8] = {0.f,0.f,0.f,0.f,0.f,0.f,0.f,0.f};
  float s2[8] = {0.f,0.f,0.f,0.f,0.f,0.f,0.f,0.f};
#pragma unroll
  for (int i=0; i<16; ++i){
    int row = rb + i*16;
    u32x4 v = *(const u32x4*)&sm[row*136 + cch*8];
    __builtin_nontemporal_store(v, (u32x4*)(Ob + (size_t)(row0+row)*128 + cch*8));
    const __half* hp = (const __half*)&v;
#pragma unroll
    for (int k=0;k<8;++k){
      float f = __half2float(hp[k]);
      s1[k] += f;
      s2[k] += f*f;
    }
  }
#pragma unroll
  for (int k=0;k<8;++k){
    atomicAdd(&sqred[cch*8+k], s1[k]);
    atomicAdd(&sqred[128+cch*8+k], s2[k]);
  }
  __syncthreads();
  if (t < 128){
    atomicAdd(&sums[col0 + t], sqred[t]);
    atomicAdd(&sums[384 + col0 + t], sqred[128+t]);
  }
}

// ---------------- fused apply: ga (blocks 0..1023) + gb (blocks 1024..7167) ----
__global__ void apply_gagb(const __half* __restrict__ O0, const __half* __restrict__ O1,
                           const __half* __restrict__ O2, ushort_t* __restrict__ nb,
                           const float* __restrict__ sums,
                           const float* __restrict__ g1a, const float* __restrict__ b1a,
                           const float* __restrict__ g1b, const float* __restrict__ b1b,
                           float* __restrict__ asum, float* __restrict__ st){
  __shared__ float red[256];
  int bx = blockIdx.x;
  int t = threadIdx.x;
  if (bx < 1024){
    red[t] = 0.f;
    int c8 = t & 15, al = t >> 4;
    int i = bx*16 + al;
    int c0 = c8*8;
    float gf[8], bfv[8], gc[8], bcv[8];
#pragma unroll
    for (int k=0;k<8;++k){
      int c = c0+k;
      float mf = sums[c]*(1.f/NM);
      float rf = rsqrtf(sums[384+c]*(1.f/NM) - mf*mf + 1e-5f);
      gf[k]  = g1a[c]*rf;      bfv[k] = b1a[c] - mf*gf[k];
      float mc = sums[c+128]*(1.f/NM);
      float rc = rsqrtf(sums[384+c+128]*(1.f/NM) - mc*mc + 1e-5f);
      gc[k]  = g1a[c+128]*rc;  bcv[k] = b1a[c+128] - mc*gc[k];
    }
    float s[8] = {0.f,0.f,0.f,0.f,0.f,0.f,0.f,0.f};
    size_t base = (size_t)i*12*128;
#pragma unroll
    for (int j=0;j<12;++j){
      u32x4 vf = __builtin_nontemporal_load((const u32x4*)(O0 + base + j*128 + c0));
      u32x4 vc = __builtin_nontemporal_load((const u32x4*)(O1 + base + j*128 + c0));
      const __half* hf = (const __half*)&vf;
      const __half* hc = (const __half*)&vc;
#pragma unroll
      for (int k=0;k<8;++k)
        s[k] += sigmoidf_(fmaf(__half2float(hf[k]), gf[k], bfv[k]))
              * softplusf_(fmaf(__half2float(hc[k]), gc[k], bcv[k]));
    }
    float* dst = asum + (size_t)i*128 + c0;
    __syncthreads();
#pragma unroll
    for (int k=0;k<8;++k){
      dst[k] = s[k];
      atomicAdd(&red[c0+k], s[k]);
      atomicAdd(&red[128+c0+k], s[k]*s[k]);
    }
    __syncthreads();
    atomicAdd(&st[t], red[t]);
  } else {
    int c8 = t & 7, rloc = t >> 3;
    int r = (bx-1024)*32 + rloc;
    int c0 = c8*8;
    float gf[8], bfv[8], gc[8], bcv[8];
#pragma unroll
    for (int k=0;k<8;++k){
      int c = c0+k;
      float mf = sums[256+c]*(1.f/NM);
      float rf = rsqrtf(sums[384+256+c]*(1.f/NM) - mf*mf + 1e-5f);
      gf[k]  = g1b[c]*rf;      bfv[k] = b1b[c] - mf*gf[k];
      float mc = sums[256+64+c]*(1.f/NM);
      float rc = rsqrtf(sums[384+256+64+c]*(1.f/NM) - mc*mc + 1e-5f);
      gc[k]  = g1b[c+64]*rc;   bcv[k] = b1b[c+64] - mc*gc[k];
    }
    size_t gbase = (size_t)r*128;
    u32x4 vf = __builtin_nontemporal_load((const u32x4*)(O2 + gbase + c0));
    u32x4 vc = __builtin_nontemporal_load((const u32x4*)(O2 + gbase + 64 + c0));
    const __half* hf = (const __half*)&vf;
    const __half* hc = (const __half*)&vc;
    ushort_t* np = nb + (size_t)r*64 + c0;
    u32x4 old = *(const u32x4*)np;
    const ushort_t* op = (const ushort_t*)&old;
    u32x4 outv;
    ushort_t* ov = (ushort_t*)&outv;
#pragma unroll
    for (int k=0;k<8;++k){
      float x = bf2f(op[k]) + sigmoidf_(fmaf(__half2float(hf[k]), gf[k], bfv[k]))
                            * softplusf_(fmaf(__half2float(hc[k]), gc[k], bcv[k]));
      ov[k] = f2bf(softplusf_(x));
    }
    *(u32x4*)np = outv;
  }
}

// ---------------- fused: apply_out1 (blocks 121..8312) + next-pass wtr (0..119)
//                  + next-pass stats zero (block 120) ----
__global__ void out1_wtr(ushort_t* __restrict__ a0, const float* __restrict__ asum,
                         const float* __restrict__ st, const float* __restrict__ g2a,
                         const float* __restrict__ b2a,
                         const float* __restrict__ Wa_next, const float* __restrict__ Wb_next,
                         ushort_t* __restrict__ Wt, float* __restrict__ zstats){
  __shared__ ushort_t tile[32][33];
  int bx = blockIdx.x;
  int t = threadIdx.x;
  if (bx < 120){
    if (Wa_next == nullptr) return;
    int by = bx / 10, kx = bx - by*10;
    const float* W; int NO, o0, obase;
    if (by < 8){ W = Wa_next; NO = 256; o0 = by*32; obase = o0; }
    else       { W = Wb_next; NO = 128; o0 = (by-8)*32; obase = 256 + o0; }
    int k0 = kx*32;
    int tx = t & 31, ty = t >> 5;
#pragma unroll
    for (int i = ty; i < 32; i += 8)
      tile[i][tx] = f2bf(W[(size_t)(k0+i)*NO + o0 + tx]);
    __syncthreads();
#pragma unroll
    for (int i = ty; i < 32; i += 8)
      Wt[(size_t)(obase+i)*320 + k0 + tx] = tile[tx][i];
  } else if (bx == 120){
    if (Wa_next == nullptr) return;
#pragma unroll
    for (int k=0;k<4;++k) zstats[t + k*256] = 0.f;
  } else {
    int e = (bx-121)*256 + t; // n*128
    int c = e & 127;
    float m  = st[c]*(1.f/N_ATOM);
    float var = st[128+c]*(1.f/N_ATOM) - m*m;
    float rs = rsqrtf(var + 1e-5f);
    float g = g2a[c]*rs;
    float b = b2a[c] - m*g;
    a0[e] = f2bf(softplusf_(bf2f(a0[e]) + fmaf(asum[e], g, b)));
  }
}

// ---------------- fused pooling: blocks 0..127 atoms, 128..255 bonds ----------
__global__ void pool_fused(const ushort_t* __restrict__ a, const ushort_t* __restrict__ nb,
                           float* __restrict__ pooled){
  __shared__ float sh[256];
  int bx = blockIdx.x; int t = threadIdx.x; // 256
  if (bx < 128){
    int b = bx;
    int c = t & 127, h = t >> 7;
    float s = 0.f;
    for (int i=h;i<128;i+=2) s += bf2f(a[(size_t)((b<<7)+i)*128 + c]);
    sh[t] = s;
    __syncthreads();
    if (t < 128)
      pooled[b*896 + t] = softplusf_((sh[t]+sh[t+128]) * (1.f/128.f));
  } else {
    int b = bx - 128;
    float s0=0.f, s1=0.f, s2=0.f;
    for (int i=0;i<128;++i){
      size_t base = (size_t)((b<<7)+i)*768;
      s0 += bf2f(nb[base + t]);
      s1 += bf2f(nb[base + t + 256]);
      s2 += bf2f(nb[base + t + 512]);
    }
    pooled[b*896 + 128 + t]       = softplusf_(s0 * (1.f/128.f));
    pooled[b*896 + 128 + t + 256] = softplusf_(s1 * (1.f/128.f));
    pooled[b*896 + 128 + t + 512] = softplusf_(s2 * (1.f/128.f));
  }
}

// ---------------- muz with inline threefry eps (PRECISE math for eps) ----------
__global__ void muz_v2(const float* __restrict__ pooled, const float* __restrict__ muW,
                       const float* __restrict__ mub, const float* __restrict__ lvW,
                       const float* __restrict__ lvb,
                       float* __restrict__ out_mu, float* __restrict__ out_lv,
                       float* __restrict__ out_z, float* __restrict__ zws){
  int t = threadIdx.x; // 256 -> (b,l)
  // ---- eps[t]: partitionable threefry, counter (0, t), key (0,42) ----
  float epsv;
  {
    const uint32_t k0 = 0u, k1 = 42u;
    const uint32_t ks2 = k0 ^ k1 ^ 0x1BD11BDAu;
    uint32_t x0 = 0u + k0;
    uint32_t x1 = (uint32_t)t + k1;
#define RND_(r) { x0 += x1; x1 = rotl32_(x1, r); x1 ^= x0; }
    RND_(13) RND_(15) RND_(26) RND_(6)  x0 += k1;  x1 += ks2 + 1u;
    RND_(17) RND_(29) RND_(16) RND_(24) x0 += ks2; x1 += k0 + 2u;
    RND_(13) RND_(15) RND_(26) RND_(6)  x0 += k0;  x1 += k1 + 3u;
    RND_(17) RND_(29) RND_(16) RND_(24) x0 += k1;  x1 += ks2 + 4u;
    RND_(13) RND_(15) RND_(26) RND_(6)  x0 += ks2; x1 += k0 + 5u;
#undef RND_
    uint32_t bits = x0 ^ x1;
    float f = __uint_as_float((bits >> 9) | 0x3f800000u) - 1.0f;
    float u = __fadd_rn(__fmul_rn(f, 1.99999994f), -0.99999994f);
    u = fmaxf(-0.99999994f, u);
    float w = -log1pf(-u*u);
    float p;
    if (w < 5.0f){
      w -= 2.5f;
      p = 2.81022636e-08f;
      p = fmaf(p, w, 3.43273939e-07f);
      p = fmaf(p, w, -3.5233877e-06f);
      p = fmaf(p, w, -4.39150654e-06f);
      p = fmaf(p, w, 0.00021858087f);
      p = fmaf(p, w, -0.00125372503f);
      p = fmaf(p, w, -0.00417768164f);
      p = fmaf(p, w, 0.246640727f);
      p = fmaf(p, w, 1.50140941f);
    } else {
      w = sqrtf(w) - 3.0f;
      p = -0.000200214257f;
      p = fmaf(p, w, 0.000100950558f);
      p = fmaf(p, w, 0.00134934322f);
      p = fmaf(p, w, -0.00367342844f);
      p = fmaf(p, w, 0.00573950773f);
      p = fmaf(p, w, -0.0076224613f);
      p = fmaf(p, w, 0.00943887047f);
      p = fmaf(p, w, 1.00167406f);
      p = fmaf(p, w, 2.83297682f);
    }
    epsv = 1.41421356237f * (p * u);
  }
  int b = t >> 1, l = t & 1;
  const float* pr = pooled + b*896;
  float smu = mub[l], slv = lvb[l];
  for (int k=0;k<896;++k){
    float p = pr[k];
    smu = fmaf(p, muW[k*2+l], smu);
    slv = fmaf(p, lvW[k*2+l], slv);
  }
  out_mu[t] = smu; out_lv[t] = slv;
  float zv = fmaf(epsv, __expf(0.5f*slv), smu);
  out_z[t] = zv; zws[t] = zv;
}

__global__ void compute_f_kernel(const float* __restrict__ zws, const float* __restrict__ decW,
                                 const float* __restrict__ decb, const float* __restrict__ pooled,
                                 float* __restrict__ f){
  int b = blockIdx.x;
  float z0 = zws[b*2], z1 = zws[b*2+1];
  for (int k = threadIdx.x; k < 896; k += 256){
    float zd = fmaf(z0, decW[k], fmaf(z1, decW[896+k], decb[k]));
    f[b*896+k] = __fdividef(zd, pooled[b*896+k]);
  }
}

// ---------------- fused decode: blocks 0..8191 atoms, 8192..57343 bonds ----------
__global__ void dec_fused(ushort_t* __restrict__ a, ushort_t* __restrict__ nb,
                          const float* __restrict__ f){
  int bx = blockIdx.x; int t = threadIdx.x; // 256
  if (bx < 8192){
    int e = bx*256 + t; // n*128
    int c = e & 127; int b = e >> 14;
    a[e] = f2bf(softplusf_(bf2f(a[e]) * f[b*896 + c]));
  } else {
    int blk = bx - 8192;
    int oy = blk >> 14, i = blk & 16383;
    int off = oy*256 + t;
    int b = i >> 7;
    size_t e = (size_t)i*768 + off;
    nb[e] = f2bf(softplusf_(bf2f(nb[e]) * f[b*896 + 128 + off]));
  }
}

// ---------------- final embeddings ----------------
__global__ void embed_atom2_kernel(const ushort_t* __restrict__ a, const float* __restrict__ W,
                                   const float* __restrict__ bias, float* __restrict__ za2){
  __shared__ float row[128];
  int i = blockIdx.x; int t = threadIdx.x; // 128
  row[t] = bf2f(a[(size_t)i*128+t]);
  __syncthreads();
  if (t < 92){
    float s = bias[t];
#pragma unroll
    for (int k=0;k<128;++k) s = fmaf(row[k], W[k*92+t], s);
    za2[(size_t)i*92+t] = sigmoidf_(s);
  }
}

__global__ void bproj_kernel(const ushort_t* __restrict__ nb, const float* __restrict__ W,
                             const float* __restrict__ bias, float* __restrict__ bp){
  __shared__ float Ws[64][41];
  __shared__ float rows[6][64];
  int t = threadIdx.x; // 256
  for (int e=t; e<64*41; e+=256) Ws[e/41][e%41] = W[e];
  int r0 = blockIdx.x*6;
  for (int e=t; e<6*64; e+=256){
    int rr = e>>6, c = e&63;
    rows[rr][c] = bf2f(nb[(size_t)(r0+rr)*64 + c]);
  }
  __syncthreads();
  if (t < 246){
    int rr = t/41, o = t - rr*41;
    float s = bias[o];
#pragma unroll
    for (int k=0;k<64;++k) s = fmaf(rows[rr][k], Ws[k][o], s);
    bp[(size_t)(r0+rr)*41 + o] = sigmoidf_(s);
  }
}

__global__ void zdec_v2(const float* __restrict__ za2, const float* __restrict__ bp,
                        const int* __restrict__ idx, float* __restrict__ out){
  int e0 = blockIdx.x*2048 + threadIdx.x;
#pragma unroll
  for (int i=0;i<8;++i){
    int e = e0 + i*256;
    int r = e/225, c = e - r*225;
    float v;
    if (c < 92)       v = za2[(size_t)(r/12)*92 + c];
    else if (c < 184) v = za2[(size_t)idx[r]*92 + (c-92)];
    else              v = bp[(size_t)r*41 + (c-184)];
    __builtin_nontemporal_store(v, out + (size_t)e);
  }
}

// ---------------- host side ----------------
struct WsPlan {
  ushort_t *Abf, *NBbf, *Wt;
  __half* big;
  float *asum, *pooled, *fbuf, *zws, *sums0, *sums1;
};

struct PassW {
  const float *Wa,*Wb,*g1a,*b1a,*g1b,*b1b,*g2a,*b2a;
};

extern "C" void kernel_launch(void* const* d_in, const int* in_sizes, int n_in,
                              void* d_out, int out_size, void* d_ws, size_t ws_size,
                              hipStream_t stream) {
  (void)in_sizes; (void)n_in; (void)out_size; (void)ws_size;
  const float* atom_fea   = (const float*)d_in[0];
  const float* nbr_fea    = (const float*)d_in[1];
  const int*   idx        = (const int*)d_in[2];
  const float* emb_atom_W = (const float*)d_in[4];
  const float* emb_atom_b = (const float*)d_in[5];
  const float* emb_bond_W = (const float*)d_in[6];
  const float* emb_bond_b = (const float*)d_in[7];
  const float* emb_atom2_W= (const float*)d_in[8];
  const float* emb_atom2_b= (const float*)d_in[9];
  const float* emb_bond2_W= (const float*)d_in[10];
  const float* emb_bond2_b= (const float*)d_in[11];
  const float* mu_W       = (const float*)d_in[12];
  const float* mu_b       = (const float*)d_in[13];
  const float* lv_W       = (const float*)d_in[14];
  const float* lv_b       = (const float*)d_in[15];
  const float* dec_W      = (const float*)d_in[16];
  const float* dec_b      = (const float*)d_in[17];
  const float* c1_Wa  = (const float*)d_in[18];
  const float* c1_Wb  = (const float*)d_in[19];
  const float* c1_g1a = (const float*)d_in[20];
  const float* c1_b1a = (const float*)d_in[21];
  const float* c1_g1b = (const float*)d_in[22];
  const float* c1_b1b = (const float*)d_in[23];
  const float* c1_g2a = (const float*)d_in[24];
  const float* c1_b2a = (const float*)d_in[25];
  const float* c2_Wa  = (const float*)d_in[26];
  const float* c2_Wb  = (const float*)d_in[27];
  const float* c2_g1a = (const float*)d_in[28];
  const float* c2_b1a = (const float*)d_in[29];
  const float* c2_g1b = (const float*)d_in[30];
  const float* c2_b1b = (const float*)d_in[31];
  const float* c2_g2a = (const float*)d_in[32];
  const float* c2_b2a = (const float*)d_in[33];

  float* out = (float*)d_out;

  hipFuncSetAttribute((const void*)conv_gemm_v10,
                      hipFuncAttributeMaxDynamicSharedMemorySize, GEMM_LDS_V9);

  WsPlan P;
  char* w = (char*)d_ws;
  auto alloc = [&](size_t bytes) -> char* {
    char* p = w; w += (bytes + 255) & ~(size_t)255; return p;
  };
  P.Abf    = (ushort_t*)alloc((size_t)N_ATOM*128*2);
  P.NBbf   = (ushort_t*)alloc((size_t)NM*64*2);
  P.big    = (__half*)  alloc((size_t)NM*384*2);
  P.asum   = (float*)   alloc((size_t)N_ATOM*128*4);
  P.pooled = (float*)   alloc(114688*4);
  P.fbuf   = (float*)   alloc(114688*4);
  P.Wt     = (ushort_t*)alloc(384*320*2);
  P.zws    = (float*)   alloc(256*4);
  P.sums0  = (float*)   alloc(1024*4);   // slot 0: sums[768] + st[256]
  P.sums1  = (float*)   alloc(1024*4);   // slot 1
  float* za2   = P.asum;                 // reuse after conv stacks
  float* bproj = (float*)P.big;          // reuse big in the final phase

  PassW pw[6] = {
    { c1_Wa,            c1_Wb,            c1_g1a,       c1_b1a,       c1_g1b,       c1_b1b,       c1_g2a,       c1_b2a       },
    { c1_Wa+320*256,    c1_Wb+320*128,    c1_g1a+256,   c1_b1a+256,   c1_g1b+128,   c1_b1b+128,   c1_g2a+128,   c1_b2a+128   },
    { c1_Wa+2*320*256,  c1_Wb+2*320*128,  c1_g1a+2*256, c1_b1a+2*256, c1_g1b+2*128, c1_b1b+2*128, c1_g2a+2*128, c1_b2a+2*128 },
    { c2_Wa,            c2_Wb,            c2_g1a,       c2_b1a,       c2_g1b,       c2_b1b,       c2_g2a,       c2_b2a       },
    { c2_Wa+320*256,    c2_Wb+320*128,    c2_g1a+256,   c2_b1a+256,   c2_g1b+128,   c2_b1b+128,   c2_g2a+128,   c2_b2a+128   },
    { c2_Wa+2*320*256,  c2_Wb+2*320*128,  c2_g1a+2*256, c2_b1a+2*256, c2_g1b+2*128, c2_b1b+2*128, c2_g2a+2*128, c2_b2a+2*128 },
  };

  auto conv_pass = [&](int p){
    float* sums_cur = (p & 1) ? P.sums1 : P.sums0;
    float* sums_nxt = (p & 1) ? P.sums0 : P.sums1;
    const __half* O0 = P.big;
    const __half* O1 = P.big + (size_t)NM*128;
    const __half* O2 = P.big + (size_t)NM*256;
    conv_gemm_v10<<<2304, 256, GEMM_LDS_V9, stream>>>(P.Abf, P.NBbf, idx, P.Wt, P.big, sums_cur);
    apply_gagb<<<7168, 256, 0, stream>>>(O0, O1, O2, P.NBbf, sums_cur,
                                         pw[p].g1a, pw[p].b1a, pw[p].g1b, pw[p].b1b,
                                         P.asum, sums_cur + 768);
    const float* Wa_n = (p < 5) ? pw[p+1].Wa : nullptr;
    const float* Wb_n = (p < 5) ? pw[p+1].Wb : nullptr;
    out1_wtr<<<8313, 256, 0, stream>>>(P.Abf, P.asum, sums_cur + 768,
                                       pw[p].g2a, pw[p].b2a, Wa_n, Wb_n, P.Wt, sums_nxt);
  };

  tif_v2<<<21600, 256, 0, stream>>>(atom_fea, nbr_fea, idx, out + O_TIF);
  embed_fused<<<57344, 256, 0, stream>>>(atom_fea, nbr_fea, emb_atom_W, emb_atom_b,
                                         emb_bond_W, emb_bond_b, P.Abf, P.NBbf);
  wtr2_kernel<<<dim3(10,12), 256, 0, stream>>>(pw[0].Wa, pw[0].Wb, P.Wt, P.sums0);

  conv_pass(0);
  conv_pass(1);
  conv_pass(2);

  pool_fused<<<256, 256, 0, stream>>>(P.Abf, P.NBbf, P.pooled);
  muz_v2<<<1, 256, 0, stream>>>(P.pooled, mu_W, mu_b, lv_W, lv_b,
                                out + O_MU, out + O_LV, out + O_Z, P.zws);
  compute_f_kernel<<<NCRY, 256, 0, stream>>>(P.zws, dec_W, dec_b, P.pooled, P.fbuf);
  dec_fused<<<57344, 256, 0, stream>>>(P.Abf, P.NBbf, P.fbuf);

  conv_pass(3);
  conv_pass(4);
  conv_pass(5);

  embed_atom2_kernel<<<N_ATOM, 128, 0, stream>>>(P.Abf, emb_atom2_W, emb_atom2_b, za2);
  bproj_kernel<<<NM/6, 256, 0, stream>>>(P.NBbf, emb_bond2_W, emb_bond2_b, bproj);
  zdec_v2<<<21600, 256, 0, stream>>>(za2, bproj, idx, out + O_ZDEC);
}

// Round 16
// 1576.745 us; speedup vs baseline: 1.7204x; 1.0043x over previous
//
#include <hip/hip_runtime.h>
#include <hip/hip_bf16.h>
#include <hip/hip_fp16.h>
#include <cstdint>
#include <cstddef>

// ---------------- constants ----------------
#define N_ATOM 16384
#define M_NBR  12
#define NCRY   128
#define NM     (N_ATOM*M_NBR) // 196608

// output offsets (floats)
#define O_ZDEC 0
#define O_MU   44236800
#define O_LV   44237056
#define O_Z    44237312
#define O_TIF  44237568

typedef unsigned short ushort_t;
typedef float f32x4 __attribute__((ext_vector_type(4)));
typedef short bf16x8 __attribute__((ext_vector_type(8)));
typedef unsigned int u32x4 __attribute__((ext_vector_type(4)));

// fast-math activation helpers (v_exp/v_log/v_rcp paths; ~1e-7 rel err, fine vs 0.2525 thr)
__device__ __forceinline__ float sigmoidf_(float x){
  return __fdividef(1.f, 1.f + __expf(-x));
}
__device__ __forceinline__ float softplusf_(float x){
  return fmaxf(x,0.f) + 0.69314718056f * __log2f(1.f + __expf(-fabsf(x)));
}
__device__ __forceinline__ uint32_t rotl32_(uint32_t x, int r){ return (x<<r)|(x>>(32-r)); }
__device__ __forceinline__ float bf2f(ushort_t u){ return __uint_as_float(((uint32_t)u)<<16); }
__device__ __forceinline__ ushort_t f2bf(float x){
  uint32_t u = __float_as_uint(x);
  uint32_t r = (u + 0x7FFFu + ((u>>16)&1u)) >> 16;
  return (ushort_t)r;
}

// async global->LDS, 16B per lane; LDS dest = wave-uniform base + lane*16
#define GLDS16(g, l) __builtin_amdgcn_global_load_lds( \
    (const __attribute__((address_space(1))) void*)(g), \
    (__attribute__((address_space(3))) void*)(l), 16, 0, 0)

// ---------------- fused front: tif (blocks 0..21599) + embed atom (..29791)
//                  + embed bond (..78943) ----------------
__global__ void front_fused(const float* __restrict__ atom, const float* __restrict__ nbr,
                            const int* __restrict__ idx, float* __restrict__ out_tif,
                            const float* __restrict__ Wa, const float* __restrict__ ba,
                            const float* __restrict__ Wb, const float* __restrict__ bb,
                            ushort_t* __restrict__ a0, ushort_t* __restrict__ nb0){
  int bx = blockIdx.x; int t = threadIdx.x; // 256
  if (bx < 21600){
    int e0 = bx*2048 + t;
#pragma unroll
    for (int i=0;i<8;++i){
      int e = e0 + i*256;
      int r = e/225, c = e - r*225;
      float v;
      if (c < 92)       v = atom[(r/12)*92 + c];
      else if (c < 184) v = atom[idx[r]*92 + (c-92)];
      else              v = nbr[(size_t)r*41 + (c-184)];
      __builtin_nontemporal_store(v, out_tif + (size_t)e);
    }
  } else if (bx < 29792){
    __shared__ float row[2][92];
    int al = t >> 7, tt = t & 127;
    int i = (bx-21600)*2 + al;
    if (tt < 92) row[al][tt] = atom[i*92+tt];
    __syncthreads();
    float s = ba[tt];
#pragma unroll
    for (int k=0;k<92;++k) s = fmaf(row[al][k], Wa[k*128+tt], s);
    a0[(size_t)i*128+tt] = f2bf(s);
  } else {
    __shared__ float rows[4][41];
    int r0 = (bx-29792)*4;
    if (t < 164) rows[t/41][t%41] = nbr[(size_t)r0*41 + t];
    __syncthreads();
    int rr = t >> 6, c = t & 63;
    float s = bb[c];
#pragma unroll
    for (int k=0;k<41;++k) s = fmaf(rows[rr][k], Wb[k*64+c], s);
    nb0[(size_t)(r0+rr)*64 + c] = f2bf(s);
  }
}

// ---------------- weight transpose (pass 0) + stats zeroing ----------
__global__ void wtr2_kernel(const float* __restrict__ Wa, const float* __restrict__ Wb,
                            ushort_t* __restrict__ Wt, float* __restrict__ zstats){
  __shared__ ushort_t tile[32][33];
  if (blockIdx.x == 0 && blockIdx.y == 0){
#pragma unroll
    for (int k=0;k<4;++k) zstats[threadIdx.x + k*256] = 0.f;
  }
  int by = blockIdx.y;
  const float* W; int NO, o0, obase;
  if (by < 8){ W = Wa; NO = 256; o0 = by*32; obase = o0; }
  else       { W = Wb; NO = 128; o0 = (by-8)*32; obase = 256 + o0; }
  int k0 = blockIdx.x*32;
  int tx = threadIdx.x & 31, ty = threadIdx.x >> 5; // 256 thr
#pragma unroll
  for (int i = ty; i < 32; i += 8)
    tile[i][tx] = f2bf(W[(size_t)(k0+i)*NO + o0 + tx]);
  __syncthreads();
#pragma unroll
  for (int i = ty; i < 32; i += 8)
    Wt[(size_t)(obase+i)*320 + k0 + tx] = tile[tx][i];
}

// ---------------- MFMA conv GEMM v10: 3-stage counted-vmcnt + XCD swizzle ----
#define GEMM_LDS_V9 75776
__launch_bounds__(256, 2)
__global__ void conv_gemm_v10(const ushort_t* __restrict__ a_bf, const ushort_t* __restrict__ nb_bf,
                              const int* __restrict__ idx, const ushort_t* __restrict__ Wt,
                              __half* __restrict__ O, float* __restrict__ sums){
  extern __shared__ char smraw[];
  ushort_t* sm   = (ushort_t*)smraw;           // As: 3x8192 ushorts @0; Bs: 3x4096 @24576
  float*   sqred = (float*)(smraw + 73728);    // 256 floats
  int*     idxs  = (int*)(smraw + 74752);      // 256 ints
  ushort_t* As = sm;
  ushort_t* Bs = sm + 24576;
  const int t = threadIdx.x;
  const int lane = t & 63;
  const int w = t >> 6;
  const int lm = lane & 15, lg = lane >> 4;
  // bijective XCD swizzle: 2304 = 8 XCD * 288; logical = r0i*3 + cb
  const int flat = blockIdx.x;
  const int wg   = (flat & 7)*288 + (flat >> 3);
  const int r0i  = wg / 3;
  const int cb   = wg - r0i*3;
  const int row0 = r0i * 256;
  const int col0 = cb * 128;
  __half* Ob = O + (size_t)cb * ((size_t)NM*128);

  idxs[t] = idx[row0 + t];
  sqred[t] = 0.f;

  auto stage = [&](int ks, int b_){
    ushort_t* Ad = As + b_*8192;
    ushort_t* Bd = Bs + b_*4096;
#pragma unroll
    for (int i=0;i<4;++i){
      int e = t + i*256;              // 0..1023
      int r = e >> 2, ch = e & 3;
      const ushort_t* ga;
      if (ks < 4)      ga = a_bf + (size_t)((row0+r)/12)*128 + ks*32 + ch*8;
      else if (ks < 8) ga = a_bf + (size_t)idxs[r]*128 + (ks-4)*32 + ch*8;
      else             ga = nb_bf + (size_t)(row0+r)*64 + (ks-8)*32 + ch*8;
      GLDS16(ga, Ad + e*8);
    }
#pragma unroll
    for (int i=0;i<2;++i){
      int e = t + i*256;              // 0..511
      int r = e >> 2, ch = e & 3;
      GLDS16(Wt + (size_t)(col0+r)*320 + ks*32 + ch*8, Bd + e*8);
    }
  };

  stage(0, 0);                        // batches 0,1 in flight
  stage(1, 1);

  f32x4 acc[4][8] = {};
#pragma unroll
  for (int ks = 0; ks < 10; ++ks){
    const int buf = ks % 3;
    if (ks < 8){
      stage(ks+2, (ks+2) % 3);
      asm volatile("s_waitcnt vmcnt(12)" ::: "memory");  // oldest 6 (batch ks) landed
    } else if (ks == 8){
      asm volatile("s_waitcnt vmcnt(6)" ::: "memory");
    } else {
      asm volatile("s_waitcnt vmcnt(0)" ::: "memory");
    }
    __builtin_amdgcn_s_barrier();
    __builtin_amdgcn_sched_barrier(0);
    const ushort_t* Ab = As + buf*8192;
    const ushort_t* Bb = Bs + buf*4096;
    bf16x8 afr[4], bfr[8];
#pragma unroll
    for (int fm=0; fm<4; ++fm)
      afr[fm] = *(const bf16x8*)&Ab[(w*64 + fm*16 + lm)*32 + lg*8];
#pragma unroll
    for (int fn=0; fn<8; ++fn)
      bfr[fn] = *(const bf16x8*)&Bb[(fn*16 + lm)*32 + lg*8];
    __builtin_amdgcn_s_setprio(1);
#pragma unroll
    for (int fm=0; fm<4; ++fm)
#pragma unroll
      for (int fn=0; fn<8; ++fn)
        acc[fm][fn] = __builtin_amdgcn_mfma_f32_16x16x32_bf16(afr[fm], bfr[fn], acc[fm][fn], 0, 0, 0);
    __builtin_amdgcn_s_setprio(0);
    asm volatile("s_waitcnt lgkmcnt(0)" ::: "memory");
    __builtin_amdgcn_sched_barrier(0);                   // rule #18 fence
    __builtin_amdgcn_s_barrier();
  }

  // epilogue: stage f16 tile [256][136] in LDS, NT stores + sum/ssq
#pragma unroll
  for (int fm=0; fm<4; ++fm){
    int rw = w*64 + fm*16 + lg*4;
#pragma unroll
    for (int fn=0; fn<8; ++fn){
      int cl = fn*16 + lm;
#pragma unroll
      for (int j=0; j<4; ++j){
        __half h = __float2half(acc[fm][fn][j]);
        sm[(rw+j)*136 + cl] = *(ushort_t*)&h;
      }
    }
  }
  __syncthreads();

  const int cch = t & 15, rb = t >> 4;
  float s1[8] = {0.f,0.f,0.f,0.f,0.f,0.f,0.f,0.f};
  float s2[8] = {0.f,0.f,0.f,0.f,0.f,0.f,0.f,0.f};
#pragma unroll
  for (int i=0; i<16; ++i){
    int row = rb + i*16;
    u32x4 v = *(const u32x4*)&sm[row*136 + cch*8];
    __builtin_nontemporal_store(v, (u32x4*)(Ob + (size_t)(row0+row)*128 + cch*8));
    const __half* hp = (const __half*)&v;
#pragma unroll
    for (int k=0;k<8;++k){
      float f = __half2float(hp[k]);
      s1[k] += f;
      s2[k] += f*f;
    }
  }
#pragma unroll
  for (int k=0;k<8;++k){
    atomicAdd(&sqred[cch*8+k], s1[k]);
    atomicAdd(&sqred[128+cch*8+k], s2[k]);
  }
  __syncthreads();
  if (t < 128){
    atomicAdd(&sums[col0 + t], sqred[t]);
    atomicAdd(&sums[384 + col0 + t], sqred[128+t]);
  }
}

// ---------------- fused apply: ga (blocks 0..1023) + gb (blocks 1024..7167) ----
__global__ void apply_gagb(const __half* __restrict__ O0, const __half* __restrict__ O1,
                           const __half* __restrict__ O2, ushort_t* __restrict__ nb,
                           const float* __restrict__ sums,
                           const float* __restrict__ g1a, const float* __restrict__ b1a,
                           const float* __restrict__ g1b, const float* __restrict__ b1b,
                           float* __restrict__ asum, float* __restrict__ st){
  __shared__ float red[256];
  int bx = blockIdx.x;
  int t = threadIdx.x;
  if (bx < 1024){
    red[t] = 0.f;
    int c8 = t & 15, al = t >> 4;
    int i = bx*16 + al;
    int c0 = c8*8;
    float gf[8], bfv[8], gc[8], bcv[8];
#pragma unroll
    for (int k=0;k<8;++k){
      int c = c0+k;
      float mf = sums[c]*(1.f/NM);
      float rf = rsqrtf(sums[384+c]*(1.f/NM) - mf*mf + 1e-5f);
      gf[k]  = g1a[c]*rf;      bfv[k] = b1a[c] - mf*gf[k];
      float mc = sums[c+128]*(1.f/NM);
      float rc = rsqrtf(sums[384+c+128]*(1.f/NM) - mc*mc + 1e-5f);
      gc[k]  = g1a[c+128]*rc;  bcv[k] = b1a[c+128] - mc*gc[k];
    }
    float s[8] = {0.f,0.f,0.f,0.f,0.f,0.f,0.f,0.f};
    size_t base = (size_t)i*12*128;
#pragma unroll
    for (int j=0;j<12;++j){
      u32x4 vf = __builtin_nontemporal_load((const u32x4*)(O0 + base + j*128 + c0));
      u32x4 vc = __builtin_nontemporal_load((const u32x4*)(O1 + base + j*128 + c0));
      const __half* hf = (const __half*)&vf;
      const __half* hc = (const __half*)&vc;
#pragma unroll
      for (int k=0;k<8;++k)
        s[k] += sigmoidf_(fmaf(__half2float(hf[k]), gf[k], bfv[k]))
              * softplusf_(fmaf(__half2float(hc[k]), gc[k], bcv[k]));
    }
    float* dst = asum + (size_t)i*128 + c0;
    __syncthreads();
#pragma unroll
    for (int k=0;k<8;++k){
      dst[k] = s[k];
      atomicAdd(&red[c0+k], s[k]);
      atomicAdd(&red[128+c0+k], s[k]*s[k]);
    }
    __syncthreads();
    atomicAdd(&st[t], red[t]);
  } else {
    int c8 = t & 7, rloc = t >> 3;
    int r = (bx-1024)*32 + rloc;
    int c0 = c8*8;
    float gf[8], bfv[8], gc[8], bcv[8];
#pragma unroll
    for (int k=0;k<8;++k){
      int c = c0+k;
      float mf = sums[256+c]*(1.f/NM);
      float rf = rsqrtf(sums[384+256+c]*(1.f/NM) - mf*mf + 1e-5f);
      gf[k]  = g1b[c]*rf;      bfv[k] = b1b[c] - mf*gf[k];
      float mc = sums[256+64+c]*(1.f/NM);
      float rc = rsqrtf(sums[384+256+64+c]*(1.f/NM) - mc*mc + 1e-5f);
      gc[k]  = g1b[c+64]*rc;   bcv[k] = b1b[c+64] - mc*gc[k];
    }
    size_t gbase = (size_t)r*128;
    u32x4 vf = __builtin_nontemporal_load((const u32x4*)(O2 + gbase + c0));
    u32x4 vc = __builtin_nontemporal_load((const u32x4*)(O2 + gbase + 64 + c0));
    const __half* hf = (const __half*)&vf;
    const __half* hc = (const __half*)&vc;
    ushort_t* np = nb + (size_t)r*64 + c0;
    u32x4 old = *(const u32x4*)np;
    const ushort_t* op = (const ushort_t*)&old;
    u32x4 outv;
    ushort_t* ov = (ushort_t*)&outv;
#pragma unroll
    for (int k=0;k<8;++k){
      float x = bf2f(op[k]) + sigmoidf_(fmaf(__half2float(hf[k]), gf[k], bfv[k]))
                            * softplusf_(fmaf(__half2float(hc[k]), gc[k], bcv[k]));
      ov[k] = f2bf(softplusf_(x));
    }
    *(u32x4*)np = outv;
  }
}

// ---------------- fused: apply_out1 (blocks 121..8312) + next-pass wtr (0..119)
//                  + next-pass stats zero (block 120) ----
__global__ void out1_wtr(ushort_t* __restrict__ a0, const float* __restrict__ asum,
                         const float* __restrict__ st, const float* __restrict__ g2a,
                         const float* __restrict__ b2a,
                         const float* __restrict__ Wa_next, const float* __restrict__ Wb_next,
                         ushort_t* __restrict__ Wt, float* __restrict__ zstats){
  __shared__ ushort_t tile[32][33];
  int bx = blockIdx.x;
  int t = threadIdx.x;
  if (bx < 120){
    if (Wa_next == nullptr) return;
    int by = bx / 10, kx = bx - by*10;
    const float* W; int NO, o0, obase;
    if (by < 8){ W = Wa_next; NO = 256; o0 = by*32; obase = o0; }
    else       { W = Wb_next; NO = 128; o0 = (by-8)*32; obase = 256 + o0; }
    int k0 = kx*32;
    int tx = t & 31, ty = t >> 5;
#pragma unroll
    for (int i = ty; i < 32; i += 8)
      tile[i][tx] = f2bf(W[(size_t)(k0+i)*NO + o0 + tx]);
    __syncthreads();
#pragma unroll
    for (int i = ty; i < 32; i += 8)
      Wt[(size_t)(obase+i)*320 + k0 + tx] = tile[tx][i];
  } else if (bx == 120){
    if (Wa_next == nullptr) return;
#pragma unroll
    for (int k=0;k<4;++k) zstats[t + k*256] = 0.f;
  } else {
    int e = (bx-121)*256 + t; // n*128
    int c = e & 127;
    float m  = st[c]*(1.f/N_ATOM);
    float var = st[128+c]*(1.f/N_ATOM) - m*m;
    float rs = rsqrtf(var + 1e-5f);
    float g = g2a[c]*rs;
    float b = b2a[c] - m*g;
    a0[e] = f2bf(softplusf_(bf2f(a0[e]) + fmaf(asum[e], g, b)));
  }
}

// ---------------- fused pooling: blocks 0..127 atoms, 128..255 bonds ----------
__global__ void pool_fused(const ushort_t* __restrict__ a, const ushort_t* __restrict__ nb,
                           float* __restrict__ pooled){
  __shared__ float sh[256];
  int bx = blockIdx.x; int t = threadIdx.x; // 256
  if (bx < 128){
    int b = bx;
    int c = t & 127, h = t >> 7;
    float s = 0.f;
    for (int i=h;i<128;i+=2) s += bf2f(a[(size_t)((b<<7)+i)*128 + c]);
    sh[t] = s;
    __syncthreads();
    if (t < 128)
      pooled[b*896 + t] = softplusf_((sh[t]+sh[t+128]) * (1.f/128.f));
  } else {
    int b = bx - 128;
    float s0=0.f, s1=0.f, s2=0.f;
    for (int i=0;i<128;++i){
      size_t base = (size_t)((b<<7)+i)*768;
      s0 += bf2f(nb[base + t]);
      s1 += bf2f(nb[base + t + 256]);
      s2 += bf2f(nb[base + t + 512]);
    }
    pooled[b*896 + 128 + t]       = softplusf_(s0 * (1.f/128.f));
    pooled[b*896 + 128 + t + 256] = softplusf_(s1 * (1.f/128.f));
    pooled[b*896 + 128 + t + 512] = softplusf_(s2 * (1.f/128.f));
  }
}

// ---------------- muz with inline threefry eps (PRECISE math for eps) ----------
__global__ void muz_v2(const float* __restrict__ pooled, const float* __restrict__ muW,
                       const float* __restrict__ mub, const float* __restrict__ lvW,
                       const float* __restrict__ lvb,
                       float* __restrict__ out_mu, float* __restrict__ out_lv,
                       float* __restrict__ out_z, float* __restrict__ zws){
  int t = threadIdx.x; // 256 -> (b,l)
  float epsv;
  {
    const uint32_t k0 = 0u, k1 = 42u;
    const uint32_t ks2 = k0 ^ k1 ^ 0x1BD11BDAu;
    uint32_t x0 = 0u + k0;
    uint32_t x1 = (uint32_t)t + k1;
#define RND_(r) { x0 += x1; x1 = rotl32_(x1, r); x1 ^= x0; }
    RND_(13) RND_(15) RND_(26) RND_(6)  x0 += k1;  x1 += ks2 + 1u;
    RND_(17) RND_(29) RND_(16) RND_(24) x0 += ks2; x1 += k0 + 2u;
    RND_(13) RND_(15) RND_(26) RND_(6)  x0 += k0;  x1 += k1 + 3u;
    RND_(17) RND_(29) RND_(16) RND_(24) x0 += k1;  x1 += ks2 + 4u;
    RND_(13) RND_(15) RND_(26) RND_(6)  x0 += ks2; x1 += k0 + 5u;
#undef RND_
    uint32_t bits = x0 ^ x1;
    float f = __uint_as_float((bits >> 9) | 0x3f800000u) - 1.0f;
    float u = __fadd_rn(__fmul_rn(f, 1.99999994f), -0.99999994f);
    u = fmaxf(-0.99999994f, u);
    float w = -log1pf(-u*u);
    float p;
    if (w < 5.0f){
      w -= 2.5f;
      p = 2.81022636e-08f;
      p = fmaf(p, w, 3.43273939e-07f);
      p = fmaf(p, w, -3.5233877e-06f);
      p = fmaf(p, w, -4.39150654e-06f);
      p = fmaf(p, w, 0.00021858087f);
      p = fmaf(p, w, -0.00125372503f);
      p = fmaf(p, w, -0.00417768164f);
      p = fmaf(p, w, 0.246640727f);
      p = fmaf(p, w, 1.50140941f);
    } else {
      w = sqrtf(w) - 3.0f;
      p = -0.000200214257f;
      p = fmaf(p, w, 0.000100950558f);
      p = fmaf(p, w, 0.00134934322f);
      p = fmaf(p, w, -0.00367342844f);
      p = fmaf(p, w, 0.00573950773f);
      p = fmaf(p, w, -0.0076224613f);
      p = fmaf(p, w, 0.00943887047f);
      p = fmaf(p, w, 1.00167406f);
      p = fmaf(p, w, 2.83297682f);
    }
    epsv = 1.41421356237f * (p * u);
  }
  int b = t >> 1, l = t & 1;
  const float* pr = pooled + b*896;
  float smu = mub[l], slv = lvb[l];
  for (int k=0;k<896;++k){
    float p = pr[k];
    smu = fmaf(p, muW[k*2+l], smu);
    slv = fmaf(p, lvW[k*2+l], slv);
  }
  out_mu[t] = smu; out_lv[t] = slv;
  float zv = fmaf(epsv, __expf(0.5f*slv), smu);
  out_z[t] = zv; zws[t] = zv;
}

__global__ void compute_f_kernel(const float* __restrict__ zws, const float* __restrict__ decW,
                                 const float* __restrict__ decb, const float* __restrict__ pooled,
                                 float* __restrict__ f){
  int b = blockIdx.x;
  float z0 = zws[b*2], z1 = zws[b*2+1];
  for (int k = threadIdx.x; k < 896; k += 256){
    float zd = fmaf(z0, decW[k], fmaf(z1, decW[896+k], decb[k]));
    f[b*896+k] = __fdividef(zd, pooled[b*896+k]);
  }
}

// ---------------- fused decode: blocks 0..8191 atoms, 8192..57343 bonds ----------
__global__ void dec_fused(ushort_t* __restrict__ a, ushort_t* __restrict__ nb,
                          const float* __restrict__ f){
  int bx = blockIdx.x; int t = threadIdx.x; // 256
  if (bx < 8192){
    int e = bx*256 + t; // n*128
    int c = e & 127; int b = e >> 14;
    a[e] = f2bf(softplusf_(bf2f(a[e]) * f[b*896 + c]));
  } else {
    int blk = bx - 8192;
    int oy = blk >> 14, i = blk & 16383;
    int off = oy*256 + t;
    int b = i >> 7;
    size_t e = (size_t)i*768 + off;
    nb[e] = f2bf(softplusf_(bf2f(nb[e]) * f[b*896 + 128 + off]));
  }
}

// ---------------- fused tail-1: embed_atom2 (blocks 0..8191) + bproj (8192..40959) ----
__global__ void tail_fused(const ushort_t* __restrict__ a, const float* __restrict__ Wa2,
                           const float* __restrict__ ba2,
                           const ushort_t* __restrict__ nb, const float* __restrict__ Wb2,
                           const float* __restrict__ bb2,
                           float* __restrict__ za2, float* __restrict__ bp){
  int bx = blockIdx.x; int t = threadIdx.x; // 256
  if (bx < 8192){
    __shared__ float row[2][128];
    int al = t >> 7, tt = t & 127;
    int i = bx*2 + al;
    row[al][tt] = bf2f(a[(size_t)i*128+tt]);
    __syncthreads();
    if (tt < 92){
      float s = ba2[tt];
#pragma unroll
      for (int k=0;k<128;++k) s = fmaf(row[al][k], Wa2[k*92+tt], s);
      za2[(size_t)i*92+tt] = sigmoidf_(s);
    }
  } else {
    __shared__ float Ws[64][41];
    __shared__ float rows[6][64];
    for (int e=t; e<64*41; e+=256) Ws[e/41][e%41] = Wb2[e];
    int r0 = (bx-8192)*6;
    for (int e=t; e<6*64; e+=256){
      int rr = e>>6, c = e&63;
      rows[rr][c] = bf2f(nb[(size_t)(r0+rr)*64 + c]);
    }
    __syncthreads();
    if (t < 246){
      int rr = t/41, o = t - rr*41;
      float s = bb2[o];
#pragma unroll
      for (int k=0;k<64;++k) s = fmaf(rows[rr][k], Ws[k][o], s);
      bp[(size_t)(r0+rr)*41 + o] = sigmoidf_(s);
    }
  }
}

__global__ void zdec_v2(const float* __restrict__ za2, const float* __restrict__ bp,
                        const int* __restrict__ idx, float* __restrict__ out){
  int e0 = blockIdx.x*2048 + threadIdx.x;
#pragma unroll
  for (int i=0;i<8;++i){
    int e = e0 + i*256;
    int r = e/225, c = e - r*225;
    float v;
    if (c < 92)       v = za2[(size_t)(r/12)*92 + c];
    else if (c < 184) v = za2[(size_t)idx[r]*92 + (c-92)];
    else              v = bp[(size_t)r*41 + (c-184)];
    __builtin_nontemporal_store(v, out + (size_t)e);
  }
}

// ---------------- host side ----------------
struct WsPlan {
  ushort_t *Abf, *NBbf, *Wt;
  __half* big;
  float *asum, *pooled, *fbuf, *zws, *sums0, *sums1;
};

struct PassW {
  const float *Wa,*Wb,*g1a,*b1a,*g1b,*b1b,*g2a,*b2a;
};

extern "C" void kernel_launch(void* const* d_in, const int* in_sizes, int n_in,
                              void* d_out, int out_size, void* d_ws, size_t ws_size,
                              hipStream_t stream) {
  (void)in_sizes; (void)n_in; (void)out_size; (void)ws_size;
  const float* atom_fea   = (const float*)d_in[0];
  const float* nbr_fea    = (const float*)d_in[1];
  const int*   idx        = (const int*)d_in[2];
  const float* emb_atom_W = (const float*)d_in[4];
  const float* emb_atom_b = (const float*)d_in[5];
  const float* emb_bond_W = (const float*)d_in[6];
  const float* emb_bond_b = (const float*)d_in[7];
  const float* emb_atom2_W= (const float*)d_in[8];
  const float* emb_atom2_b= (const float*)d_in[9];
  const float* emb_bond2_W= (const float*)d_in[10];
  const float* emb_bond2_b= (const float*)d_in[11];
  const float* mu_W       = (const float*)d_in[12];
  const float* mu_b       = (const float*)d_in[13];
  const float* lv_W       = (const float*)d_in[14];
  const float* lv_b       = (const float*)d_in[15];
  const float* dec_W      = (const float*)d_in[16];
  const float* dec_b      = (const float*)d_in[17];
  const float* c1_Wa  = (const float*)d_in[18];
  const float* c1_Wb  = (const float*)d_in[19];
  const float* c1_g1a = (const float*)d_in[20];
  const float* c1_b1a = (const float*)d_in[21];
  const float* c1_g1b = (const float*)d_in[22];
  const float* c1_b1b = (const float*)d_in[23];
  const float* c1_g2a = (const float*)d_in[24];
  const float* c1_b2a = (const float*)d_in[25];
  const float* c2_Wa  = (const float*)d_in[26];
  const float* c2_Wb  = (const float*)d_in[27];
  const float* c2_g1a = (const float*)d_in[28];
  const float* c2_b1a = (const float*)d_in[29];
  const float* c2_g1b = (const float*)d_in[30];
  const float* c2_b1b = (const float*)d_in[31];
  const float* c2_g2a = (const float*)d_in[32];
  const float* c2_b2a = (const float*)d_in[33];

  float* out = (float*)d_out;

  hipFuncSetAttribute((const void*)conv_gemm_v10,
                      hipFuncAttributeMaxDynamicSharedMemorySize, GEMM_LDS_V9);

  WsPlan P;
  char* w = (char*)d_ws;
  auto alloc = [&](size_t bytes) -> char* {
    char* p = w; w += (bytes + 255) & ~(size_t)255; return p;
  };
  P.Abf    = (ushort_t*)alloc((size_t)N_ATOM*128*2);
  P.NBbf   = (ushort_t*)alloc((size_t)NM*64*2);
  P.big    = (__half*)  alloc((size_t)NM*384*2);
  P.asum   = (float*)   alloc((size_t)N_ATOM*128*4);
  P.pooled = (float*)   alloc(114688*4);
  P.fbuf   = (float*)   alloc(114688*4);
  P.Wt     = (ushort_t*)alloc(384*320*2);
  P.zws    = (float*)   alloc(256*4);
  P.sums0  = (float*)   alloc(1024*4);   // slot 0: sums[768] + st[256]
  P.sums1  = (float*)   alloc(1024*4);   // slot 1
  float* za2   = P.asum;                 // reuse after conv stacks
  float* bproj = (float*)P.big;          // reuse big in the final phase

  PassW pw[6] = {
    { c1_Wa,            c1_Wb,            c1_g1a,       c1_b1a,       c1_g1b,       c1_b1b,       c1_g2a,       c1_b2a       },
    { c1_Wa+320*256,    c1_Wb+320*128,    c1_g1a+256,   c1_b1a+256,   c1_g1b+128,   c1_b1b+128,   c1_g2a+128,   c1_b2a+128   },
    { c1_Wa+2*320*256,  c1_Wb+2*320*128,  c1_g1a+2*256, c1_b1a+2*256, c1_g1b+2*128, c1_b1b+2*128, c1_g2a+2*128, c1_b2a+2*128 },
    { c2_Wa,            c2_Wb,            c2_g1a,       c2_b1a,       c2_g1b,       c2_b1b,       c2_g2a,       c2_b2a       },
    { c2_Wa+320*256,    c2_Wb+320*128,    c2_g1a+256,   c2_b1a+256,   c2_g1b+128,   c2_b1b+128,   c2_g2a+128,   c2_b2a+128   },
    { c2_Wa+2*320*256,  c2_Wb+2*320*128,  c2_g1a+2*256, c2_b1a+2*256, c2_g1b+2*128, c2_b1b+2*128, c2_g2a+2*128, c2_b2a+2*128 },
  };

  auto conv_pass = [&](int p){
    float* sums_cur = (p & 1) ? P.sums1 : P.sums0;
    float* sums_nxt = (p & 1) ? P.sums0 : P.sums1;
    const __half* O0 = P.big;
    const __half* O1 = P.big + (size_t)NM*128;
    const __half* O2 = P.big + (size_t)NM*256;
    conv_gemm_v10<<<2304, 256, GEMM_LDS_V9, stream>>>(P.Abf, P.NBbf, idx, P.Wt, P.big, sums_cur);
    apply_gagb<<<7168, 256, 0, stream>>>(O0, O1, O2, P.NBbf, sums_cur,
                                         pw[p].g1a, pw[p].b1a, pw[p].g1b, pw[p].b1b,
                                         P.asum, sums_cur + 768);
    const float* Wa_n = (p < 5) ? pw[p+1].Wa : nullptr;
    const float* Wb_n = (p < 5) ? pw[p+1].Wb : nullptr;
    out1_wtr<<<8313, 256, 0, stream>>>(P.Abf, P.asum, sums_cur + 768,
                                       pw[p].g2a, pw[p].b2a, Wa_n, Wb_n, P.Wt, sums_nxt);
  };

  front_fused<<<78944, 256, 0, stream>>>(atom_fea, nbr_fea, idx, out + O_TIF,
                                         emb_atom_W, emb_atom_b, emb_bond_W, emb_bond_b,
                                         P.Abf, P.NBbf);
  wtr2_kernel<<<dim3(10,12), 256, 0, stream>>>(pw[0].Wa, pw[0].Wb, P.Wt, P.sums0);

  conv_pass(0);
  conv_pass(1);
  conv_pass(2);

  pool_fused<<<256, 256, 0, stream>>>(P.Abf, P.NBbf, P.pooled);
  muz_v2<<<1, 256, 0, stream>>>(P.pooled, mu_W, mu_b, lv_W, lv_b,
                                out + O_MU, out + O_LV, out + O_Z, P.zws);
  compute_f_kernel<<<NCRY, 256, 0, stream>>>(P.zws, dec_W, dec_b, P.pooled, P.fbuf);
  dec_fused<<<57344, 256, 0, stream>>>(P.Abf, P.NBbf, P.fbuf);

  conv_pass(3);
  conv_pass(4);
  conv_pass(5);

  tail_fused<<<40960, 256, 0, stream>>>(P.Abf, emb_atom2_W, emb_atom2_b,
                                        P.NBbf, emb_bond2_W, emb_bond2_b, za2, bproj);
  zdec_v2<<<21600, 256, 0, stream>>>(za2, bproj, idx, out + O_ZDEC);
}

// Round 17
// 1573.705 us; speedup vs baseline: 1.7237x; 1.0019x over previous
//
#include <hip/hip_runtime.h>
#include <hip/hip_bf16.h>
#include <hip/hip_fp16.h>
#include <cstdint>
#include <cstddef>

// ---------------- constants ----------------
#define N_ATOM 16384
#define M_NBR  12
#define NCRY   128
#define NM     (N_ATOM*M_NBR) // 196608

// output offsets (floats)
#define O_ZDEC 0
#define O_MU   44236800
#define O_LV   44237056
#define O_Z    44237312
#define O_TIF  44237568

typedef unsigned short ushort_t;
typedef float f32x4 __attribute__((ext_vector_type(4)));
typedef short bf16x8 __attribute__((ext_vector_type(8)));
typedef unsigned int u32x4 __attribute__((ext_vector_type(4)));

// fast-math activation helpers (v_exp/v_log/v_rcp paths; ~1e-7 rel err, fine vs 0.2525 thr)
__device__ __forceinline__ float sigmoidf_(float x){
  return __fdividef(1.f, 1.f + __expf(-x));
}
__device__ __forceinline__ float softplusf_(float x){
  return fmaxf(x,0.f) + 0.69314718056f * __log2f(1.f + __expf(-fabsf(x)));
}
__device__ __forceinline__ uint32_t rotl32_(uint32_t x, int r){ return (x<<r)|(x>>(32-r)); }
__device__ __forceinline__ float bf2f(ushort_t u){ return __uint_as_float(((uint32_t)u)<<16); }
__device__ __forceinline__ ushort_t f2bf(float x){
  uint32_t u = __float_as_uint(x);
  uint32_t r = (u + 0x7FFFu + ((u>>16)&1u)) >> 16;
  return (ushort_t)r;
}

// async global->LDS, 16B per lane; LDS dest = wave-uniform base + lane*16
#define GLDS16(g, l) __builtin_amdgcn_global_load_lds( \
    (const __attribute__((address_space(1))) void*)(g), \
    (__attribute__((address_space(3))) void*)(l), 16, 0, 0)

// ---------------- fused front: tif tiles (0..6143) + embed atom (..14335)
//                  + embed bond (..63487) ----------------
// tif: 32 rows/block staged in LDS via 3 branch-uniform phases, then contiguous
// float4 NT writes (fixes wave divergence + scalar stores).
__global__ void front_fused(const float* __restrict__ atom, const float* __restrict__ nbr,
                            const int* __restrict__ idx, float* __restrict__ out_tif,
                            const float* __restrict__ Wa, const float* __restrict__ ba,
                            const float* __restrict__ Wb, const float* __restrict__ bb,
                            ushort_t* __restrict__ a0, ushort_t* __restrict__ nb0){
  int bx = blockIdx.x; int t = threadIdx.x; // 256
  if (bx < 6144){
    __shared__ float tile[32*225];     // 28.8 KB
    __shared__ int   idxs[32];
    const int r0 = bx*32;
    if (t < 32) idxs[t] = idx[r0 + t];
    __syncthreads();
    // phase A: self atom features (few distinct rows, L2-hot)
    for (int e = t; e < 32*92; e += 256){
      int rr = e / 92, c = e - rr*92;
      tile[rr*225 + c] = atom[((r0+rr)/12)*92 + c];
    }
    // phase B: gathered atom rows (uniform gather phase)
    for (int e = t; e < 32*92; e += 256){
      int rr = e / 92, c = e - rr*92;
      tile[rr*225 + 92 + c] = atom[idxs[rr]*92 + c];
    }
    // phase C: bond features (contiguous source)
    for (int e = t; e < 32*41; e += 256){
      int rr = e / 41, c = e - rr*41;
      tile[rr*225 + 184 + c] = nbr[(size_t)r0*41 + e];
    }
    __syncthreads();
    float* dst = out_tif + (size_t)r0*225;
    for (int e4 = t; e4 < 1800; e4 += 256){
      f32x4 v = *(const f32x4*)&tile[e4*4];
      __builtin_nontemporal_store(v, (f32x4*)(dst + e4*4));
    }
  } else if (bx < 14336){
    __shared__ float row[2][92];
    int al = t >> 7, tt = t & 127;
    int i = (bx-6144)*2 + al;
    if (tt < 92) row[al][tt] = atom[i*92+tt];
    __syncthreads();
    float s = ba[tt];
#pragma unroll
    for (int k=0;k<92;++k) s = fmaf(row[al][k], Wa[k*128+tt], s);
    a0[(size_t)i*128+tt] = f2bf(s);
  } else {
    __shared__ float rows[4][41];
    int r0 = (bx-14336)*4;
    if (t < 164) rows[t/41][t%41] = nbr[(size_t)r0*41 + t];
    __syncthreads();
    int rr = t >> 6, c = t & 63;
    float s = bb[c];
#pragma unroll
    for (int k=0;k<41;++k) s = fmaf(rows[rr][k], Wb[k*64+c], s);
    nb0[(size_t)(r0+rr)*64 + c] = f2bf(s);
  }
}

// ---------------- weight transpose (pass 0) + stats zeroing ----------
__global__ void wtr2_kernel(const float* __restrict__ Wa, const float* __restrict__ Wb,
                            ushort_t* __restrict__ Wt, float* __restrict__ zstats){
  __shared__ ushort_t tile[32][33];
  if (blockIdx.x == 0 && blockIdx.y == 0){
#pragma unroll
    for (int k=0;k<4;++k) zstats[threadIdx.x + k*256] = 0.f;
  }
  int by = blockIdx.y;
  const float* W; int NO, o0, obase;
  if (by < 8){ W = Wa; NO = 256; o0 = by*32; obase = o0; }
  else       { W = Wb; NO = 128; o0 = (by-8)*32; obase = 256 + o0; }
  int k0 = blockIdx.x*32;
  int tx = threadIdx.x & 31, ty = threadIdx.x >> 5; // 256 thr
#pragma unroll
  for (int i = ty; i < 32; i += 8)
    tile[i][tx] = f2bf(W[(size_t)(k0+i)*NO + o0 + tx]);
  __syncthreads();
#pragma unroll
  for (int i = ty; i < 32; i += 8)
    Wt[(size_t)(obase+i)*320 + k0 + tx] = tile[tx][i];
}

// ---------------- MFMA conv GEMM v10: 3-stage counted-vmcnt + XCD swizzle ----
#define GEMM_LDS_V9 75776
__launch_bounds__(256, 2)
__global__ void conv_gemm_v10(const ushort_t* __restrict__ a_bf, const ushort_t* __restrict__ nb_bf,
                              const int* __restrict__ idx, const ushort_t* __restrict__ Wt,
                              __half* __restrict__ O, float* __restrict__ sums){
  extern __shared__ char smraw[];
  ushort_t* sm   = (ushort_t*)smraw;           // As: 3x8192 ushorts @0; Bs: 3x4096 @24576
  float*   sqred = (float*)(smraw + 73728);    // 256 floats
  int*     idxs  = (int*)(smraw + 74752);      // 256 ints
  ushort_t* As = sm;
  ushort_t* Bs = sm + 24576;
  const int t = threadIdx.x;
  const int lane = t & 63;
  const int w = t >> 6;
  const int lm = lane & 15, lg = lane >> 4;
  // bijective XCD swizzle: 2304 = 8 XCD * 288; logical = r0i*3 + cb
  const int flat = blockIdx.x;
  const int wg   = (flat & 7)*288 + (flat >> 3);
  const int r0i  = wg / 3;
  const int cb   = wg - r0i*3;
  const int row0 = r0i * 256;
  const int col0 = cb * 128;
  __half* Ob = O + (size_t)cb * ((size_t)NM*128);

  idxs[t] = idx[row0 + t];
  sqred[t] = 0.f;

  auto stage = [&](int ks, int b_){
    ushort_t* Ad = As + b_*8192;
    ushort_t* Bd = Bs + b_*4096;
#pragma unroll
    for (int i=0;i<4;++i){
      int e = t + i*256;              // 0..1023
      int r = e >> 2, ch = e & 3;
      const ushort_t* ga;
      if (ks < 4)      ga = a_bf + (size_t)((row0+r)/12)*128 + ks*32 + ch*8;
      else if (ks < 8) ga = a_bf + (size_t)idxs[r]*128 + (ks-4)*32 + ch*8;
      else             ga = nb_bf + (size_t)(row0+r)*64 + (ks-8)*32 + ch*8;
      GLDS16(ga, Ad + e*8);
    }
#pragma unroll
    for (int i=0;i<2;++i){
      int e = t + i*256;              // 0..511
      int r = e >> 2, ch = e & 3;
      GLDS16(Wt + (size_t)(col0+r)*320 + ks*32 + ch*8, Bd + e*8);
    }
  };

  stage(0, 0);                        // batches 0,1 in flight
  stage(1, 1);

  f32x4 acc[4][8] = {};
#pragma unroll
  for (int ks = 0; ks < 10; ++ks){
    const int buf = ks % 3;
    if (ks < 8){
      stage(ks+2, (ks+2) % 3);
      asm volatile("s_waitcnt vmcnt(12)" ::: "memory");  // oldest 6 (batch ks) landed
    } else if (ks == 8){
      asm volatile("s_waitcnt vmcnt(6)" ::: "memory");
    } else {
      asm volatile("s_waitcnt vmcnt(0)" ::: "memory");
    }
    __builtin_amdgcn_s_barrier();
    __builtin_amdgcn_sched_barrier(0);
    const ushort_t* Ab = As + buf*8192;
    const ushort_t* Bb = Bs + buf*4096;
    bf16x8 afr[4], bfr[8];
#pragma unroll
    for (int fm=0; fm<4; ++fm)
      afr[fm] = *(const bf16x8*)&Ab[(w*64 + fm*16 + lm)*32 + lg*8];
#pragma unroll
    for (int fn=0; fn<8; ++fn)
      bfr[fn] = *(const bf16x8*)&Bb[(fn*16 + lm)*32 + lg*8];
    __builtin_amdgcn_s_setprio(1);
#pragma unroll
    for (int fm=0; fm<4; ++fm)
#pragma unroll
      for (int fn=0; fn<8; ++fn)
        acc[fm][fn] = __builtin_amdgcn_mfma_f32_16x16x32_bf16(afr[fm], bfr[fn], acc[fm][fn], 0, 0, 0);
    __builtin_amdgcn_s_setprio(0);
    asm volatile("s_waitcnt lgkmcnt(0)" ::: "memory");
    __builtin_amdgcn_sched_barrier(0);                   // rule #18 fence
    __builtin_amdgcn_s_barrier();
  }

  // epilogue: stage f16 tile [256][136] in LDS, NT stores + sum/ssq
#pragma unroll
  for (int fm=0; fm<4; ++fm){
    int rw = w*64 + fm*16 + lg*4;
#pragma unroll
    for (int fn=0; fn<8; ++fn){
      int cl = fn*16 + lm;
#pragma unroll
      for (int j=0; j<4; ++j){
        __half h = __float2half(acc[fm][fn][j]);
        sm[(rw+j)*136 + cl] = *(ushort_t*)&h;
      }
    }
  }
  __syncthreads();

  const int cch = t & 15, rb = t >> 4;
  float s1[8] = {0.f,0.f,0.f,0.f,0.f,0.f,0.f,0.f};
  float s2[8] = {0.f,0.f,0.f,0.f,0.f,0.f,0.f,0.f};
#pragma unroll
  for (int i=0; i<16; ++i){
    int row = rb + i*16;
    u32x4 v = *(const u32x4*)&sm[row*136 + cch*8];
    __builtin_nontemporal_store(v, (u32x4*)(Ob + (size_t)(row0+row)*128 + cch*8));
    const __half* hp = (const __half*)&v;
#pragma unroll
    for (int k=0;k<8;++k){
      float f = __half2float(hp[k]);
      s1[k] += f;
      s2[k] += f*f;
    }
  }
#pragma unroll
  for (int k=0;k<8;++k){
    atomicAdd(&sqred[cch*8+k], s1[k]);
    atomicAdd(&sqred[128+cch*8+k], s2[k]);
  }
  __syncthreads();
  if (t < 128){
    atomicAdd(&sums[col0 + t], sqred[t]);
    atomicAdd(&sums[384 + col0 + t], sqred[128+t]);
  }
}

// ---------------- fused apply: ga (blocks 0..1023) + gb (blocks 1024..7167) ----
__global__ void apply_gagb(const __half* __restrict__ O0, const __half* __restrict__ O1,
                           const __half* __restrict__ O2, ushort_t* __restrict__ nb,
                           const float* __restrict__ sums,
                           const float* __restrict__ g1a, const float* __restrict__ b1a,
                           const float* __restrict__ g1b, const float* __restrict__ b1b,
                           float* __restrict__ asum, float* __restrict__ st){
  __shared__ float red[256];
  int bx = blockIdx.x;
  int t = threadIdx.x;
  if (bx < 1024){
    red[t] = 0.f;
    int c8 = t & 15, al = t >> 4;
    int i = bx*16 + al;
    int c0 = c8*8;
    float gf[8], bfv[8], gc[8], bcv[8];
#pragma unroll
    for (int k=0;k<8;++k){
      int c = c0+k;
      float mf = sums[c]*(1.f/NM);
      float rf = rsqrtf(sums[384+c]*(1.f/NM) - mf*mf + 1e-5f);
      gf[k]  = g1a[c]*rf;      bfv[k] = b1a[c] - mf*gf[k];
      float mc = sums[c+128]*(1.f/NM);
      float rc = rsqrtf(sums[384+c+128]*(1.f/NM) - mc*mc + 1e-5f);
      gc[k]  = g1a[c+128]*rc;  bcv[k] = b1a[c+128] - mc*gc[k];
    }
    float s[8] = {0.f,0.f,0.f,0.f,0.f,0.f,0.f,0.f};
    size_t base = (size_t)i*12*128;
#pragma unroll
    for (int j=0;j<12;++j){
      u32x4 vf = __builtin_nontemporal_load((const u32x4*)(O0 + base + j*128 + c0));
      u32x4 vc = __builtin_nontemporal_load((const u32x4*)(O1 + base + j*128 + c0));
      const __half* hf = (const __half*)&vf;
      const __half* hc = (const __half*)&vc;
#pragma unroll
      for (int k=0;k<8;++k)
        s[k] += sigmoidf_(fmaf(__half2float(hf[k]), gf[k], bfv[k]))
              * softplusf_(fmaf(__half2float(hc[k]), gc[k], bcv[k]));
    }
    float* dst = asum + (size_t)i*128 + c0;
    __syncthreads();
#pragma unroll
    for (int k=0;k<8;++k){
      dst[k] = s[k];
      atomicAdd(&red[c0+k], s[k]);
      atomicAdd(&red[128+c0+k], s[k]*s[k]);
    }
    __syncthreads();
    atomicAdd(&st[t], red[t]);
  } else {
    int c8 = t & 7, rloc = t >> 3;
    int r = (bx-1024)*32 + rloc;
    int c0 = c8*8;
    float gf[8], bfv[8], gc[8], bcv[8];
#pragma unroll
    for (int k=0;k<8;++k){
      int c = c0+k;
      float mf = sums[256+c]*(1.f/NM);
      float rf = rsqrtf(sums[384+256+c]*(1.f/NM) - mf*mf + 1e-5f);
      gf[k]  = g1b[c]*rf;      bfv[k] = b1b[c] - mf*gf[k];
      float mc = sums[256+64+c]*(1.f/NM);
      float rc = rsqrtf(sums[384+256+64+c]*(1.f/NM) - mc*mc + 1e-5f);
      gc[k]  = g1b[c+64]*rc;   bcv[k] = b1b[c+64] - mc*gc[k];
    }
    size_t gbase = (size_t)r*128;
    u32x4 vf = __builtin_nontemporal_load((const u32x4*)(O2 + gbase + c0));
    u32x4 vc = __builtin_nontemporal_load((const u32x4*)(O2 + gbase + 64 + c0));
    const __half* hf = (const __half*)&vf;
    const __half* hc = (const __half*)&vc;
    ushort_t* np = nb + (size_t)r*64 + c0;
    u32x4 old = *(const u32x4*)np;
    const ushort_t* op = (const ushort_t*)&old;
    u32x4 outv;
    ushort_t* ov = (ushort_t*)&outv;
#pragma unroll
    for (int k=0;k<8;++k){
      float x = bf2f(op[k]) + sigmoidf_(fmaf(__half2float(hf[k]), gf[k], bfv[k]))
                            * softplusf_(fmaf(__half2float(hc[k]), gc[k], bcv[k]));
      ov[k] = f2bf(softplusf_(x));
    }
    *(u32x4*)np = outv;
  }
}

// ---------------- fused: apply_out1 (blocks 121..8312) + next-pass wtr (0..119)
//                  + next-pass stats zero (block 120) ----
__global__ void out1_wtr(ushort_t* __restrict__ a0, const float* __restrict__ asum,
                         const float* __restrict__ st, const float* __restrict__ g2a,
                         const float* __restrict__ b2a,
                         const float* __restrict__ Wa_next, const float* __restrict__ Wb_next,
                         ushort_t* __restrict__ Wt, float* __restrict__ zstats){
  __shared__ ushort_t tile[32][33];
  int bx = blockIdx.x;
  int t = threadIdx.x;
  if (bx < 120){
    if (Wa_next == nullptr) return;
    int by = bx / 10, kx = bx - by*10;
    const float* W; int NO, o0, obase;
    if (by < 8){ W = Wa_next; NO = 256; o0 = by*32; obase = o0; }
    else       { W = Wb_next; NO = 128; o0 = (by-8)*32; obase = 256 + o0; }
    int k0 = kx*32;
    int tx = t & 31, ty = t >> 5;
#pragma unroll
    for (int i = ty; i < 32; i += 8)
      tile[i][tx] = f2bf(W[(size_t)(k0+i)*NO + o0 + tx]);
    __syncthreads();
#pragma unroll
    for (int i = ty; i < 32; i += 8)
      Wt[(size_t)(obase+i)*320 + k0 + tx] = tile[tx][i];
  } else if (bx == 120){
    if (Wa_next == nullptr) return;
#pragma unroll
    for (int k=0;k<4;++k) zstats[t + k*256] = 0.f;
  } else {
    int e = (bx-121)*256 + t; // n*128
    int c = e & 127;
    float m  = st[c]*(1.f/N_ATOM);
    float var = st[128+c]*(1.f/N_ATOM) - m*m;
    float rs = rsqrtf(var + 1e-5f);
    float g = g2a[c]*rs;
    float b = b2a[c] - m*g;
    a0[e] = f2bf(softplusf_(bf2f(a0[e]) + fmaf(asum[e], g, b)));
  }
}

// ---------------- fused pooling: blocks 0..127 atoms, 128..255 bonds ----------
__global__ void pool_fused(const ushort_t* __restrict__ a, const ushort_t* __restrict__ nb,
                           float* __restrict__ pooled){
  __shared__ float sh[256];
  int bx = blockIdx.x; int t = threadIdx.x; // 256
  if (bx < 128){
    int b = bx;
    int c = t & 127, h = t >> 7;
    float s = 0.f;
    for (int i=h;i<128;i+=2) s += bf2f(a[(size_t)((b<<7)+i)*128 + c]);
    sh[t] = s;
    __syncthreads();
    if (t < 128)
      pooled[b*896 + t] = softplusf_((sh[t]+sh[t+128]) * (1.f/128.f));
  } else {
    int b = bx - 128;
    float s0=0.f, s1=0.f, s2=0.f;
    for (int i=0;i<128;++i){
      size_t base = (size_t)((b<<7)+i)*768;
      s0 += bf2f(nb[base + t]);
      s1 += bf2f(nb[base + t + 256]);
      s2 += bf2f(nb[base + t + 512]);
    }
    pooled[b*896 + 128 + t]       = softplusf_(s0 * (1.f/128.f));
    pooled[b*896 + 128 + t + 256] = softplusf_(s1 * (1.f/128.f));
    pooled[b*896 + 128 + t + 512] = softplusf_(s2 * (1.f/128.f));
  }
}

// ---------------- muz with inline threefry eps (PRECISE math for eps) ----------
__global__ void muz_v2(const float* __restrict__ pooled, const float* __restrict__ muW,
                       const float* __restrict__ mub, const float* __restrict__ lvW,
                       const float* __restrict__ lvb,
                       float* __restrict__ out_mu, float* __restrict__ out_lv,
                       float* __restrict__ out_z, float* __restrict__ zws){
  int t = threadIdx.x; // 256 -> (b,l)
  float epsv;
  {
    const uint32_t k0 = 0u, k1 = 42u;
    const uint32_t ks2 = k0 ^ k1 ^ 0x1BD11BDAu;
    uint32_t x0 = 0u + k0;
    uint32_t x1 = (uint32_t)t + k1;
#define RND_(r) { x0 += x1; x1 = rotl32_(x1, r); x1 ^= x0; }
    RND_(13) RND_(15) RND_(26) RND_(6)  x0 += k1;  x1 += ks2 + 1u;
    RND_(17) RND_(29) RND_(16) RND_(24) x0 += ks2; x1 += k0 + 2u;
    RND_(13) RND_(15) RND_(26) RND_(6)  x0 += k0;  x1 += k1 + 3u;
    RND_(17) RND_(29) RND_(16) RND_(24) x0 += k1;  x1 += ks2 + 4u;
    RND_(13) RND_(15) RND_(26) RND_(6)  x0 += ks2; x1 += k0 + 5u;
#undef RND_
    uint32_t bits = x0 ^ x1;
    float f = __uint_as_float((bits >> 9) | 0x3f800000u) - 1.0f;
    float u = __fadd_rn(__fmul_rn(f, 1.99999994f), -0.99999994f);
    u = fmaxf(-0.99999994f, u);
    float w = -log1pf(-u*u);
    float p;
    if (w < 5.0f){
      w -= 2.5f;
      p = 2.81022636e-08f;
      p = fmaf(p, w, 3.43273939e-07f);
      p = fmaf(p, w, -3.5233877e-06f);
      p = fmaf(p, w, -4.39150654e-06f);
      p = fmaf(p, w, 0.00021858087f);
      p = fmaf(p, w, -0.00125372503f);
      p = fmaf(p, w, -0.00417768164f);
      p = fmaf(p, w, 0.246640727f);
      p = fmaf(p, w, 1.50140941f);
    } else {
      w = sqrtf(w) - 3.0f;
      p = -0.000200214257f;
      p = fmaf(p, w, 0.000100950558f);
      p = fmaf(p, w, 0.00134934322f);
      p = fmaf(p, w, -0.00367342844f);
      p = fmaf(p, w, 0.00573950773f);
      p = fmaf(p, w, -0.0076224613f);
      p = fmaf(p, w, 0.00943887047f);
      p = fmaf(p, w, 1.00167406f);
      p = fmaf(p, w, 2.83297682f);
    }
    epsv = 1.41421356237f * (p * u);
  }
  int b = t >> 1, l = t & 1;
  const float* pr = pooled + b*896;
  float smu = mub[l], slv = lvb[l];
  for (int k=0;k<896;++k){
    float p = pr[k];
    smu = fmaf(p, muW[k*2+l], smu);
    slv = fmaf(p, lvW[k*2+l], slv);
  }
  out_mu[t] = smu; out_lv[t] = slv;
  float zv = fmaf(epsv, __expf(0.5f*slv), smu);
  out_z[t] = zv; zws[t] = zv;
}

__global__ void compute_f_kernel(const float* __restrict__ zws, const float* __restrict__ decW,
                                 const float* __restrict__ decb, const float* __restrict__ pooled,
                                 float* __restrict__ f){
  int b = blockIdx.x;
  float z0 = zws[b*2], z1 = zws[b*2+1];
  for (int k = threadIdx.x; k < 896; k += 256){
    float zd = fmaf(z0, decW[k], fmaf(z1, decW[896+k], decb[k]));
    f[b*896+k] = __fdividef(zd, pooled[b*896+k]);
  }
}

// ---------------- fused decode: blocks 0..8191 atoms, 8192..57343 bonds ----------
__global__ void dec_fused(ushort_t* __restrict__ a, ushort_t* __restrict__ nb,
                          const float* __restrict__ f){
  int bx = blockIdx.x; int t = threadIdx.x; // 256
  if (bx < 8192){
    int e = bx*256 + t; // n*128
    int c = e & 127; int b = e >> 14;
    a[e] = f2bf(softplusf_(bf2f(a[e]) * f[b*896 + c]));
  } else {
    int blk = bx - 8192;
    int oy = blk >> 14, i = blk & 16383;
    int off = oy*256 + t;
    int b = i >> 7;
    size_t e = (size_t)i*768 + off;
    nb[e] = f2bf(softplusf_(bf2f(nb[e]) * f[b*896 + 128 + off]));
  }
}

// ---------------- fused tail-1: embed_atom2 (blocks 0..8191) + bproj (8192..40959) ----
__global__ void tail_fused(const ushort_t* __restrict__ a, const float* __restrict__ Wa2,
                           const float* __restrict__ ba2,
                           const ushort_t* __restrict__ nb, const float* __restrict__ Wb2,
                           const float* __restrict__ bb2,
                           float* __restrict__ za2, float* __restrict__ bp){
  int bx = blockIdx.x; int t = threadIdx.x; // 256
  if (bx < 8192){
    __shared__ float row[2][128];
    int al = t >> 7, tt = t & 127;
    int i = bx*2 + al;
    row[al][tt] = bf2f(a[(size_t)i*128+tt]);
    __syncthreads();
    if (tt < 92){
      float s = ba2[tt];
#pragma unroll
      for (int k=0;k<128;++k) s = fmaf(row[al][k], Wa2[k*92+tt], s);
      za2[(size_t)i*92+tt] = sigmoidf_(s);
    }
  } else {
    __shared__ float Ws[64][41];
    __shared__ float rows[6][64];
    for (int e=t; e<64*41; e+=256) Ws[e/41][e%41] = Wb2[e];
    int r0 = (bx-8192)*6;
    for (int e=t; e<6*64; e+=256){
      int rr = e>>6, c = e&63;
      rows[rr][c] = bf2f(nb[(size_t)(r0+rr)*64 + c]);
    }
    __syncthreads();
    if (t < 246){
      int rr = t/41, o = t - rr*41;
      float s = bb2[o];
#pragma unroll
      for (int k=0;k<64;++k) s = fmaf(rows[rr][k], Ws[k][o], s);
      bp[(size_t)(r0+rr)*41 + o] = sigmoidf_(s);
    }
  }
}

// ---------------- zdec v3: LDS-tiled branch-uniform gather, float4 NT writes ----
__global__ void zdec_v3(const float* __restrict__ za2, const float* __restrict__ bp,
                        const int* __restrict__ idx, float* __restrict__ out){
  __shared__ float tile[32*225];     // 28.8 KB
  __shared__ int   idxs[32];
  int bx = blockIdx.x; int t = threadIdx.x; // 256
  const int r0 = bx*32;
  if (t < 32) idxs[t] = idx[r0 + t];
  __syncthreads();
  for (int e = t; e < 32*92; e += 256){
    int rr = e / 92, c = e - rr*92;
    tile[rr*225 + c] = za2[((r0+rr)/12)*92 + c];
  }
  for (int e = t; e < 32*92; e += 256){
    int rr = e / 92, c = e - rr*92;
    tile[rr*225 + 92 + c] = za2[idxs[rr]*92 + c];
  }
  for (int e = t; e < 32*41; e += 256){
    int rr = e / 41, c = e - rr*41;
    tile[rr*225 + 184 + c] = bp[(size_t)r0*41 + e];
  }
  __syncthreads();
  float* dst = out + (size_t)r0*225;
  for (int e4 = t; e4 < 1800; e4 += 256){
    f32x4 v = *(const f32x4*)&tile[e4*4];
    __builtin_nontemporal_store(v, (f32x4*)(dst + e4*4));
  }
}

// ---------------- host side ----------------
struct WsPlan {
  ushort_t *Abf, *NBbf, *Wt;
  __half* big;
  float *asum, *pooled, *fbuf, *zws, *sums0, *sums1;
};

struct PassW {
  const float *Wa,*Wb,*g1a,*b1a,*g1b,*b1b,*g2a,*b2a;
};

extern "C" void kernel_launch(void* const* d_in, const int* in_sizes, int n_in,
                              void* d_out, int out_size, void* d_ws, size_t ws_size,
                              hipStream_t stream) {
  (void)in_sizes; (void)n_in; (void)out_size; (void)ws_size;
  const float* atom_fea   = (const float*)d_in[0];
  const float* nbr_fea    = (const float*)d_in[1];
  const int*   idx        = (const int*)d_in[2];
  const float* emb_atom_W = (const float*)d_in[4];
  const float* emb_atom_b = (const float*)d_in[5];
  const float* emb_bond_W = (const float*)d_in[6];
  const float* emb_bond_b = (const float*)d_in[7];
  const float* emb_atom2_W= (const float*)d_in[8];
  const float* emb_atom2_b= (const float*)d_in[9];
  const float* emb_bond2_W= (const float*)d_in[10];
  const float* emb_bond2_b= (const float*)d_in[11];
  const float* mu_W       = (const float*)d_in[12];
  const float* mu_b       = (const float*)d_in[13];
  const float* lv_W       = (const float*)d_in[14];
  const float* lv_b       = (const float*)d_in[15];
  const float* dec_W      = (const float*)d_in[16];
  const float* dec_b      = (const float*)d_in[17];
  const float* c1_Wa  = (const float*)d_in[18];
  const float* c1_Wb  = (const float*)d_in[19];
  const float* c1_g1a = (const float*)d_in[20];
  const float* c1_b1a = (const float*)d_in[21];
  const float* c1_g1b = (const float*)d_in[22];
  const float* c1_b1b = (const float*)d_in[23];
  const float* c1_g2a = (const float*)d_in[24];
  const float* c1_b2a = (const float*)d_in[25];
  const float* c2_Wa  = (const float*)d_in[26];
  const float* c2_Wb  = (const float*)d_in[27];
  const float* c2_g1a = (const float*)d_in[28];
  const float* c2_b1a = (const float*)d_in[29];
  const float* c2_g1b = (const float*)d_in[30];
  const float* c2_b1b = (const float*)d_in[31];
  const float* c2_g2a = (const float*)d_in[32];
  const float* c2_b2a = (const float*)d_in[33];

  float* out = (float*)d_out;

  hipFuncSetAttribute((const void*)conv_gemm_v10,
                      hipFuncAttributeMaxDynamicSharedMemorySize, GEMM_LDS_V9);

  WsPlan P;
  char* w = (char*)d_ws;
  auto alloc = [&](size_t bytes) -> char* {
    char* p = w; w += (bytes + 255) & ~(size_t)255; return p;
  };
  P.Abf    = (ushort_t*)alloc((size_t)N_ATOM*128*2);
  P.NBbf   = (ushort_t*)alloc((size_t)NM*64*2);
  P.big    = (__half*)  alloc((size_t)NM*384*2);
  P.asum   = (float*)   alloc((size_t)N_ATOM*128*4);
  P.pooled = (float*)   alloc(114688*4);
  P.fbuf   = (float*)   alloc(114688*4);
  P.Wt     = (ushort_t*)alloc(384*320*2);
  P.zws    = (float*)   alloc(256*4);
  P.sums0  = (float*)   alloc(1024*4);   // slot 0: sums[768] + st[256]
  P.sums1  = (float*)   alloc(1024*4);   // slot 1
  float* za2   = P.asum;                 // reuse after conv stacks
  float* bproj = (float*)P.big;          // reuse big in the final phase

  PassW pw[6] = {
    { c1_Wa,            c1_Wb,            c1_g1a,       c1_b1a,       c1_g1b,       c1_b1b,       c1_g2a,       c1_b2a       },
    { c1_Wa+320*256,    c1_Wb+320*128,    c1_g1a+256,   c1_b1a+256,   c1_g1b+128,   c1_b1b+128,   c1_g2a+128,   c1_b2a+128   },
    { c1_Wa+2*320*256,  c1_Wb+2*320*128,  c1_g1a+2*256, c1_b1a+2*256, c1_g1b+2*128, c1_b1b+2*128, c1_g2a+2*128, c1_b2a+2*128 },
    { c2_Wa,            c2_Wb,            c2_g1a,       c2_b1a,       c2_g1b,       c2_b1b,       c2_g2a,       c2_b2a       },
    { c2_Wa+320*256,    c2_Wb+320*128,    c2_g1a+256,   c2_b1a+256,   c2_g1b+128,   c2_b1b+128,   c2_g2a+128,   c2_b2a+128   },
    { c2_Wa+2*320*256,  c2_Wb+2*320*128,  c2_g1a+2*256, c2_b1a+2*256, c2_g1b+2*128, c2_b1b+2*128, c2_g2a+2*128, c2_b2a+2*128 },
  };

  auto conv_pass = [&](int p){
    float* sums_cur = (p & 1) ? P.sums1 : P.sums0;
    float* sums_nxt = (p & 1) ? P.sums0 : P.sums1;
    const __half* O0 = P.big;
    const __half* O1 = P.big + (size_t)NM*128;
    const __half* O2 = P.big + (size_t)NM*256;
    conv_gemm_v10<<<2304, 256, GEMM_LDS_V9, stream>>>(P.Abf, P.NBbf, idx, P.Wt, P.big, sums_cur);
    apply_gagb<<<7168, 256, 0, stream>>>(O0, O1, O2, P.NBbf, sums_cur,
                                         pw[p].g1a, pw[p].b1a, pw[p].g1b, pw[p].b1b,
                                         P.asum, sums_cur + 768);
    const float* Wa_n = (p < 5) ? pw[p+1].Wa : nullptr;
    const float* Wb_n = (p < 5) ? pw[p+1].Wb : nullptr;
    out1_wtr<<<8313, 256, 0, stream>>>(P.Abf, P.asum, sums_cur + 768,
                                       pw[p].g2a, pw[p].b2a, Wa_n, Wb_n, P.Wt, sums_nxt);
  };

  front_fused<<<63488, 256, 0, stream>>>(atom_fea, nbr_fea, idx, out + O_TIF,
                                         emb_atom_W, emb_atom_b, emb_bond_W, emb_bond_b,
                                         P.Abf, P.NBbf);
  wtr2_kernel<<<dim3(10,12), 256, 0, stream>>>(pw[0].Wa, pw[0].Wb, P.Wt, P.sums0);

  conv_pass(0);
  conv_pass(1);
  conv_pass(2);

  pool_fused<<<256, 256, 0, stream>>>(P.Abf, P.NBbf, P.pooled);
  muz_v2<<<1, 256, 0, stream>>>(P.pooled, mu_W, mu_b, lv_W, lv_b,
                                out + O_MU, out + O_LV, out + O_Z, P.zws);
  compute_f_kernel<<<NCRY, 256, 0, stream>>>(P.zws, dec_W, dec_b, P.pooled, P.fbuf);
  dec_fused<<<57344, 256, 0, stream>>>(P.Abf, P.NBbf, P.fbuf);

  conv_pass(3);
  conv_pass(4);
  conv_pass(5);

  tail_fused<<<40960, 256, 0, stream>>>(P.Abf, emb_atom2_W, emb_atom2_b,
                                        P.NBbf, emb_bond2_W, emb_bond2_b, za2, bproj);
  zdec_v3<<<6144, 256, 0, stream>>>(za2, bproj, idx, out + O_ZDEC);
}